// Round 16
// baseline (392.576 us; speedup 1.0000x reference)
//
#include <hip/hip_runtime.h>
#include <math.h>

#define CN 128   // captions
#define INN 128  // images
#define LN 48    // words
#define RN 36    // regions
#define DN 1024  // feature dim
#define RTA 36   // regions per attn block (TIA=1)
#define MT 6144  // CN*LN
#define NT 4608  // INN*RN
#define EPSF 1e-8f
#define LSM 9.0f
#define LLSE 6.0f

__device__ __forceinline__ float leaky(float x){ return x > 0.f ? x : 0.1f*x; }
__device__ __forceinline__ float dot4(float4 a, float4 b){
  return a.x*b.x + a.y*b.y + a.z*b.z + a.w*b.w;
}

typedef const __attribute__((address_space(1))) unsigned int* gp_t;
typedef __attribute__((address_space(3))) unsigned int* lp_t;
__device__ __forceinline__ void gload16u(const ushort* g, ushort* l) {
  __builtin_amdgcn_global_load_lds((gp_t)g, (lp_t)l, 16, 0, 0);
}

typedef short s16x8 __attribute__((ext_vector_type(8)));
typedef float f32x4 __attribute__((ext_vector_type(4)));

__device__ __forceinline__ void bf16split(float f, ushort& h, ushort& l) {
  const unsigned u = __float_as_uint(f);
  h = (ushort)((u + 0x7fffu + ((u>>16)&1u)) >> 16);
  const float res = f - __uint_as_float((unsigned)h << 16);
  const unsigned u2 = __float_as_uint(res);
  l = (ushort)((u2 + 0x7fffu + ((u2>>16)&1u)) >> 16);
}
__device__ __forceinline__ ushort bf16rne(float f) {
  const unsigned u = __float_as_uint(f);
  return (ushort)((u + 0x7fffu + ((u>>16)&1u)) >> 16);
}
__device__ __forceinline__ float bf2f(ushort u) {
  return __uint_as_float((unsigned)u << 16);
}
// XOR swizzle within a 64-elem bf16 row (8-elem granules): 2-way max bank alias
__device__ __forceinline__ int swzi(int row, int col) {
  return (col & 7) | ((((col >> 3) ^ (row & 7)) & 7) << 3);
}

// ---------------- Kernel 1: Gram + norms + bf16 emission (planes + padded G) ----------
__global__ __launch_bounds__(256) void gram_conv_kernel(
    const float* __restrict__ imgs, const float* __restrict__ caps,
    float* __restrict__ gI, float* __restrict__ nI,
    float* __restrict__ gC, float* __restrict__ nC,
    ushort* __restrict__ aHi,
    ushort* __restrict__ bHi, ushort* __restrict__ bLo,
    ushort* __restrict__ gIb, ushort* __restrict__ gCb)
{
  __shared__ __align__(16) float L[LN*132];
  const int b = blockIdx.x, tid = threadIdx.x;
  if (b < INN) {
    const float* base = imgs + (size_t)b*RN*DN;
    const int rg = tid/12, cg = tid - (tid/12)*12;
    const bool active = tid < 216;
    float a[2][3];
    #pragma unroll
    for (int u = 0; u < 2; ++u)
      #pragma unroll
      for (int v = 0; v < 3; ++v) a[u][v] = 0.f;
    for (int d0 = 0; d0 < DN; d0 += 128) {
      __syncthreads();
      for (int idx = tid; idx < RN*32; idx += 256) {
        const int row = idx >> 5, ch = idx & 31;
        *(float4*)&L[row*132 + ch*4] = *(const float4*)(base + row*DN + d0 + ch*4);
      }
      __syncthreads();
      for (int idx = tid; idx < RN*32; idx += 256) {
        const int row = idx >> 5, ch = idx & 31;
        const float4 v = *(const float4*)&L[row*132 + ch*4];
        const float fv[4] = {v.x,v.y,v.z,v.w};
        ushort hh[4], ll[4];
        #pragma unroll
        for (int e = 0; e < 4; ++e) bf16split(fv[e], hh[e], ll[e]);
        const size_t off = (size_t)(b*RN + row)*DN + d0 + ch*4;
        *(ushort4*)(bHi + off) = make_ushort4(hh[0],hh[1],hh[2],hh[3]);
        *(ushort4*)(bLo + off) = make_ushort4(ll[0],ll[1],ll[2],ll[3]);
      }
      if (active) {
        const float* r0 = &L[(2*rg)*132],   * r1 = &L[(2*rg+1)*132];
        const float* c0 = &L[(3*cg)*132],   * c1 = &L[(3*cg+1)*132], * c2 = &L[(3*cg+2)*132];
        #pragma unroll
        for (int k = 0; k < 32; ++k) {
          const float4 x0 = *(const float4*)(r0 + k*4);
          const float4 x1 = *(const float4*)(r1 + k*4);
          const float4 y0 = *(const float4*)(c0 + k*4);
          const float4 y1 = *(const float4*)(c1 + k*4);
          const float4 y2 = *(const float4*)(c2 + k*4);
          a[0][0] += dot4(x0,y0); a[0][1] += dot4(x0,y1); a[0][2] += dot4(x0,y2);
          a[1][0] += dot4(x1,y0); a[1][1] += dot4(x1,y1); a[1][2] += dot4(x1,y2);
        }
      }
    }
    if (active) {
      float* gb = gI + (size_t)b*RN*RN;
      #pragma unroll
      for (int u = 0; u < 2; ++u)
        #pragma unroll
        for (int v = 0; v < 3; ++v) {
          const int r = 2*rg + u, s = 3*cg + v;
          gb[r*RN + s] = a[u][v];
          if (r == s) nI[b*RN + r] = sqrtf(fmaxf(a[u][v], 1e-16f));
        }
    }
    __threadfence_block();
    __syncthreads();
    const float* gsrc = gI + (size_t)b*RN*RN;
    ushort* gdst = gIb + (size_t)b*3072;
    for (int idx = tid; idx < 3072; idx += 256) {
      const int row = idx >> 6, col = idx & 63;
      gdst[idx] = (row < RN && col < RN) ? bf16rne(gsrc[row*RN + col]) : (ushort)0;
    }
  } else {
    const int c = b - INN;
    const float* base = caps + (size_t)c*LN*DN;
    const int rg = tid >> 4, cg = tid & 15;
    float a[3][3];
    #pragma unroll
    for (int u = 0; u < 3; ++u)
      #pragma unroll
      for (int v = 0; v < 3; ++v) a[u][v] = 0.f;
    for (int d0 = 0; d0 < DN; d0 += 128) {
      __syncthreads();
      for (int idx = tid; idx < LN*32; idx += 256) {
        const int row = idx >> 5, ch = idx & 31;
        *(float4*)&L[row*132 + ch*4] = *(const float4*)(base + row*DN + d0 + ch*4);
      }
      __syncthreads();
      for (int idx = tid; idx < LN*32; idx += 256) {
        const int row = idx >> 5, ch = idx & 31;
        const float4 v = *(const float4*)&L[row*132 + ch*4];
        const size_t off = (size_t)(c*LN + row)*DN + d0 + ch*4;
        *(ushort4*)(aHi + off) = make_ushort4(
            bf16rne(v.x), bf16rne(v.y), bf16rne(v.z), bf16rne(v.w));
      }
      const float* r0 = &L[(3*rg)*132],   * r1 = &L[(3*rg+1)*132], * r2 = &L[(3*rg+2)*132];
      const float* c0 = &L[(3*cg)*132],   * c1 = &L[(3*cg+1)*132], * c2 = &L[(3*cg+2)*132];
      #pragma unroll
      for (int k = 0; k < 32; ++k) {
        const float4 x0 = *(const float4*)(r0 + k*4);
        const float4 x1 = *(const float4*)(r1 + k*4);
        const float4 x2 = *(const float4*)(r2 + k*4);
        const float4 y0 = *(const float4*)(c0 + k*4);
        const float4 y1 = *(const float4*)(c1 + k*4);
        const float4 y2 = *(const float4*)(c2 + k*4);
        a[0][0] += dot4(x0,y0); a[0][1] += dot4(x0,y1); a[0][2] += dot4(x0,y2);
        a[1][0] += dot4(x1,y0); a[1][1] += dot4(x1,y1); a[1][2] += dot4(x1,y2);
        a[2][0] += dot4(x2,y0); a[2][1] += dot4(x2,y1); a[2][2] += dot4(x2,y2);
      }
    }
    float* gb = gC + (size_t)c*LN*LN;
    #pragma unroll
    for (int u = 0; u < 3; ++u)
      #pragma unroll
      for (int v = 0; v < 3; ++v) {
        const int r = 3*rg + u, s = 3*cg + v;
        gb[r*LN + s] = a[u][v];
        if (r == s) nC[c*LN + r] = sqrtf(fmaxf(a[u][v], 1e-16f));
      }
    __threadfence_block();
    __syncthreads();
    const float* gsrc = gC + (size_t)c*LN*LN;
    ushort* gdst = gCb + (size_t)c*3072;
    for (int idx = tid; idx < 3072; idx += 256) {
      const int row = idx >> 6, col = idx & 63;
      gdst[idx] = (col < LN) ? bf16rne(gsrc[row*LN + col]) : (ushort)0;
    }
  }
}

// ---------------- Kernel 2: dots GEMM via bf16x2 MFMA (unchanged) ----------------
__global__ __launch_bounds__(256) void dots_gemm_mfma(
    const ushort* __restrict__ aHi,
    const ushort* __restrict__ bHi, const ushort* __restrict__ bLo,
    float* __restrict__ dots, int arow0)
{
  __shared__ __align__(16) ushort sT[12288];
  const int tid = threadIdx.x;
  const int wv = tid >> 6, lane = tid & 63;
  const int l15 = lane & 15, kg = lane >> 4;
  const int wr = wv >> 1, wc = wv & 1;
  const int M0 = blockIdx.y * 128;
  const int N0 = blockIdx.x * 128;

  int offA[4], offB[4];
  #pragma unroll
  for (int f = 0; f < 4; ++f) {
    const int rA = wr*64 + f*16 + l15;
    offA[f] = rA*32 + ((kg ^ ((rA>>1)&3)) << 3);
    const int rB = wc*64 + f*16 + l15;
    offB[f] = rB*32 + ((kg ^ ((rB>>1)&3)) << 3);
  }
  int srow[2], sgk[2]; unsigned dOff[2];
  #pragma unroll
  for (int h = 0; h < 2; ++h) {
    const int ch = h*256 + wv*64 + lane;
    const int row = ch >> 2, gp = ch & 3;
    srow[h] = row;
    sgk[h] = (gp ^ ((row>>1)&3)) * 8;
    dOff[h] = (unsigned)(h*256 + wv*64) * 8;
  }

  f32x4 acc[4][4];
  #pragma unroll
  for (int mf = 0; mf < 4; ++mf)
    #pragma unroll
    for (int nf = 0; nf < 4; ++nf) acc[mf][nf] = (f32x4){0.f,0.f,0.f,0.f};

  const size_t aR = (size_t)(arow0 + M0);
  for (int k0 = 0; k0 < DN; k0 += 32) {
    __syncthreads();
    #pragma unroll
    for (int h = 0; h < 2; ++h) {
      const size_t ao = (aR + srow[h])*DN + k0 + sgk[h];
      const size_t bo = ((size_t)(N0 + srow[h]))*DN + k0 + sgk[h];
      gload16u(aHi + ao, sT + dOff[h]);
      gload16u(bHi + bo, sT + 4096 + dOff[h]);
      gload16u(bLo + bo, sT + 8192 + dOff[h]);
    }
    asm volatile("s_waitcnt vmcnt(0)" ::: "memory");
    __syncthreads();
    s16x8 ah[4], bh[4], bl[4];
    #pragma unroll
    for (int f = 0; f < 4; ++f) {
      ah[f] = *(const s16x8*)&sT[offA[f]];
      bh[f] = *(const s16x8*)&sT[4096 + offB[f]];
      bl[f] = *(const s16x8*)&sT[8192 + offB[f]];
    }
    #pragma unroll
    for (int mf = 0; mf < 4; ++mf)
      #pragma unroll
      for (int nf = 0; nf < 4; ++nf) {
        acc[mf][nf] = __builtin_amdgcn_mfma_f32_16x16x32_bf16(ah[mf], bh[nf], acc[mf][nf], 0,0,0);
        acc[mf][nf] = __builtin_amdgcn_mfma_f32_16x16x32_bf16(ah[mf], bl[nf], acc[mf][nf], 0,0,0);
      }
  }
  #pragma unroll
  for (int mf = 0; mf < 4; ++mf)
    #pragma unroll
    for (int nf = 0; nf < 4; ++nf) {
      const int n = N0 + wc*64 + nf*16 + l15;
      #pragma unroll
      for (int r = 0; r < 4; ++r) {
        const int m = M0 + wr*64 + mf*16 + kg*4 + r;
        dots[(size_t)m*NT + n] = acc[mf][nf][r];
      }
    }
}

// ---------------- Kernel 3: attention — 384 threads, single-pass ----------------
// R16: 96 teams cover all 84 rows in ONE Phase-B pass; norms computed by 4-lane
// teams (12/9 iters + shuffles, was 48/36 serial); epilogue LSE sums via wave
// butterflies. LDS unchanged (4 blocks/CU) but 24 waves/CU (was 16).
__global__ __launch_bounds__(384) void attn_kernel(
    const float* __restrict__ dots, const int* __restrict__ cap_lens,
    const ushort* __restrict__ gIb, const ushort* __restrict__ gCb,
    const float* __restrict__ nI, const float* __restrict__ nC,
    float* __restrict__ scores, int cbase)
{
  __shared__ float sDots[LN][RTA+1];                  // 48 x 37
  __shared__ __align__(16) ushort sMeT[LN*64];        // A: [l][r] swizzled
  __shared__ __align__(16) ushort sMeIT[48*64];       // B: [r][l] swizzled
  __shared__ __align__(16) ushort sGcA[LN*64];        // A: [l][m] swizzled
  __shared__ __align__(16) ushort sGiB[48*64];        // B: [s][r] swizzled (symmetric)
  __shared__ float sQqT[LN], sQqI[48];
  __shared__ float sW12t[LN], sInvT[LN];
  __shared__ float sW12i[RN], sInvI[RN];
  __shared__ float sColInv[RN], sRowInv[LN];
  __shared__ float sCapN[LN], sImgN[RN];
  __shared__ float sEt[LN], sEi[RN];
  __shared__ float sRed[2];

  const int cl = blockIdx.y;
  const int c  = cbase + cl;
  const int it = blockIdx.x;
  const int tid = threadIdx.x;
  const int lane = tid & 63, wv = tid >> 6;
  const int l15 = lane & 15, kg = lane >> 4;
  const int team = tid >> 2, q4 = tid & 3;
  const int nw = cap_lens[c];
  const float nwf = (float)nw;

  // ---- Phase A: stage + zero ----
  for (int idx = tid; idx < LN*RTA/4; idx += 384) {
    const int l = idx / (RTA/4), jseg = idx - l*(RTA/4);
    const float4 v = *(const float4*)(dots + ((size_t)cl*LN + l)*NT + (size_t)it*RTA + jseg*4);
    float* dst = &sDots[l][jseg*4];
    dst[0]=v.x; dst[1]=v.y; dst[2]=v.z; dst[3]=v.w;
  }
  for (int idx = tid; idx < 768; idx += 384) {
    if (idx < 384) ((uint4*)sMeT)[idx] = make_uint4(0,0,0,0);
    else           ((uint4*)sMeIT)[idx-384] = make_uint4(0,0,0,0);
  }
  {  // Gc, Gi copy-in (exactly one uint4 per thread each), swizzled granules
    const int row = tid >> 3, gk = tid & 7;
    *(uint4*)&sGcA[row*64 + (gk ^ (row&7))*8] =
      *(const uint4*)(gCb + (size_t)c*3072 + row*64 + gk*8);
    *(uint4*)&sGiB[row*64 + (gk ^ (row&7))*8] =
      *(const uint4*)(gIb + (size_t)it*3072 + row*64 + gk*8);
  }
  if (tid < LN) { sCapN[tid] = nC[c*LN + tid]; sQqT[tid] = 0.f; }
  if (tid >= 64 && tid < 112) sQqI[tid-64] = 0.f;
  if (tid >= 128 && tid < 128+RN) sImgN[tid-128] = nI[it*RN + (tid-128)];
  __syncthreads();

  // ---- norms: team-parallel (teams 0..35 colInv, 36..83 rowInv) ----
  if (team < RN) {
    const int r = team;
    float s = 0.f;
    #pragma unroll
    for (int j = 0; j < 12; ++j) { const float v = leaky(sDots[q4*12+j][r]); s += v*v; }
    s += __shfl_xor(s, 1, 4); s += __shfl_xor(s, 2, 4);
    if (q4 == 0) sColInv[r] = LSM * __builtin_amdgcn_rcpf(sqrtf(s) + EPSF);
  } else if (team < RN + LN) {
    const int l = team - RN;
    float s = 0.f;
    #pragma unroll
    for (int j = 0; j < 9; ++j) { const float v = leaky(sDots[l][q4*9+j]); s += v*v; }
    s += __shfl_xor(s, 1, 4); s += __shfl_xor(s, 2, 4);
    if (q4 == 0) sRowInv[l] = LSM * __builtin_amdgcn_rcpf(sqrtf(s) + EPSF);
  }
  __syncthreads();

  // ---- Phase B: 84 rows, single pass (one row per 4-lane team; R8: no re-batch) ----
  if (team < LN) {
    const int l = team;
    const int cb = q4*9;
    float d9[9], x9[9];
    #pragma unroll
    for (int j = 0; j < 9; ++j) d9[j] = sDots[l][cb + j];
    float se = 0.f;
    #pragma unroll
    for (int j = 0; j < 9; ++j) {
      const float e = __expf(leaky(d9[j]) * sColInv[cb + j]);
      x9[j] = e; se += e;
    }
    se += __shfl_xor(se, 1, 4); se += __shfl_xor(se, 2, 4);
    float ts = 0.f;
    #pragma unroll
    for (int j = 0; j < 9; ++j) {
      const float me = (x9[j]*36.f > se) ? x9[j] : 0.f;
      x9[j] = me; ts += me;
    }
    ts += __shfl_xor(ts, 1, 4); ts += __shfl_xor(ts, 2, 4);
    float w12 = 0.f;
    #pragma unroll
    for (int j = 0; j < 9; ++j) w12 += x9[j]*d9[j];
    w12 += __shfl_xor(w12, 1, 4); w12 += __shfl_xor(w12, 2, 4);
    #pragma unroll
    for (int j = 0; j < 9; ++j)
      sMeT[l*64 + swzi(l, cb + j)] = bf16rne(x9[j]);
    if (q4 == 0) {
      sW12t[l] = w12;
      sInvT[l] = __builtin_amdgcn_rcpf((ts > 0.f) ? ts : 1.f);
    }
  } else if (team < LN + RN) {
    const int r = team - LN;
    float d12[12], x12[12];
    #pragma unroll
    for (int j = 0; j < 12; ++j) d12[j] = sDots[q4*12+j][r];
    float se = 0.f;
    #pragma unroll
    for (int j = 0; j < 12; ++j) {
      const int l = q4*12 + j;
      const float e = (l < nw) ? __expf(leaky(d12[j]) * sRowInv[l]) : 0.f;
      x12[j] = e; se += e;
    }
    se += __shfl_xor(se, 1, 4); se += __shfl_xor(se, 2, 4);
    float ts = 0.f;
    #pragma unroll
    for (int j = 0; j < 12; ++j) {
      const float me = (x12[j]*nwf > se) ? x12[j] : 0.f;
      x12[j] = me; ts += me;
    }
    ts += __shfl_xor(ts, 1, 4); ts += __shfl_xor(ts, 2, 4);
    float w12 = 0.f;
    #pragma unroll
    for (int j = 0; j < 12; ++j) w12 += x12[j]*d12[j];
    w12 += __shfl_xor(w12, 1, 4); w12 += __shfl_xor(w12, 2, 4);
    #pragma unroll
    for (int j = 0; j < 12; ++j)
      sMeIT[r*64 + swzi(r, q4*12 + j)] = bf16rne(x12[j]);
    if (q4 == 0) {
      sW12i[r] = w12;
      sInvI[r] = __builtin_amdgcn_rcpf((ts > 0.f) ? ts : 1.f);
    }
  }
  __syncthreads();

  // ---- Phase C: qq via MFMA (18 tiles over 6 waves) ----
  #pragma unroll 1
  for (int t = wv; t < 18; t += 6) {
    const bool isT = (t < 9);
    const int tt = isT ? t : t - 9;
    const int mt = tt / 3, nt = tt - 3*(tt/3);
    const ushort* Ab = isT ? sMeT : sGcA;
    const ushort* Bb = isT ? sGiB : sMeIT;
    const int arow = mt*16 + l15;
    const int brow = nt*16 + l15;
    f32x4 acc = (f32x4){0.f,0.f,0.f,0.f};
    #pragma unroll
    for (int ks = 0; ks < 2; ++ks) {
      const s16x8 af = *(const s16x8*)&Ab[arow*64 + (((ks*4+kg) ^ (arow&7)))*8];
      const s16x8 bf = *(const s16x8*)&Bb[brow*64 + (((ks*4+kg) ^ (brow&7)))*8];
      acc = __builtin_amdgcn_mfma_f32_16x16x32_bf16(af, bf, acc, 0,0,0);
    }
    if (isT) {
      float part[4];
      #pragma unroll
      for (int rg = 0; rg < 4; ++rg) {
        const int l = mt*16 + kg*4 + rg, s = nt*16 + l15;
        part[rg] = acc[rg] * bf2f(sMeT[l*64 + swzi(l, s)]);
      }
      #pragma unroll
      for (int o = 1; o < 16; o <<= 1)
        #pragma unroll
        for (int rg = 0; rg < 4; ++rg) part[rg] += __shfl_xor(part[rg], o, 16);
      if (l15 == 0)
        #pragma unroll
        for (int rg = 0; rg < 4; ++rg)
          atomicAdd(&sQqT[mt*16 + kg*4 + rg], part[rg]);
    } else {
      float part = 0.f;
      #pragma unroll
      for (int rg = 0; rg < 4; ++rg) {
        const int l = mt*16 + kg*4 + rg, r = nt*16 + l15;
        part += acc[rg] * bf2f(sMeIT[r*64 + swzi(r, l)]);
      }
      part += __shfl_xor(part, 16);
      part += __shfl_xor(part, 32);
      if (lane < 16) atomicAdd(&sQqI[nt*16 + l15], part);
    }
  }
  __syncthreads();

  // ---- Epilogue ----
  if (tid < LN) {
    const float invd = sInvT[tid];
    const float w2 = sqrtf(fmaxf(sQqT[tid]*invd*invd, 1e-16f));
    const float sim = (sW12t[tid]*invd) * __builtin_amdgcn_rcpf(fmaxf(sCapN[tid]*w2, EPSF));
    sEt[tid] = (tid < nw) ? __expf(LLSE*sim) : 0.f;
  }
  if (tid >= 64 && tid < 64+RN) {
    const int r = tid - 64;
    const float invd = sInvI[r];
    const float w2 = sqrtf(fmaxf(sQqI[r]*invd*invd, 1e-16f));
    const float sim = (sW12i[r]*invd) * __builtin_amdgcn_rcpf(fmaxf(sImgN[r]*w2, EPSF));
    sEi[r] = __expf(LLSE*sim);
  }
  __syncthreads();
  if (wv == 0) {
    float e = (lane < LN) ? sEt[lane] : 0.f;
    #pragma unroll
    for (int o = 32; o > 0; o >>= 1) e += __shfl_xor(e, o);
    if (lane == 0) sRed[0] = e;
  } else if (wv == 1) {
    float e = (lane < RN) ? sEi[lane] : 0.f;
    #pragma unroll
    for (int o = 32; o > 0; o >>= 1) e += __shfl_xor(e, o);
    if (lane == 0) sRed[1] = e;
  }
  __syncthreads();
  if (tid == 0)
    scores[(size_t)it*CN + c] = __logf(sRed[0])/LLSE + __logf(sRed[1])/LLSE;
}

// ---------------- Kernel 4: margin ranking loss ----------------
__global__ __launch_bounds__(128) void loss_kernel(
    const float* __restrict__ S, float* __restrict__ out)
{
  __shared__ float red[128];
  const int t = threadIdx.x;
  const float d = S[t*CN + t];
  float m1 = -1e30f, m2 = -1e30f;
  for (int cc = 0; cc < CN; ++cc)
    if (cc != t) m1 = fmaxf(m1, 0.2f + S[t*CN+cc] - d);
  for (int i2 = 0; i2 < INN; ++i2)
    if (i2 != t) m2 = fmaxf(m2, 0.2f + S[i2*CN+t] - d);
  red[t] = fmaxf(m1, 0.f) + fmaxf(m2, 0.f);
  __syncthreads();
  for (int s = 64; s > 0; s >>= 1) {
    if (t < s) red[t] += red[t+s];
    __syncthreads();
  }
  if (t == 0) out[0] = red[0];
}

extern "C" void kernel_launch(void* const* d_in, const int* in_sizes, int n_in,
                              void* d_out, int out_size, void* d_ws, size_t ws_size,
                              hipStream_t stream) {
  (void)in_sizes; (void)n_in; (void)out_size;
  const float* imgs = (const float*)d_in[0];
  const float* caps = (const float*)d_in[1];
  const int*   lens = (const int*)d_in[2];

  const size_t bfUS = 2*((size_t)MT + NT)*DN;
  const size_t gbUS = (size_t)(INN + CN)*3072;
  const size_t smallF = (size_t)INN*RN*RN + INN*RN + (size_t)CN*LN*LN + CN*LN + (size_t)INN*CN;
  int g = CN;
  while (g > 8) {
    const size_t need = (bfUS + gbUS)*2 + (smallF + (size_t)g*LN*NT)*4;
    if (need <= ws_size) break;
    g >>= 1;
  }

  ushort* aHi = (ushort*)d_ws;
  ushort* aLo = aHi + (size_t)MT*DN;   // unused slot (layout stability)
  ushort* bHi = aLo + (size_t)MT*DN;
  ushort* bLo = bHi + (size_t)NT*DN;
  ushort* gIb = bLo + (size_t)NT*DN;
  ushort* gCb = gIb + (size_t)INN*3072;
  float* fbase = (float*)(gCb + (size_t)CN*3072);
  float* gI     = fbase;
  float* nI     = gI + (size_t)INN*RN*RN;
  float* gC     = nI + (size_t)INN*RN;
  float* nC     = gC + (size_t)CN*LN*LN;
  float* scores = nC + (size_t)CN*LN;
  float* dots   = scores + (size_t)INN*CN;

  gram_conv_kernel<<<dim3(INN+CN), dim3(256), 0, stream>>>(
      imgs, caps, gI, nI, gC, nC, aHi, bHi, bLo, gIb, gCb);
  for (int c0 = 0; c0 < CN; c0 += g) {
    dots_gemm_mfma<<<dim3(NT/128, g*LN/128), dim3(256), 0, stream>>>(
        aHi, bHi, bLo, dots, c0*LN);
    attn_kernel<<<dim3(INN, g), dim3(384), 0, stream>>>(
        dots, lens, gIb, gCb, nI, nC, scores, c0);
  }
  loss_kernel<<<dim3(1), dim3(128), 0, stream>>>(scores, (float*)d_out);
}

// Round 17
// 373.535 us; speedup vs baseline: 1.0510x; 1.0510x over previous
//
#include <hip/hip_runtime.h>
#include <math.h>

#define CN 128   // captions
#define INN 128  // images
#define LN 48    // words
#define RN 36    // regions
#define DN 1024  // feature dim
#define RTA 36   // regions per attn block (TIA=1)
#define MT 6144  // CN*LN
#define NT 4608  // INN*RN
#define EPSF 1e-8f
#define LSM 9.0f
#define LLSE 6.0f

__device__ __forceinline__ float leaky(float x){ return x > 0.f ? x : 0.1f*x; }
__device__ __forceinline__ float dot4(float4 a, float4 b){
  return a.x*b.x + a.y*b.y + a.z*b.z + a.w*b.w;
}

typedef const __attribute__((address_space(1))) unsigned int* gp_t;
typedef __attribute__((address_space(3))) unsigned int* lp_t;
__device__ __forceinline__ void gload16u(const ushort* g, ushort* l) {
  __builtin_amdgcn_global_load_lds((gp_t)g, (lp_t)l, 16, 0, 0);
}

typedef short s16x8 __attribute__((ext_vector_type(8)));
typedef float f32x4 __attribute__((ext_vector_type(4)));

__device__ __forceinline__ void bf16split(float f, ushort& h, ushort& l) {
  const unsigned u = __float_as_uint(f);
  h = (ushort)((u + 0x7fffu + ((u>>16)&1u)) >> 16);
  const float res = f - __uint_as_float((unsigned)h << 16);
  const unsigned u2 = __float_as_uint(res);
  l = (ushort)((u2 + 0x7fffu + ((u2>>16)&1u)) >> 16);
}
__device__ __forceinline__ ushort bf16rne(float f) {
  const unsigned u = __float_as_uint(f);
  return (ushort)((u + 0x7fffu + ((u>>16)&1u)) >> 16);
}
__device__ __forceinline__ float bf2f(ushort u) {
  return __uint_as_float((unsigned)u << 16);
}
// XOR swizzle within a 64-elem bf16 row (8-elem granules): 2-way max bank alias
__device__ __forceinline__ int swzi(int row, int col) {
  return (col & 7) | ((((col >> 3) ^ (row & 7)) & 7) << 3);
}

// ---------------- Kernel 1: Gram + norms + bf16 emission (fused in staging regs) ----
// R17: bf16 emission moved INTO the staging loop (the float4 is already in
// registers) — second LDS-read pass deleted. Outputs byte-identical.
__global__ __launch_bounds__(256) void gram_conv_kernel(
    const float* __restrict__ imgs, const float* __restrict__ caps,
    float* __restrict__ gI, float* __restrict__ nI,
    float* __restrict__ gC, float* __restrict__ nC,
    ushort* __restrict__ aHi,
    ushort* __restrict__ bHi, ushort* __restrict__ bLo,
    ushort* __restrict__ gIb, ushort* __restrict__ gCb)
{
  __shared__ __align__(16) float L[LN*132];
  const int b = blockIdx.x, tid = threadIdx.x;
  if (b < INN) {
    const float* base = imgs + (size_t)b*RN*DN;
    const int rg = tid/12, cg = tid - (tid/12)*12;
    const bool active = tid < 216;
    float a[2][3];
    #pragma unroll
    for (int u = 0; u < 2; ++u)
      #pragma unroll
      for (int v = 0; v < 3; ++v) a[u][v] = 0.f;
    for (int d0 = 0; d0 < DN; d0 += 128) {
      __syncthreads();
      for (int idx = tid; idx < RN*32; idx += 256) {
        const int row = idx >> 5, ch = idx & 31;
        const float4 v = *(const float4*)(base + row*DN + d0 + ch*4);
        *(float4*)&L[row*132 + ch*4] = v;
        const float fv[4] = {v.x,v.y,v.z,v.w};
        ushort hh[4], ll[4];
        #pragma unroll
        for (int e = 0; e < 4; ++e) bf16split(fv[e], hh[e], ll[e]);
        const size_t off = (size_t)(b*RN + row)*DN + d0 + ch*4;
        *(ushort4*)(bHi + off) = make_ushort4(hh[0],hh[1],hh[2],hh[3]);
        *(ushort4*)(bLo + off) = make_ushort4(ll[0],ll[1],ll[2],ll[3]);
      }
      __syncthreads();
      if (active) {
        const float* r0 = &L[(2*rg)*132],   * r1 = &L[(2*rg+1)*132];
        const float* c0 = &L[(3*cg)*132],   * c1 = &L[(3*cg+1)*132], * c2 = &L[(3*cg+2)*132];
        #pragma unroll
        for (int k = 0; k < 32; ++k) {
          const float4 x0 = *(const float4*)(r0 + k*4);
          const float4 x1 = *(const float4*)(r1 + k*4);
          const float4 y0 = *(const float4*)(c0 + k*4);
          const float4 y1 = *(const float4*)(c1 + k*4);
          const float4 y2 = *(const float4*)(c2 + k*4);
          a[0][0] += dot4(x0,y0); a[0][1] += dot4(x0,y1); a[0][2] += dot4(x0,y2);
          a[1][0] += dot4(x1,y0); a[1][1] += dot4(x1,y1); a[1][2] += dot4(x1,y2);
        }
      }
    }
    if (active) {
      float* gb = gI + (size_t)b*RN*RN;
      #pragma unroll
      for (int u = 0; u < 2; ++u)
        #pragma unroll
        for (int v = 0; v < 3; ++v) {
          const int r = 2*rg + u, s = 3*cg + v;
          gb[r*RN + s] = a[u][v];
          if (r == s) nI[b*RN + r] = sqrtf(fmaxf(a[u][v], 1e-16f));
        }
    }
    __threadfence_block();
    __syncthreads();
    const float* gsrc = gI + (size_t)b*RN*RN;
    ushort* gdst = gIb + (size_t)b*3072;
    for (int idx = tid; idx < 3072; idx += 256) {
      const int row = idx >> 6, col = idx & 63;
      gdst[idx] = (row < RN && col < RN) ? bf16rne(gsrc[row*RN + col]) : (ushort)0;
    }
  } else {
    const int c = b - INN;
    const float* base = caps + (size_t)c*LN*DN;
    const int rg = tid >> 4, cg = tid & 15;
    float a[3][3];
    #pragma unroll
    for (int u = 0; u < 3; ++u)
      #pragma unroll
      for (int v = 0; v < 3; ++v) a[u][v] = 0.f;
    for (int d0 = 0; d0 < DN; d0 += 128) {
      __syncthreads();
      for (int idx = tid; idx < LN*32; idx += 256) {
        const int row = idx >> 5, ch = idx & 31;
        const float4 v = *(const float4*)(base + row*DN + d0 + ch*4);
        *(float4*)&L[row*132 + ch*4] = v;
        const size_t off = (size_t)(c*LN + row)*DN + d0 + ch*4;
        *(ushort4*)(aHi + off) = make_ushort4(
            bf16rne(v.x), bf16rne(v.y), bf16rne(v.z), bf16rne(v.w));
      }
      __syncthreads();
      const float* r0 = &L[(3*rg)*132],   * r1 = &L[(3*rg+1)*132], * r2 = &L[(3*rg+2)*132];
      const float* c0 = &L[(3*cg)*132],   * c1 = &L[(3*cg+1)*132], * c2 = &L[(3*cg+2)*132];
      #pragma unroll
      for (int k = 0; k < 32; ++k) {
        const float4 x0 = *(const float4*)(r0 + k*4);
        const float4 x1 = *(const float4*)(r1 + k*4);
        const float4 x2 = *(const float4*)(r2 + k*4);
        const float4 y0 = *(const float4*)(c0 + k*4);
        const float4 y1 = *(const float4*)(c1 + k*4);
        const float4 y2 = *(const float4*)(c2 + k*4);
        a[0][0] += dot4(x0,y0); a[0][1] += dot4(x0,y1); a[0][2] += dot4(x0,y2);
        a[1][0] += dot4(x1,y0); a[1][1] += dot4(x1,y1); a[1][2] += dot4(x1,y2);
        a[2][0] += dot4(x2,y0); a[2][1] += dot4(x2,y1); a[2][2] += dot4(x2,y2);
      }
    }
    float* gb = gC + (size_t)c*LN*LN;
    #pragma unroll
    for (int u = 0; u < 3; ++u)
      #pragma unroll
      for (int v = 0; v < 3; ++v) {
        const int r = 3*rg + u, s = 3*cg + v;
        gb[r*LN + s] = a[u][v];
        if (r == s) nC[c*LN + r] = sqrtf(fmaxf(a[u][v], 1e-16f));
      }
    __threadfence_block();
    __syncthreads();
    const float* gsrc = gC + (size_t)c*LN*LN;
    ushort* gdst = gCb + (size_t)c*3072;
    for (int idx = tid; idx < 3072; idx += 256) {
      const int row = idx >> 6, col = idx & 63;
      gdst[idx] = (col < LN) ? bf16rne(gsrc[row*LN + col]) : (ushort)0;
    }
  }
}

// ---------------- Kernel 2: dots GEMM via bf16x2 MFMA (unchanged) ----------------
__global__ __launch_bounds__(256) void dots_gemm_mfma(
    const ushort* __restrict__ aHi,
    const ushort* __restrict__ bHi, const ushort* __restrict__ bLo,
    float* __restrict__ dots, int arow0)
{
  __shared__ __align__(16) ushort sT[12288];
  const int tid = threadIdx.x;
  const int wv = tid >> 6, lane = tid & 63;
  const int l15 = lane & 15, kg = lane >> 4;
  const int wr = wv >> 1, wc = wv & 1;
  const int M0 = blockIdx.y * 128;
  const int N0 = blockIdx.x * 128;

  int offA[4], offB[4];
  #pragma unroll
  for (int f = 0; f < 4; ++f) {
    const int rA = wr*64 + f*16 + l15;
    offA[f] = rA*32 + ((kg ^ ((rA>>1)&3)) << 3);
    const int rB = wc*64 + f*16 + l15;
    offB[f] = rB*32 + ((kg ^ ((rB>>1)&3)) << 3);
  }
  int srow[2], sgk[2]; unsigned dOff[2];
  #pragma unroll
  for (int h = 0; h < 2; ++h) {
    const int ch = h*256 + wv*64 + lane;
    const int row = ch >> 2, gp = ch & 3;
    srow[h] = row;
    sgk[h] = (gp ^ ((row>>1)&3)) * 8;
    dOff[h] = (unsigned)(h*256 + wv*64) * 8;
  }

  f32x4 acc[4][4];
  #pragma unroll
  for (int mf = 0; mf < 4; ++mf)
    #pragma unroll
    for (int nf = 0; nf < 4; ++nf) acc[mf][nf] = (f32x4){0.f,0.f,0.f,0.f};

  const size_t aR = (size_t)(arow0 + M0);
  for (int k0 = 0; k0 < DN; k0 += 32) {
    __syncthreads();
    #pragma unroll
    for (int h = 0; h < 2; ++h) {
      const size_t ao = (aR + srow[h])*DN + k0 + sgk[h];
      const size_t bo = ((size_t)(N0 + srow[h]))*DN + k0 + sgk[h];
      gload16u(aHi + ao, sT + dOff[h]);
      gload16u(bHi + bo, sT + 4096 + dOff[h]);
      gload16u(bLo + bo, sT + 8192 + dOff[h]);
    }
    asm volatile("s_waitcnt vmcnt(0)" ::: "memory");
    __syncthreads();
    s16x8 ah[4], bh[4], bl[4];
    #pragma unroll
    for (int f = 0; f < 4; ++f) {
      ah[f] = *(const s16x8*)&sT[offA[f]];
      bh[f] = *(const s16x8*)&sT[4096 + offB[f]];
      bl[f] = *(const s16x8*)&sT[8192 + offB[f]];
    }
    #pragma unroll
    for (int mf = 0; mf < 4; ++mf)
      #pragma unroll
      for (int nf = 0; nf < 4; ++nf) {
        acc[mf][nf] = __builtin_amdgcn_mfma_f32_16x16x32_bf16(ah[mf], bh[nf], acc[mf][nf], 0,0,0);
        acc[mf][nf] = __builtin_amdgcn_mfma_f32_16x16x32_bf16(ah[mf], bl[nf], acc[mf][nf], 0,0,0);
      }
  }
  #pragma unroll
  for (int mf = 0; mf < 4; ++mf)
    #pragma unroll
    for (int nf = 0; nf < 4; ++nf) {
      const int n = N0 + wc*64 + nf*16 + l15;
      #pragma unroll
      for (int r = 0; r < 4; ++r) {
        const int m = M0 + wr*64 + mf*16 + kg*4 + r;
        dots[(size_t)m*NT + n] = acc[mf][nf][r];
      }
    }
}

// ---------------- Kernel 3: attention (exact R15 version, 256 threads) ----------------
// R16 lesson: 384-thread single-pass restructure regressed (occupancy flat,
// conflicts +38%). This is the known-good R15 shape.
__global__ __launch_bounds__(256) void attn_kernel(
    const float* __restrict__ dots, const int* __restrict__ cap_lens,
    const ushort* __restrict__ gIb, const ushort* __restrict__ gCb,
    const float* __restrict__ nI, const float* __restrict__ nC,
    float* __restrict__ scores, int cbase)
{
  __shared__ float sDots[LN][RTA+1];                  // 48 x 37
  __shared__ __align__(16) ushort sMeT[LN*64];        // A: [l][r] swizzled
  __shared__ __align__(16) ushort sMeIT[48*64];       // B: [r][l] swizzled
  __shared__ __align__(16) ushort sGcA[LN*64];        // A: [l][m] swizzled
  __shared__ __align__(16) ushort sGiB[48*64];        // B: [s][r] swizzled (symmetric)
  __shared__ float sQqT[LN], sQqI[48];
  __shared__ float sW12t[LN], sInvT[LN];
  __shared__ float sW12i[RN], sInvI[RN];
  __shared__ float sColInv[RN], sRowInv[LN];
  __shared__ float sCapN[LN], sImgN[RN];
  __shared__ float sEt[LN], sEi[RN];

  const int cl = blockIdx.y;
  const int c  = cbase + cl;
  const int it = blockIdx.x;
  const int tid = threadIdx.x;
  const int lane = tid & 63, wv = tid >> 6;
  const int l15 = lane & 15, kg = lane >> 4;
  const int nw = cap_lens[c];
  const float nwf = (float)nw;

  // ---- Phase A: stage ----
  for (int idx = tid; idx < LN*RTA/4; idx += 256) {
    const int l = idx / (RTA/4), jseg = idx - l*(RTA/4);
    const float4 v = *(const float4*)(dots + ((size_t)cl*LN + l)*NT + (size_t)it*RTA + jseg*4);
    float* dst = &sDots[l][jseg*4];
    dst[0]=v.x; dst[1]=v.y; dst[2]=v.z; dst[3]=v.w;
  }
  for (int idx = tid; idx < 768; idx += 256) {
    if (idx < 384) ((uint4*)sMeT)[idx] = make_uint4(0,0,0,0);
    else ((uint4*)sMeIT)[idx-384] = make_uint4(0,0,0,0);
  }
  for (int idx = tid; idx < 384; idx += 256) {
    const int row = idx >> 3, gk = idx & 7;
    *(uint4*)&sGcA[row*64 + (gk ^ (row&7))*8] =
      *(const uint4*)(gCb + (size_t)c*3072 + row*64 + gk*8);
  }
  for (int idx = tid; idx < 384; idx += 256) {
    const int row = idx >> 3, gk = idx & 7;
    *(uint4*)&sGiB[row*64 + (gk ^ (row&7))*8] =
      *(const uint4*)(gIb + (size_t)it*3072 + row*64 + gk*8);
  }
  if (tid < LN) { sCapN[tid] = nC[c*LN + tid]; sQqT[tid] = 0.f; }
  if (tid >= 64 && tid < 64+48) sQqI[tid-64] = 0.f;
  if (tid >= 128 && tid < 128+RN) sImgN[tid-128] = nI[it*RN + (tid-128)];
  __syncthreads();

  if (tid < RN) {
    float s = 0.f;
    for (int l = 0; l < LN; ++l) { const float v = leaky(sDots[l][tid]); s += v*v; }
    sColInv[tid] = LSM * __builtin_amdgcn_rcpf(sqrtf(s) + EPSF);
  }
  if (tid >= 64 && tid < 64+LN) {
    const int l = tid - 64;
    float s = 0.f;
    for (int r = 0; r < RN; ++r) { const float v = leaky(sDots[l][r]); s += v*v; }
    sRowInv[l] = LSM * __builtin_amdgcn_rcpf(sqrtf(s) + EPSF);
  }
  __syncthreads();

  // ---- Phase B: me rows (one row per 4-lane team; R8: do NOT re-batch) ----
  const int team = tid >> 2, q4 = tid & 3;
  #pragma unroll 1
  for (int pass = 0; pass < 2; ++pass) {
    const int vrow = pass*64 + team;
    if (vrow < LN) {
      const int l = vrow;
      const int cb = q4*9;
      float d9[9], x9[9];
      #pragma unroll
      for (int j = 0; j < 9; ++j) d9[j] = sDots[l][cb + j];
      float se = 0.f;
      #pragma unroll
      for (int j = 0; j < 9; ++j) {
        const float e = __expf(leaky(d9[j]) * sColInv[cb + j]);
        x9[j] = e; se += e;
      }
      se += __shfl_xor(se, 1, 4); se += __shfl_xor(se, 2, 4);
      float ts = 0.f;
      #pragma unroll
      for (int j = 0; j < 9; ++j) {
        const float me = (x9[j]*36.f > se) ? x9[j] : 0.f;
        x9[j] = me; ts += me;
      }
      ts += __shfl_xor(ts, 1, 4); ts += __shfl_xor(ts, 2, 4);
      float w12 = 0.f;
      #pragma unroll
      for (int j = 0; j < 9; ++j) w12 += x9[j]*d9[j];
      w12 += __shfl_xor(w12, 1, 4); w12 += __shfl_xor(w12, 2, 4);
      #pragma unroll
      for (int j = 0; j < 9; ++j)
        sMeT[l*64 + swzi(l, cb + j)] = bf16rne(x9[j]);
      if (q4 == 0) {
        sW12t[l] = w12;
        sInvT[l] = __builtin_amdgcn_rcpf((ts > 0.f) ? ts : 1.f);
      }
    } else {
      const int r = vrow - LN;
      if (r < RN) {
        float d12[12], x12[12];
        #pragma unroll
        for (int j = 0; j < 12; ++j) d12[j] = sDots[q4*12+j][r];
        float se = 0.f;
        #pragma unroll
        for (int j = 0; j < 12; ++j) {
          const int l = q4*12 + j;
          const float e = (l < nw) ? __expf(leaky(d12[j]) * sRowInv[l]) : 0.f;
          x12[j] = e; se += e;
        }
        se += __shfl_xor(se, 1, 4); se += __shfl_xor(se, 2, 4);
        float ts = 0.f;
        #pragma unroll
        for (int j = 0; j < 12; ++j) {
          const float me = (x12[j]*nwf > se) ? x12[j] : 0.f;
          x12[j] = me; ts += me;
        }
        ts += __shfl_xor(ts, 1, 4); ts += __shfl_xor(ts, 2, 4);
        float w12 = 0.f;
        #pragma unroll
        for (int j = 0; j < 12; ++j) w12 += x12[j]*d12[j];
        w12 += __shfl_xor(w12, 1, 4); w12 += __shfl_xor(w12, 2, 4);
        #pragma unroll
        for (int j = 0; j < 12; ++j)
          sMeIT[r*64 + swzi(r, q4*12 + j)] = bf16rne(x12[j]);
        if (q4 == 0) {
          sW12i[r] = w12;
          sInvI[r] = __builtin_amdgcn_rcpf((ts > 0.f) ? ts : 1.f);
        }
      }
    }
  }
  __syncthreads();

  // ---- Phase C: qq via MFMA (18 tiles: 9 t2i + 9 i2t) ----
  #pragma unroll 1
  for (int t = wv; t < 18; t += 4) {
    const bool isT = (t < 9);
    const int tt = isT ? t : t - 9;
    const int mt = tt / 3, nt = tt - 3*(tt/3);
    const ushort* Ab = isT ? sMeT : sGcA;
    const ushort* Bb = isT ? sGiB : sMeIT;
    const int arow = mt*16 + l15;
    const int brow = nt*16 + l15;
    f32x4 acc = (f32x4){0.f,0.f,0.f,0.f};
    #pragma unroll
    for (int ks = 0; ks < 2; ++ks) {
      const s16x8 af = *(const s16x8*)&Ab[arow*64 + (((ks*4+kg) ^ (arow&7)))*8];
      const s16x8 bf = *(const s16x8*)&Bb[brow*64 + (((ks*4+kg) ^ (brow&7)))*8];
      acc = __builtin_amdgcn_mfma_f32_16x16x32_bf16(af, bf, acc, 0,0,0);
    }
    if (isT) {
      float part[4];
      #pragma unroll
      for (int rg = 0; rg < 4; ++rg) {
        const int l = mt*16 + kg*4 + rg, s = nt*16 + l15;
        part[rg] = acc[rg] * bf2f(sMeT[l*64 + swzi(l, s)]);
      }
      #pragma unroll
      for (int o = 1; o < 16; o <<= 1)
        #pragma unroll
        for (int rg = 0; rg < 4; ++rg) part[rg] += __shfl_xor(part[rg], o, 16);
      if (l15 == 0)
        #pragma unroll
        for (int rg = 0; rg < 4; ++rg)
          atomicAdd(&sQqT[mt*16 + kg*4 + rg], part[rg]);
    } else {
      float part = 0.f;
      #pragma unroll
      for (int rg = 0; rg < 4; ++rg) {
        const int l = mt*16 + kg*4 + rg, r = nt*16 + l15;
        part += acc[rg] * bf2f(sMeIT[r*64 + swzi(r, l)]);
      }
      part += __shfl_xor(part, 16);
      part += __shfl_xor(part, 32);
      if (lane < 16) atomicAdd(&sQqI[nt*16 + l15], part);
    }
  }
  __syncthreads();

  // ---- Epilogue ----
  if (tid < LN) {
    const float invd = sInvT[tid];
    const float w2 = sqrtf(fmaxf(sQqT[tid]*invd*invd, 1e-16f));
    const float sim = (sW12t[tid]*invd) * __builtin_amdgcn_rcpf(fmaxf(sCapN[tid]*w2, EPSF));
    sEt[tid] = (tid < nw) ? __expf(LLSE*sim) : 0.f;
  }
  if (tid >= 64 && tid < 64+RN) {
    const int r = tid - 64;
    const float invd = sInvI[r];
    const float w2 = sqrtf(fmaxf(sQqI[r]*invd*invd, 1e-16f));
    const float sim = (sW12i[r]*invd) * __builtin_amdgcn_rcpf(fmaxf(sImgN[r]*w2, EPSF));
    sEi[r] = __expf(LLSE*sim);
  }
  __syncthreads();
  if (tid == 0) {
    float st = 0.f, si2 = 0.f;
    for (int l = 0; l < LN; ++l) st += sEt[l];
    for (int r = 0; r < RN; ++r) si2 += sEi[r];
    scores[(size_t)it*CN + c] = __logf(st)/LLSE + __logf(si2)/LLSE;
  }
}

// ---------------- Kernel 4: margin ranking loss ----------------
__global__ __launch_bounds__(128) void loss_kernel(
    const float* __restrict__ S, float* __restrict__ out)
{
  __shared__ float red[128];
  const int t = threadIdx.x;
  const float d = S[t*CN + t];
  float m1 = -1e30f, m2 = -1e30f;
  for (int cc = 0; cc < CN; ++cc)
    if (cc != t) m1 = fmaxf(m1, 0.2f + S[t*CN+cc] - d);
  for (int i2 = 0; i2 < INN; ++i2)
    if (i2 != t) m2 = fmaxf(m2, 0.2f + S[i2*CN+t] - d);
  red[t] = fmaxf(m1, 0.f) + fmaxf(m2, 0.f);
  __syncthreads();
  for (int s = 64; s > 0; s >>= 1) {
    if (t < s) red[t] += red[t+s];
    __syncthreads();
  }
  if (t == 0) out[0] = red[0];
}

extern "C" void kernel_launch(void* const* d_in, const int* in_sizes, int n_in,
                              void* d_out, int out_size, void* d_ws, size_t ws_size,
                              hipStream_t stream) {
  (void)in_sizes; (void)n_in; (void)out_size;
  const float* imgs = (const float*)d_in[0];
  const float* caps = (const float*)d_in[1];
  const int*   lens = (const int*)d_in[2];

  const size_t bfUS = 2*((size_t)MT + NT)*DN;
  const size_t gbUS = (size_t)(INN + CN)*3072;
  const size_t smallF = (size_t)INN*RN*RN + INN*RN + (size_t)CN*LN*LN + CN*LN + (size_t)INN*CN;
  int g = CN;
  while (g > 8) {
    const size_t need = (bfUS + gbUS)*2 + (smallF + (size_t)g*LN*NT)*4;
    if (need <= ws_size) break;
    g >>= 1;
  }

  ushort* aHi = (ushort*)d_ws;
  ushort* aLo = aHi + (size_t)MT*DN;   // unused slot (layout stability)
  ushort* bHi = aLo + (size_t)MT*DN;
  ushort* bLo = bHi + (size_t)NT*DN;
  ushort* gIb = bLo + (size_t)NT*DN;
  ushort* gCb = gIb + (size_t)INN*3072;
  float* fbase = (float*)(gCb + (size_t)CN*3072);
  float* gI     = fbase;
  float* nI     = gI + (size_t)INN*RN*RN;
  float* gC     = nI + (size_t)INN*RN;
  float* nC     = gC + (size_t)CN*LN*LN;
  float* scores = nC + (size_t)CN*LN;
  float* dots   = scores + (size_t)INN*CN;

  gram_conv_kernel<<<dim3(INN+CN), dim3(256), 0, stream>>>(
      imgs, caps, gI, nI, gC, nC, aHi, bHi, bLo, gIb, gCb);
  for (int c0 = 0; c0 < CN; c0 += g) {
    dots_gemm_mfma<<<dim3(NT/128, g*LN/128), dim3(256), 0, stream>>>(
        aHi, bHi, bLo, dots, c0*LN);
    attn_kernel<<<dim3(INN, g), dim3(256), 0, stream>>>(
        dots, lens, gIb, gCb, nI, nC, scores, c0);
  }
  loss_kernel<<<dim3(1), dim3(128), 0, stream>>>(scores, (float*)d_out);
}

// Round 18
// 373.193 us; speedup vs baseline: 1.0519x; 1.0009x over previous
//
#include <hip/hip_runtime.h>
#include <math.h>

#define CN 128   // captions
#define INN 128  // images
#define LN 48    // words
#define RN 36    // regions
#define DN 1024  // feature dim
#define RTA 36   // regions per attn block (TIA=1)
#define MT 6144  // CN*LN
#define NT 4608  // INN*RN
#define EPSF 1e-8f
#define LSM 9.0f
#define LLSE 6.0f

__device__ __forceinline__ float leaky(float x){ return x > 0.f ? x : 0.1f*x; }
__device__ __forceinline__ float dot4(float4 a, float4 b){
  return a.x*b.x + a.y*b.y + a.z*b.z + a.w*b.w;
}

typedef const __attribute__((address_space(1))) unsigned int* gp_t;
typedef __attribute__((address_space(3))) unsigned int* lp_t;
__device__ __forceinline__ void gload16u(const ushort* g, ushort* l) {
  __builtin_amdgcn_global_load_lds((gp_t)g, (lp_t)l, 16, 0, 0);
}

typedef short s16x8 __attribute__((ext_vector_type(8)));
typedef float f32x4 __attribute__((ext_vector_type(4)));

__device__ __forceinline__ void bf16split(float f, ushort& h, ushort& l) {
  const unsigned u = __float_as_uint(f);
  h = (ushort)((u + 0x7fffu + ((u>>16)&1u)) >> 16);
  const float res = f - __uint_as_float((unsigned)h << 16);
  const unsigned u2 = __float_as_uint(res);
  l = (ushort)((u2 + 0x7fffu + ((u2>>16)&1u)) >> 16);
}
__device__ __forceinline__ ushort bf16rne(float f) {
  const unsigned u = __float_as_uint(f);
  return (ushort)((u + 0x7fffu + ((u>>16)&1u)) >> 16);
}
__device__ __forceinline__ float bf2f(ushort u) {
  return __uint_as_float((unsigned)u << 16);
}
// XOR swizzle within a 64-elem bf16 row (8-elem granules): 2-way max bank alias
__device__ __forceinline__ int swzi(int row, int col) {
  return (col & 7) | ((((col >> 3) ^ (row & 7)) & 7) << 3);
}

// ---------------- Kernel 1: Gram + norms + bf16 emission (fused in staging regs) ----
__global__ __launch_bounds__(256) void gram_conv_kernel(
    const float* __restrict__ imgs, const float* __restrict__ caps,
    float* __restrict__ gI, float* __restrict__ nI,
    float* __restrict__ gC, float* __restrict__ nC,
    ushort* __restrict__ aHi,
    ushort* __restrict__ bHi, ushort* __restrict__ bLo,
    ushort* __restrict__ gIb, ushort* __restrict__ gCb)
{
  __shared__ __align__(16) float L[LN*132];
  const int b = blockIdx.x, tid = threadIdx.x;
  if (b < INN) {
    const float* base = imgs + (size_t)b*RN*DN;
    const int rg = tid/12, cg = tid - (tid/12)*12;
    const bool active = tid < 216;
    float a[2][3];
    #pragma unroll
    for (int u = 0; u < 2; ++u)
      #pragma unroll
      for (int v = 0; v < 3; ++v) a[u][v] = 0.f;
    for (int d0 = 0; d0 < DN; d0 += 128) {
      __syncthreads();
      for (int idx = tid; idx < RN*32; idx += 256) {
        const int row = idx >> 5, ch = idx & 31;
        const float4 v = *(const float4*)(base + row*DN + d0 + ch*4);
        *(float4*)&L[row*132 + ch*4] = v;
        const float fv[4] = {v.x,v.y,v.z,v.w};
        ushort hh[4], ll[4];
        #pragma unroll
        for (int e = 0; e < 4; ++e) bf16split(fv[e], hh[e], ll[e]);
        const size_t off = (size_t)(b*RN + row)*DN + d0 + ch*4;
        *(ushort4*)(bHi + off) = make_ushort4(hh[0],hh[1],hh[2],hh[3]);
        *(ushort4*)(bLo + off) = make_ushort4(ll[0],ll[1],ll[2],ll[3]);
      }
      __syncthreads();
      if (active) {
        const float* r0 = &L[(2*rg)*132],   * r1 = &L[(2*rg+1)*132];
        const float* c0 = &L[(3*cg)*132],   * c1 = &L[(3*cg+1)*132], * c2 = &L[(3*cg+2)*132];
        #pragma unroll
        for (int k = 0; k < 32; ++k) {
          const float4 x0 = *(const float4*)(r0 + k*4);
          const float4 x1 = *(const float4*)(r1 + k*4);
          const float4 y0 = *(const float4*)(c0 + k*4);
          const float4 y1 = *(const float4*)(c1 + k*4);
          const float4 y2 = *(const float4*)(c2 + k*4);
          a[0][0] += dot4(x0,y0); a[0][1] += dot4(x0,y1); a[0][2] += dot4(x0,y2);
          a[1][0] += dot4(x1,y0); a[1][1] += dot4(x1,y1); a[1][2] += dot4(x1,y2);
        }
      }
    }
    if (active) {
      float* gb = gI + (size_t)b*RN*RN;
      #pragma unroll
      for (int u = 0; u < 2; ++u)
        #pragma unroll
        for (int v = 0; v < 3; ++v) {
          const int r = 2*rg + u, s = 3*cg + v;
          gb[r*RN + s] = a[u][v];
          if (r == s) nI[b*RN + r] = sqrtf(fmaxf(a[u][v], 1e-16f));
        }
    }
    __threadfence_block();
    __syncthreads();
    const float* gsrc = gI + (size_t)b*RN*RN;
    ushort* gdst = gIb + (size_t)b*3072;
    for (int idx = tid; idx < 3072; idx += 256) {
      const int row = idx >> 6, col = idx & 63;
      gdst[idx] = (row < RN && col < RN) ? bf16rne(gsrc[row*RN + col]) : (ushort)0;
    }
  } else {
    const int c = b - INN;
    const float* base = caps + (size_t)c*LN*DN;
    const int rg = tid >> 4, cg = tid & 15;
    float a[3][3];
    #pragma unroll
    for (int u = 0; u < 3; ++u)
      #pragma unroll
      for (int v = 0; v < 3; ++v) a[u][v] = 0.f;
    for (int d0 = 0; d0 < DN; d0 += 128) {
      __syncthreads();
      for (int idx = tid; idx < LN*32; idx += 256) {
        const int row = idx >> 5, ch = idx & 31;
        const float4 v = *(const float4*)(base + row*DN + d0 + ch*4);
        *(float4*)&L[row*132 + ch*4] = v;
        const size_t off = (size_t)(c*LN + row)*DN + d0 + ch*4;
        *(ushort4*)(aHi + off) = make_ushort4(
            bf16rne(v.x), bf16rne(v.y), bf16rne(v.z), bf16rne(v.w));
      }
      __syncthreads();
      const float* r0 = &L[(3*rg)*132],   * r1 = &L[(3*rg+1)*132], * r2 = &L[(3*rg+2)*132];
      const float* c0 = &L[(3*cg)*132],   * c1 = &L[(3*cg+1)*132], * c2 = &L[(3*cg+2)*132];
      #pragma unroll
      for (int k = 0; k < 32; ++k) {
        const float4 x0 = *(const float4*)(r0 + k*4);
        const float4 x1 = *(const float4*)(r1 + k*4);
        const float4 x2 = *(const float4*)(r2 + k*4);
        const float4 y0 = *(const float4*)(c0 + k*4);
        const float4 y1 = *(const float4*)(c1 + k*4);
        const float4 y2 = *(const float4*)(c2 + k*4);
        a[0][0] += dot4(x0,y0); a[0][1] += dot4(x0,y1); a[0][2] += dot4(x0,y2);
        a[1][0] += dot4(x1,y0); a[1][1] += dot4(x1,y1); a[1][2] += dot4(x1,y2);
        a[2][0] += dot4(x2,y0); a[2][1] += dot4(x2,y1); a[2][2] += dot4(x2,y2);
      }
    }
    float* gb = gC + (size_t)c*LN*LN;
    #pragma unroll
    for (int u = 0; u < 3; ++u)
      #pragma unroll
      for (int v = 0; v < 3; ++v) {
        const int r = 3*rg + u, s = 3*cg + v;
        gb[r*LN + s] = a[u][v];
        if (r == s) nC[c*LN + r] = sqrtf(fmaxf(a[u][v], 1e-16f));
      }
    __threadfence_block();
    __syncthreads();
    const float* gsrc = gC + (size_t)c*LN*LN;
    ushort* gdst = gCb + (size_t)c*3072;
    for (int idx = tid; idx < 3072; idx += 256) {
      const int row = idx >> 6, col = idx & 63;
      gdst[idx] = (col < LN) ? bf16rne(gsrc[row*LN + col]) : (ushort)0;
    }
  }
}

// ---------------- Kernel 2: dots GEMM via bf16x2 MFMA (unchanged) ----------------
__global__ __launch_bounds__(256) void dots_gemm_mfma(
    const ushort* __restrict__ aHi,
    const ushort* __restrict__ bHi, const ushort* __restrict__ bLo,
    float* __restrict__ dots, int arow0)
{
  __shared__ __align__(16) ushort sT[12288];
  const int tid = threadIdx.x;
  const int wv = tid >> 6, lane = tid & 63;
  const int l15 = lane & 15, kg = lane >> 4;
  const int wr = wv >> 1, wc = wv & 1;
  const int M0 = blockIdx.y * 128;
  const int N0 = blockIdx.x * 128;

  int offA[4], offB[4];
  #pragma unroll
  for (int f = 0; f < 4; ++f) {
    const int rA = wr*64 + f*16 + l15;
    offA[f] = rA*32 + ((kg ^ ((rA>>1)&3)) << 3);
    const int rB = wc*64 + f*16 + l15;
    offB[f] = rB*32 + ((kg ^ ((rB>>1)&3)) << 3);
  }
  int srow[2], sgk[2]; unsigned dOff[2];
  #pragma unroll
  for (int h = 0; h < 2; ++h) {
    const int ch = h*256 + wv*64 + lane;
    const int row = ch >> 2, gp = ch & 3;
    srow[h] = row;
    sgk[h] = (gp ^ ((row>>1)&3)) * 8;
    dOff[h] = (unsigned)(h*256 + wv*64) * 8;
  }

  f32x4 acc[4][4];
  #pragma unroll
  for (int mf = 0; mf < 4; ++mf)
    #pragma unroll
    for (int nf = 0; nf < 4; ++nf) acc[mf][nf] = (f32x4){0.f,0.f,0.f,0.f};

  const size_t aR = (size_t)(arow0 + M0);
  for (int k0 = 0; k0 < DN; k0 += 32) {
    __syncthreads();
    #pragma unroll
    for (int h = 0; h < 2; ++h) {
      const size_t ao = (aR + srow[h])*DN + k0 + sgk[h];
      const size_t bo = ((size_t)(N0 + srow[h]))*DN + k0 + sgk[h];
      gload16u(aHi + ao, sT + dOff[h]);
      gload16u(bHi + bo, sT + 4096 + dOff[h]);
      gload16u(bLo + bo, sT + 8192 + dOff[h]);
    }
    asm volatile("s_waitcnt vmcnt(0)" ::: "memory");
    __syncthreads();
    s16x8 ah[4], bh[4], bl[4];
    #pragma unroll
    for (int f = 0; f < 4; ++f) {
      ah[f] = *(const s16x8*)&sT[offA[f]];
      bh[f] = *(const s16x8*)&sT[4096 + offB[f]];
      bl[f] = *(const s16x8*)&sT[8192 + offB[f]];
    }
    #pragma unroll
    for (int mf = 0; mf < 4; ++mf)
      #pragma unroll
      for (int nf = 0; nf < 4; ++nf) {
        acc[mf][nf] = __builtin_amdgcn_mfma_f32_16x16x32_bf16(ah[mf], bh[nf], acc[mf][nf], 0,0,0);
        acc[mf][nf] = __builtin_amdgcn_mfma_f32_16x16x32_bf16(ah[mf], bl[nf], acc[mf][nf], 0,0,0);
      }
  }
  #pragma unroll
  for (int mf = 0; mf < 4; ++mf)
    #pragma unroll
    for (int nf = 0; nf < 4; ++nf) {
      const int n = N0 + wc*64 + nf*16 + l15;
      #pragma unroll
      for (int r = 0; r < 4; ++r) {
        const int m = M0 + wr*64 + mf*16 + kg*4 + r;
        dots[(size_t)m*NT + n] = acc[mf][nf][r];
      }
    }
}

// ---------------- Kernel 3: attention (R15 structure + parallel norms/epilogue) ----
// R18: team-parallel norms (two 64-team passes; Phase B untouched — R16's
// regression came from the single-pass Phase-B write pattern, not norms) and
// wave-butterfly epilogue with single fused log.
__global__ __launch_bounds__(256) void attn_kernel(
    const float* __restrict__ dots, const int* __restrict__ cap_lens,
    const ushort* __restrict__ gIb, const ushort* __restrict__ gCb,
    const float* __restrict__ nI, const float* __restrict__ nC,
    float* __restrict__ scores, int cbase)
{
  __shared__ float sDots[LN][RTA+1];                  // 48 x 37
  __shared__ __align__(16) ushort sMeT[LN*64];        // A: [l][r] swizzled
  __shared__ __align__(16) ushort sMeIT[48*64];       // B: [r][l] swizzled
  __shared__ __align__(16) ushort sGcA[LN*64];        // A: [l][m] swizzled
  __shared__ __align__(16) ushort sGiB[48*64];        // B: [s][r] swizzled (symmetric)
  __shared__ float sQqT[LN], sQqI[48];
  __shared__ float sW12t[LN], sInvT[LN];
  __shared__ float sW12i[RN], sInvI[RN];
  __shared__ float sColInv[RN], sRowInv[LN];
  __shared__ float sCapN[LN], sImgN[RN];
  __shared__ float sEt[LN], sEi[RN];
  __shared__ float sRed[2];

  const int cl = blockIdx.y;
  const int c  = cbase + cl;
  const int it = blockIdx.x;
  const int tid = threadIdx.x;
  const int lane = tid & 63, wv = tid >> 6;
  const int l15 = lane & 15, kg = lane >> 4;
  const int team = tid >> 2, q4 = tid & 3;
  const int nw = cap_lens[c];
  const float nwf = (float)nw;

  // ---- Phase A: stage ----
  for (int idx = tid; idx < LN*RTA/4; idx += 256) {
    const int l = idx / (RTA/4), jseg = idx - l*(RTA/4);
    const float4 v = *(const float4*)(dots + ((size_t)cl*LN + l)*NT + (size_t)it*RTA + jseg*4);
    float* dst = &sDots[l][jseg*4];
    dst[0]=v.x; dst[1]=v.y; dst[2]=v.z; dst[3]=v.w;
  }
  for (int idx = tid; idx < 768; idx += 256) {
    if (idx < 384) ((uint4*)sMeT)[idx] = make_uint4(0,0,0,0);
    else ((uint4*)sMeIT)[idx-384] = make_uint4(0,0,0,0);
  }
  for (int idx = tid; idx < 384; idx += 256) {
    const int row = idx >> 3, gk = idx & 7;
    *(uint4*)&sGcA[row*64 + (gk ^ (row&7))*8] =
      *(const uint4*)(gCb + (size_t)c*3072 + row*64 + gk*8);
  }
  for (int idx = tid; idx < 384; idx += 256) {
    const int row = idx >> 3, gk = idx & 7;
    *(uint4*)&sGiB[row*64 + (gk ^ (row&7))*8] =
      *(const uint4*)(gIb + (size_t)it*3072 + row*64 + gk*8);
  }
  if (tid < LN) { sCapN[tid] = nC[c*LN + tid]; sQqT[tid] = 0.f; }
  if (tid >= 64 && tid < 64+48) sQqI[tid-64] = 0.f;
  if (tid >= 128 && tid < 128+RN) sImgN[tid-128] = nI[it*RN + (tid-128)];
  __syncthreads();

  // ---- norms: team-parallel, two 64-team passes ----
  #pragma unroll 1
  for (int pass = 0; pass < 2; ++pass) {
    const int vrow = pass*64 + team;
    if (vrow < RN) {
      float s = 0.f;
      #pragma unroll
      for (int j = 0; j < 12; ++j) { const float v = leaky(sDots[q4*12+j][vrow]); s += v*v; }
      s += __shfl_xor(s, 1, 4); s += __shfl_xor(s, 2, 4);
      if (q4 == 0) sColInv[vrow] = LSM * __builtin_amdgcn_rcpf(sqrtf(s) + EPSF);
    } else if (vrow < RN + LN) {
      const int l = vrow - RN;
      float s = 0.f;
      #pragma unroll
      for (int j = 0; j < 9; ++j) { const float v = leaky(sDots[l][q4*9+j]); s += v*v; }
      s += __shfl_xor(s, 1, 4); s += __shfl_xor(s, 2, 4);
      if (q4 == 0) sRowInv[l] = LSM * __builtin_amdgcn_rcpf(sqrtf(s) + EPSF);
    }
  }
  __syncthreads();

  // ---- Phase B: me rows (one row per 4-lane team; R8: do NOT re-batch) ----
  #pragma unroll 1
  for (int pass = 0; pass < 2; ++pass) {
    const int vrow = pass*64 + team;
    if (vrow < LN) {
      const int l = vrow;
      const int cb = q4*9;
      float d9[9], x9[9];
      #pragma unroll
      for (int j = 0; j < 9; ++j) d9[j] = sDots[l][cb + j];
      float se = 0.f;
      #pragma unroll
      for (int j = 0; j < 9; ++j) {
        const float e = __expf(leaky(d9[j]) * sColInv[cb + j]);
        x9[j] = e; se += e;
      }
      se += __shfl_xor(se, 1, 4); se += __shfl_xor(se, 2, 4);
      float ts = 0.f;
      #pragma unroll
      for (int j = 0; j < 9; ++j) {
        const float me = (x9[j]*36.f > se) ? x9[j] : 0.f;
        x9[j] = me; ts += me;
      }
      ts += __shfl_xor(ts, 1, 4); ts += __shfl_xor(ts, 2, 4);
      float w12 = 0.f;
      #pragma unroll
      for (int j = 0; j < 9; ++j) w12 += x9[j]*d9[j];
      w12 += __shfl_xor(w12, 1, 4); w12 += __shfl_xor(w12, 2, 4);
      #pragma unroll
      for (int j = 0; j < 9; ++j)
        sMeT[l*64 + swzi(l, cb + j)] = bf16rne(x9[j]);
      if (q4 == 0) {
        sW12t[l] = w12;
        sInvT[l] = __builtin_amdgcn_rcpf((ts > 0.f) ? ts : 1.f);
      }
    } else {
      const int r = vrow - LN;
      if (r < RN) {
        float d12[12], x12[12];
        #pragma unroll
        for (int j = 0; j < 12; ++j) d12[j] = sDots[q4*12+j][r];
        float se = 0.f;
        #pragma unroll
        for (int j = 0; j < 12; ++j) {
          const int l = q4*12 + j;
          const float e = (l < nw) ? __expf(leaky(d12[j]) * sRowInv[l]) : 0.f;
          x12[j] = e; se += e;
        }
        se += __shfl_xor(se, 1, 4); se += __shfl_xor(se, 2, 4);
        float ts = 0.f;
        #pragma unroll
        for (int j = 0; j < 12; ++j) {
          const float me = (x12[j]*nwf > se) ? x12[j] : 0.f;
          x12[j] = me; ts += me;
        }
        ts += __shfl_xor(ts, 1, 4); ts += __shfl_xor(ts, 2, 4);
        float w12 = 0.f;
        #pragma unroll
        for (int j = 0; j < 12; ++j) w12 += x12[j]*d12[j];
        w12 += __shfl_xor(w12, 1, 4); w12 += __shfl_xor(w12, 2, 4);
        #pragma unroll
        for (int j = 0; j < 12; ++j)
          sMeIT[r*64 + swzi(r, q4*12 + j)] = bf16rne(x12[j]);
        if (q4 == 0) {
          sW12i[r] = w12;
          sInvI[r] = __builtin_amdgcn_rcpf((ts > 0.f) ? ts : 1.f);
        }
      }
    }
  }
  __syncthreads();

  // ---- Phase C: qq via MFMA (18 tiles: 9 t2i + 9 i2t) ----
  #pragma unroll 1
  for (int t = wv; t < 18; t += 4) {
    const bool isT = (t < 9);
    const int tt = isT ? t : t - 9;
    const int mt = tt / 3, nt = tt - 3*(tt/3);
    const ushort* Ab = isT ? sMeT : sGcA;
    const ushort* Bb = isT ? sGiB : sMeIT;
    const int arow = mt*16 + l15;
    const int brow = nt*16 + l15;
    f32x4 acc = (f32x4){0.f,0.f,0.f,0.f};
    #pragma unroll
    for (int ks = 0; ks < 2; ++ks) {
      const s16x8 af = *(const s16x8*)&Ab[arow*64 + (((ks*4+kg) ^ (arow&7)))*8];
      const s16x8 bf = *(const s16x8*)&Bb[brow*64 + (((ks*4+kg) ^ (brow&7)))*8];
      acc = __builtin_amdgcn_mfma_f32_16x16x32_bf16(af, bf, acc, 0,0,0);
    }
    if (isT) {
      float part[4];
      #pragma unroll
      for (int rg = 0; rg < 4; ++rg) {
        const int l = mt*16 + kg*4 + rg, s = nt*16 + l15;
        part[rg] = acc[rg] * bf2f(sMeT[l*64 + swzi(l, s)]);
      }
      #pragma unroll
      for (int o = 1; o < 16; o <<= 1)
        #pragma unroll
        for (int rg = 0; rg < 4; ++rg) part[rg] += __shfl_xor(part[rg], o, 16);
      if (l15 == 0)
        #pragma unroll
        for (int rg = 0; rg < 4; ++rg)
          atomicAdd(&sQqT[mt*16 + kg*4 + rg], part[rg]);
    } else {
      float part = 0.f;
      #pragma unroll
      for (int rg = 0; rg < 4; ++rg) {
        const int l = mt*16 + kg*4 + rg, r = nt*16 + l15;
        part += acc[rg] * bf2f(sMeIT[r*64 + swzi(r, l)]);
      }
      part += __shfl_xor(part, 16);
      part += __shfl_xor(part, 32);
      if (lane < 16) atomicAdd(&sQqI[nt*16 + l15], part);
    }
  }
  __syncthreads();

  // ---- Epilogue ----
  if (tid < LN) {
    const float invd = sInvT[tid];
    const float w2 = sqrtf(fmaxf(sQqT[tid]*invd*invd, 1e-16f));
    const float sim = (sW12t[tid]*invd) * __builtin_amdgcn_rcpf(fmaxf(sCapN[tid]*w2, EPSF));
    sEt[tid] = (tid < nw) ? __expf(LLSE*sim) : 0.f;
  }
  if (tid >= 64 && tid < 64+RN) {
    const int r = tid - 64;
    const float invd = sInvI[r];
    const float w2 = sqrtf(fmaxf(sQqI[r]*invd*invd, 1e-16f));
    const float sim = (sW12i[r]*invd) * __builtin_amdgcn_rcpf(fmaxf(sImgN[r]*w2, EPSF));
    sEi[r] = __expf(LLSE*sim);
  }
  __syncthreads();
  if (wv == 0) {
    float e = (lane < LN) ? sEt[lane] : 0.f;
    #pragma unroll
    for (int o = 32; o > 0; o >>= 1) e += __shfl_xor(e, o);
    if (lane == 0) sRed[0] = e;
  } else if (wv == 1) {
    float e = (lane < RN) ? sEi[lane] : 0.f;
    #pragma unroll
    for (int o = 32; o > 0; o >>= 1) e += __shfl_xor(e, o);
    if (lane == 0) sRed[1] = e;
  }
  __syncthreads();
  if (tid == 0)
    scores[(size_t)it*CN + c] = __logf(sRed[0]*sRed[1])/LLSE;
}

// ---------------- Kernel 4: margin ranking loss ----------------
__global__ __launch_bounds__(128) void loss_kernel(
    const float* __restrict__ S, float* __restrict__ out)
{
  __shared__ float red[128];
  const int t = threadIdx.x;
  const float d = S[t*CN + t];
  float m1 = -1e30f, m2 = -1e30f;
  for (int cc = 0; cc < CN; ++cc)
    if (cc != t) m1 = fmaxf(m1, 0.2f + S[t*CN+cc] - d);
  for (int i2 = 0; i2 < INN; ++i2)
    if (i2 != t) m2 = fmaxf(m2, 0.2f + S[i2*CN+t] - d);
  red[t] = fmaxf(m1, 0.f) + fmaxf(m2, 0.f);
  __syncthreads();
  for (int s = 64; s > 0; s >>= 1) {
    if (t < s) red[t] += red[t+s];
    __syncthreads();
  }
  if (t == 0) out[0] = red[0];
}

extern "C" void kernel_launch(void* const* d_in, const int* in_sizes, int n_in,
                              void* d_out, int out_size, void* d_ws, size_t ws_size,
                              hipStream_t stream) {
  (void)in_sizes; (void)n_in; (void)out_size;
  const float* imgs = (const float*)d_in[0];
  const float* caps = (const float*)d_in[1];
  const int*   lens = (const int*)d_in[2];

  const size_t bfUS = 2*((size_t)MT + NT)*DN;
  const size_t gbUS = (size_t)(INN + CN)*3072;
  const size_t smallF = (size_t)INN*RN*RN + INN*RN + (size_t)CN*LN*LN + CN*LN + (size_t)INN*CN;
  int g = CN;
  while (g > 8) {
    const size_t need = (bfUS + gbUS)*2 + (smallF + (size_t)g*LN*NT)*4;
    if (need <= ws_size) break;
    g >>= 1;
  }

  ushort* aHi = (ushort*)d_ws;
  ushort* aLo = aHi + (size_t)MT*DN;   // unused slot (layout stability)
  ushort* bHi = aLo + (size_t)MT*DN;
  ushort* bLo = bHi + (size_t)NT*DN;
  ushort* gIb = bLo + (size_t)NT*DN;
  ushort* gCb = gIb + (size_t)INN*3072;
  float* fbase = (float*)(gCb + (size_t)CN*3072);
  float* gI     = fbase;
  float* nI     = gI + (size_t)INN*RN*RN;
  float* gC     = nI + (size_t)INN*RN;
  float* nC     = gC + (size_t)CN*LN*LN;
  float* scores = nC + (size_t)CN*LN;
  float* dots   = scores + (size_t)INN*CN;

  gram_conv_kernel<<<dim3(INN+CN), dim3(256), 0, stream>>>(
      imgs, caps, gI, nI, gC, nC, aHi, bHi, bLo, gIb, gCb);
  for (int c0 = 0; c0 < CN; c0 += g) {
    dots_gemm_mfma<<<dim3(NT/128, g*LN/128), dim3(256), 0, stream>>>(
        aHi, bHi, bLo, dots, c0*LN);
    attn_kernel<<<dim3(INN, g), dim3(256), 0, stream>>>(
        dots, lens, gIb, gCb, nI, nC, scores, c0);
  }
  loss_kernel<<<dim3(1), dim3(128), 0, stream>>>(scores, (float*)d_out);
}

// Round 19
// 344.209 us; speedup vs baseline: 1.1405x; 1.0842x over previous
//
#include <hip/hip_runtime.h>
#include <math.h>

#define CN 128   // captions
#define INN 128  // images
#define LN 48    // words
#define RN 36    // regions
#define DN 1024  // feature dim
#define RTA 36   // regions per attn block (TIA=1)
#define MT 6144  // CN*LN
#define NT 4608  // INN*RN
#define EPSF 1e-8f
#define LSM 9.0f
#define LLSE 6.0f

__device__ __forceinline__ float leaky(float x){ return x > 0.f ? x : 0.1f*x; }
__device__ __forceinline__ float dot4(float4 a, float4 b){
  return a.x*b.x + a.y*b.y + a.z*b.z + a.w*b.w;
}

typedef const __attribute__((address_space(1))) unsigned int* gp_t;
typedef __attribute__((address_space(3))) unsigned int* lp_t;
__device__ __forceinline__ void gload16u(const ushort* g, ushort* l) {
  __builtin_amdgcn_global_load_lds((gp_t)g, (lp_t)l, 16, 0, 0);
}

typedef short s16x8 __attribute__((ext_vector_type(8)));
typedef float f32x4 __attribute__((ext_vector_type(4)));

__device__ __forceinline__ void bf16split(float f, ushort& h, ushort& l) {
  const unsigned u = __float_as_uint(f);
  h = (ushort)((u + 0x7fffu + ((u>>16)&1u)) >> 16);
  const float res = f - __uint_as_float((unsigned)h << 16);
  const unsigned u2 = __float_as_uint(res);
  l = (ushort)((u2 + 0x7fffu + ((u2>>16)&1u)) >> 16);
}
__device__ __forceinline__ ushort bf16rne(float f) {
  const unsigned u = __float_as_uint(f);
  return (ushort)((u + 0x7fffu + ((u>>16)&1u)) >> 16);
}
__device__ __forceinline__ float bf2f(ushort u) {
  return __uint_as_float((unsigned)u << 16);
}
// XOR swizzle within a 64-elem bf16 row (8-elem granules): 2-way max bank alias
__device__ __forceinline__ int swzi(int row, int col) {
  return (col & 7) | ((((col >> 3) ^ (row & 7)) & 7) << 3);
}

// ---------------- Kernel 1: Gram + norms + bf16 emission (fused in staging regs) ----
__global__ __launch_bounds__(256) void gram_conv_kernel(
    const float* __restrict__ imgs, const float* __restrict__ caps,
    float* __restrict__ gI, float* __restrict__ nI,
    float* __restrict__ gC, float* __restrict__ nC,
    ushort* __restrict__ aHi,
    ushort* __restrict__ bHi, ushort* __restrict__ bLo,
    ushort* __restrict__ gIb, ushort* __restrict__ gCb)
{
  __shared__ __align__(16) float L[LN*132];
  const int b = blockIdx.x, tid = threadIdx.x;
  if (b < INN) {
    const float* base = imgs + (size_t)b*RN*DN;
    const int rg = tid/12, cg = tid - (tid/12)*12;
    const bool active = tid < 216;
    float a[2][3];
    #pragma unroll
    for (int u = 0; u < 2; ++u)
      #pragma unroll
      for (int v = 0; v < 3; ++v) a[u][v] = 0.f;
    for (int d0 = 0; d0 < DN; d0 += 128) {
      __syncthreads();
      for (int idx = tid; idx < RN*32; idx += 256) {
        const int row = idx >> 5, ch = idx & 31;
        const float4 v = *(const float4*)(base + row*DN + d0 + ch*4);
        *(float4*)&L[row*132 + ch*4] = v;
        const float fv[4] = {v.x,v.y,v.z,v.w};
        ushort hh[4], ll[4];
        #pragma unroll
        for (int e = 0; e < 4; ++e) bf16split(fv[e], hh[e], ll[e]);
        const size_t off = (size_t)(b*RN + row)*DN + d0 + ch*4;
        *(ushort4*)(bHi + off) = make_ushort4(hh[0],hh[1],hh[2],hh[3]);
        *(ushort4*)(bLo + off) = make_ushort4(ll[0],ll[1],ll[2],ll[3]);
      }
      __syncthreads();
      if (active) {
        const float* r0 = &L[(2*rg)*132],   * r1 = &L[(2*rg+1)*132];
        const float* c0 = &L[(3*cg)*132],   * c1 = &L[(3*cg+1)*132], * c2 = &L[(3*cg+2)*132];
        #pragma unroll
        for (int k = 0; k < 32; ++k) {
          const float4 x0 = *(const float4*)(r0 + k*4);
          const float4 x1 = *(const float4*)(r1 + k*4);
          const float4 y0 = *(const float4*)(c0 + k*4);
          const float4 y1 = *(const float4*)(c1 + k*4);
          const float4 y2 = *(const float4*)(c2 + k*4);
          a[0][0] += dot4(x0,y0); a[0][1] += dot4(x0,y1); a[0][2] += dot4(x0,y2);
          a[1][0] += dot4(x1,y0); a[1][1] += dot4(x1,y1); a[1][2] += dot4(x1,y2);
        }
      }
    }
    if (active) {
      float* gb = gI + (size_t)b*RN*RN;
      #pragma unroll
      for (int u = 0; u < 2; ++u)
        #pragma unroll
        for (int v = 0; v < 3; ++v) {
          const int r = 2*rg + u, s = 3*cg + v;
          gb[r*RN + s] = a[u][v];
          if (r == s) nI[b*RN + r] = sqrtf(fmaxf(a[u][v], 1e-16f));
        }
    }
    __threadfence_block();
    __syncthreads();
    const float* gsrc = gI + (size_t)b*RN*RN;
    ushort* gdst = gIb + (size_t)b*3072;
    for (int idx = tid; idx < 3072; idx += 256) {
      const int row = idx >> 6, col = idx & 63;
      gdst[idx] = (row < RN && col < RN) ? bf16rne(gsrc[row*RN + col]) : (ushort)0;
    }
  } else {
    const int c = b - INN;
    const float* base = caps + (size_t)c*LN*DN;
    const int rg = tid >> 4, cg = tid & 15;
    float a[3][3];
    #pragma unroll
    for (int u = 0; u < 3; ++u)
      #pragma unroll
      for (int v = 0; v < 3; ++v) a[u][v] = 0.f;
    for (int d0 = 0; d0 < DN; d0 += 128) {
      __syncthreads();
      for (int idx = tid; idx < LN*32; idx += 256) {
        const int row = idx >> 5, ch = idx & 31;
        const float4 v = *(const float4*)(base + row*DN + d0 + ch*4);
        *(float4*)&L[row*132 + ch*4] = v;
        const size_t off = (size_t)(c*LN + row)*DN + d0 + ch*4;
        *(ushort4*)(aHi + off) = make_ushort4(
            bf16rne(v.x), bf16rne(v.y), bf16rne(v.z), bf16rne(v.w));
      }
      __syncthreads();
      const float* r0 = &L[(3*rg)*132],   * r1 = &L[(3*rg+1)*132], * r2 = &L[(3*rg+2)*132];
      const float* c0 = &L[(3*cg)*132],   * c1 = &L[(3*cg+1)*132], * c2 = &L[(3*cg+2)*132];
      #pragma unroll
      for (int k = 0; k < 32; ++k) {
        const float4 x0 = *(const float4*)(r0 + k*4);
        const float4 x1 = *(const float4*)(r1 + k*4);
        const float4 x2 = *(const float4*)(r2 + k*4);
        const float4 y0 = *(const float4*)(c0 + k*4);
        const float4 y1 = *(const float4*)(c1 + k*4);
        const float4 y2 = *(const float4*)(c2 + k*4);
        a[0][0] += dot4(x0,y0); a[0][1] += dot4(x0,y1); a[0][2] += dot4(x0,y2);
        a[1][0] += dot4(x1,y0); a[1][1] += dot4(x1,y1); a[1][2] += dot4(x1,y2);
        a[2][0] += dot4(x2,y0); a[2][1] += dot4(x2,y1); a[2][2] += dot4(x2,y2);
      }
    }
    float* gb = gC + (size_t)c*LN*LN;
    #pragma unroll
    for (int u = 0; u < 3; ++u)
      #pragma unroll
      for (int v = 0; v < 3; ++v) {
        const int r = 3*rg + u, s = 3*cg + v;
        gb[r*LN + s] = a[u][v];
        if (r == s) nC[c*LN + r] = sqrtf(fmaxf(a[u][v], 1e-16f));
      }
    __threadfence_block();
    __syncthreads();
    const float* gsrc = gC + (size_t)c*LN*LN;
    ushort* gdst = gCb + (size_t)c*3072;
    for (int idx = tid; idx < 3072; idx += 256) {
      const int row = idx >> 6, col = idx & 63;
      gdst[idx] = (col < LN) ? bf16rne(gsrc[row*LN + col]) : (ushort)0;
    }
  }
}

// ---------------- Kernel 2: dots GEMM via bf16x2 MFMA (unchanged) ----------------
__global__ __launch_bounds__(256) void dots_gemm_mfma(
    const ushort* __restrict__ aHi,
    const ushort* __restrict__ bHi, const ushort* __restrict__ bLo,
    float* __restrict__ dots, int arow0)
{
  __shared__ __align__(16) ushort sT[12288];
  const int tid = threadIdx.x;
  const int wv = tid >> 6, lane = tid & 63;
  const int l15 = lane & 15, kg = lane >> 4;
  const int wr = wv >> 1, wc = wv & 1;
  const int M0 = blockIdx.y * 128;
  const int N0 = blockIdx.x * 128;

  int offA[4], offB[4];
  #pragma unroll
  for (int f = 0; f < 4; ++f) {
    const int rA = wr*64 + f*16 + l15;
    offA[f] = rA*32 + ((kg ^ ((rA>>1)&3)) << 3);
    const int rB = wc*64 + f*16 + l15;
    offB[f] = rB*32 + ((kg ^ ((rB>>1)&3)) << 3);
  }
  int srow[2], sgk[2]; unsigned dOff[2];
  #pragma unroll
  for (int h = 0; h < 2; ++h) {
    const int ch = h*256 + wv*64 + lane;
    const int row = ch >> 2, gp = ch & 3;
    srow[h] = row;
    sgk[h] = (gp ^ ((row>>1)&3)) * 8;
    dOff[h] = (unsigned)(h*256 + wv*64) * 8;
  }

  f32x4 acc[4][4];
  #pragma unroll
  for (int mf = 0; mf < 4; ++mf)
    #pragma unroll
    for (int nf = 0; nf < 4; ++nf) acc[mf][nf] = (f32x4){0.f,0.f,0.f,0.f};

  const size_t aR = (size_t)(arow0 + M0);
  for (int k0 = 0; k0 < DN; k0 += 32) {
    __syncthreads();
    #pragma unroll
    for (int h = 0; h < 2; ++h) {
      const size_t ao = (aR + srow[h])*DN + k0 + sgk[h];
      const size_t bo = ((size_t)(N0 + srow[h]))*DN + k0 + sgk[h];
      gload16u(aHi + ao, sT + dOff[h]);
      gload16u(bHi + bo, sT + 4096 + dOff[h]);
      gload16u(bLo + bo, sT + 8192 + dOff[h]);
    }
    asm volatile("s_waitcnt vmcnt(0)" ::: "memory");
    __syncthreads();
    s16x8 ah[4], bh[4], bl[4];
    #pragma unroll
    for (int f = 0; f < 4; ++f) {
      ah[f] = *(const s16x8*)&sT[offA[f]];
      bh[f] = *(const s16x8*)&sT[4096 + offB[f]];
      bl[f] = *(const s16x8*)&sT[8192 + offB[f]];
    }
    #pragma unroll
    for (int mf = 0; mf < 4; ++mf)
      #pragma unroll
      for (int nf = 0; nf < 4; ++nf) {
        acc[mf][nf] = __builtin_amdgcn_mfma_f32_16x16x32_bf16(ah[mf], bh[nf], acc[mf][nf], 0,0,0);
        acc[mf][nf] = __builtin_amdgcn_mfma_f32_16x16x32_bf16(ah[mf], bl[nf], acc[mf][nf], 0,0,0);
      }
  }
  #pragma unroll
  for (int mf = 0; mf < 4; ++mf)
    #pragma unroll
    for (int nf = 0; nf < 4; ++nf) {
      const int n = N0 + wc*64 + nf*16 + l15;
      #pragma unroll
      for (int r = 0; r < 4; ++r) {
        const int m = M0 + wr*64 + mf*16 + kg*4 + r;
        dots[(size_t)m*NT + n] = acc[mf][nf][r];
      }
    }
}

// ---------------- Kernel 3: attention — G operands read direct from global ----
// R19: sGcA/sGiB LDS staging removed; Phase C loads G fragments straight from
// gIb/gCb (L2-resident, 16B/lane). LDS 33.8->21.5KB => 7 blocks/CU.
__global__ __launch_bounds__(256) void attn_kernel(
    const float* __restrict__ dots, const int* __restrict__ cap_lens,
    const ushort* __restrict__ gIb, const ushort* __restrict__ gCb,
    const float* __restrict__ nI, const float* __restrict__ nC,
    float* __restrict__ scores, int cbase)
{
  __shared__ float sDots[LN][RTA+1];                  // 48 x 37
  __shared__ __align__(16) ushort sMeT[LN*64];        // A: [l][r] swizzled
  __shared__ __align__(16) ushort sMeIT[48*64];       // B: [r][l] swizzled
  __shared__ float sQqT[LN], sQqI[48];
  __shared__ float sW12t[LN], sInvT[LN];
  __shared__ float sW12i[RN], sInvI[RN];
  __shared__ float sColInv[RN], sRowInv[LN];
  __shared__ float sCapN[LN], sImgN[RN];
  __shared__ float sEt[LN], sEi[RN];
  __shared__ float sRed[2];

  const int cl = blockIdx.y;
  const int c  = cbase + cl;
  const int it = blockIdx.x;
  const int tid = threadIdx.x;
  const int lane = tid & 63, wv = tid >> 6;
  const int l15 = lane & 15, kg = lane >> 4;
  const int team = tid >> 2, q4 = tid & 3;
  const int nw = cap_lens[c];
  const float nwf = (float)nw;

  // ---- Phase A: stage dots + zero Me ----
  for (int idx = tid; idx < LN*RTA/4; idx += 256) {
    const int l = idx / (RTA/4), jseg = idx - l*(RTA/4);
    const float4 v = *(const float4*)(dots + ((size_t)cl*LN + l)*NT + (size_t)it*RTA + jseg*4);
    float* dst = &sDots[l][jseg*4];
    dst[0]=v.x; dst[1]=v.y; dst[2]=v.z; dst[3]=v.w;
  }
  for (int idx = tid; idx < 768; idx += 256) {
    if (idx < 384) ((uint4*)sMeT)[idx] = make_uint4(0,0,0,0);
    else ((uint4*)sMeIT)[idx-384] = make_uint4(0,0,0,0);
  }
  if (tid < LN) { sCapN[tid] = nC[c*LN + tid]; sQqT[tid] = 0.f; }
  if (tid >= 64 && tid < 64+48) sQqI[tid-64] = 0.f;
  if (tid >= 128 && tid < 128+RN) sImgN[tid-128] = nI[it*RN + (tid-128)];
  __syncthreads();

  // ---- norms: team-parallel, two 64-team passes ----
  #pragma unroll 1
  for (int pass = 0; pass < 2; ++pass) {
    const int vrow = pass*64 + team;
    if (vrow < RN) {
      float s = 0.f;
      #pragma unroll
      for (int j = 0; j < 12; ++j) { const float v = leaky(sDots[q4*12+j][vrow]); s += v*v; }
      s += __shfl_xor(s, 1, 4); s += __shfl_xor(s, 2, 4);
      if (q4 == 0) sColInv[vrow] = LSM * __builtin_amdgcn_rcpf(sqrtf(s) + EPSF);
    } else if (vrow < RN + LN) {
      const int l = vrow - RN;
      float s = 0.f;
      #pragma unroll
      for (int j = 0; j < 9; ++j) { const float v = leaky(sDots[l][q4*9+j]); s += v*v; }
      s += __shfl_xor(s, 1, 4); s += __shfl_xor(s, 2, 4);
      if (q4 == 0) sRowInv[l] = LSM * __builtin_amdgcn_rcpf(sqrtf(s) + EPSF);
    }
  }
  __syncthreads();

  // ---- Phase B: me rows (one row per 4-lane team; R8: do NOT re-batch) ----
  #pragma unroll 1
  for (int pass = 0; pass < 2; ++pass) {
    const int vrow = pass*64 + team;
    if (vrow < LN) {
      const int l = vrow;
      const int cb = q4*9;
      float d9[9], x9[9];
      #pragma unroll
      for (int j = 0; j < 9; ++j) d9[j] = sDots[l][cb + j];
      float se = 0.f;
      #pragma unroll
      for (int j = 0; j < 9; ++j) {
        const float e = __expf(leaky(d9[j]) * sColInv[cb + j]);
        x9[j] = e; se += e;
      }
      se += __shfl_xor(se, 1, 4); se += __shfl_xor(se, 2, 4);
      float ts = 0.f;
      #pragma unroll
      for (int j = 0; j < 9; ++j) {
        const float me = (x9[j]*36.f > se) ? x9[j] : 0.f;
        x9[j] = me; ts += me;
      }
      ts += __shfl_xor(ts, 1, 4); ts += __shfl_xor(ts, 2, 4);
      float w12 = 0.f;
      #pragma unroll
      for (int j = 0; j < 9; ++j) w12 += x9[j]*d9[j];
      w12 += __shfl_xor(w12, 1, 4); w12 += __shfl_xor(w12, 2, 4);
      #pragma unroll
      for (int j = 0; j < 9; ++j)
        sMeT[l*64 + swzi(l, cb + j)] = bf16rne(x9[j]);
      if (q4 == 0) {
        sW12t[l] = w12;
        sInvT[l] = __builtin_amdgcn_rcpf((ts > 0.f) ? ts : 1.f);
      }
    } else {
      const int r = vrow - LN;
      if (r < RN) {
        float d12[12], x12[12];
        #pragma unroll
        for (int j = 0; j < 12; ++j) d12[j] = sDots[q4*12+j][r];
        float se = 0.f;
        #pragma unroll
        for (int j = 0; j < 12; ++j) {
          const int l = q4*12 + j;
          const float e = (l < nw) ? __expf(leaky(d12[j]) * sRowInv[l]) : 0.f;
          x12[j] = e; se += e;
        }
        se += __shfl_xor(se, 1, 4); se += __shfl_xor(se, 2, 4);
        float ts = 0.f;
        #pragma unroll
        for (int j = 0; j < 12; ++j) {
          const float me = (x12[j]*nwf > se) ? x12[j] : 0.f;
          x12[j] = me; ts += me;
        }
        ts += __shfl_xor(ts, 1, 4); ts += __shfl_xor(ts, 2, 4);
        float w12 = 0.f;
        #pragma unroll
        for (int j = 0; j < 12; ++j) w12 += x12[j]*d12[j];
        w12 += __shfl_xor(w12, 1, 4); w12 += __shfl_xor(w12, 2, 4);
        #pragma unroll
        for (int j = 0; j < 12; ++j)
          sMeIT[r*64 + swzi(r, q4*12 + j)] = bf16rne(x12[j]);
        if (q4 == 0) {
          sW12i[r] = w12;
          sInvI[r] = __builtin_amdgcn_rcpf((ts > 0.f) ? ts : 1.f);
        }
      }
    }
  }
  __syncthreads();

  // ---- Phase C: qq via MFMA; G operands direct from global (L2-hit) ----
  const ushort* gIbase = gIb + (size_t)it*3072;
  const ushort* gCbase = gCb + (size_t)c*3072;
  #pragma unroll 1
  for (int t = wv; t < 18; t += 4) {
    const bool isT = (t < 9);
    const int tt = isT ? t : t - 9;
    const int mt = tt / 3, nt = tt - 3*(tt/3);
    const int arow = mt*16 + l15;
    const int brow = nt*16 + l15;
    f32x4 acc = (f32x4){0.f,0.f,0.f,0.f};
    if (isT) {
      #pragma unroll
      for (int ks = 0; ks < 2; ++ks) {
        const s16x8 af = *(const s16x8*)&sMeT[arow*64 + (((ks*4+kg) ^ (arow&7)))*8];
        const s16x8 bf = *(const s16x8*)(gIbase + brow*64 + (ks*4+kg)*8);
        acc = __builtin_amdgcn_mfma_f32_16x16x32_bf16(af, bf, acc, 0,0,0);
      }
      float part[4];
      #pragma unroll
      for (int rg = 0; rg < 4; ++rg) {
        const int l = mt*16 + kg*4 + rg, s = nt*16 + l15;
        part[rg] = acc[rg] * bf2f(sMeT[l*64 + swzi(l, s)]);
      }
      #pragma unroll
      for (int o = 1; o < 16; o <<= 1)
        #pragma unroll
        for (int rg = 0; rg < 4; ++rg) part[rg] += __shfl_xor(part[rg], o, 16);
      if (l15 == 0)
        #pragma unroll
        for (int rg = 0; rg < 4; ++rg)
          atomicAdd(&sQqT[mt*16 + kg*4 + rg], part[rg]);
    } else {
      #pragma unroll
      for (int ks = 0; ks < 2; ++ks) {
        const s16x8 af = *(const s16x8*)(gCbase + arow*64 + (ks*4+kg)*8);
        const s16x8 bf = *(const s16x8*)&sMeIT[brow*64 + (((ks*4+kg) ^ (brow&7)))*8];
        acc = __builtin_amdgcn_mfma_f32_16x16x32_bf16(af, bf, acc, 0,0,0);
      }
      float part = 0.f;
      #pragma unroll
      for (int rg = 0; rg < 4; ++rg) {
        const int l = mt*16 + kg*4 + rg, r = nt*16 + l15;
        part += acc[rg] * bf2f(sMeIT[r*64 + swzi(r, l)]);
      }
      part += __shfl_xor(part, 16);
      part += __shfl_xor(part, 32);
      if (lane < 16) atomicAdd(&sQqI[nt*16 + l15], part);
    }
  }
  __syncthreads();

  // ---- Epilogue ----
  if (tid < LN) {
    const float invd = sInvT[tid];
    const float w2 = sqrtf(fmaxf(sQqT[tid]*invd*invd, 1e-16f));
    const float sim = (sW12t[tid]*invd) * __builtin_amdgcn_rcpf(fmaxf(sCapN[tid]*w2, EPSF));
    sEt[tid] = (tid < nw) ? __expf(LLSE*sim) : 0.f;
  }
  if (tid >= 64 && tid < 64+RN) {
    const int r = tid - 64;
    const float invd = sInvI[r];
    const float w2 = sqrtf(fmaxf(sQqI[r]*invd*invd, 1e-16f));
    const float sim = (sW12i[r]*invd) * __builtin_amdgcn_rcpf(fmaxf(sImgN[r]*w2, EPSF));
    sEi[r] = __expf(LLSE*sim);
  }
  __syncthreads();
  if (wv == 0) {
    float e = (lane < LN) ? sEt[lane] : 0.f;
    #pragma unroll
    for (int o = 32; o > 0; o >>= 1) e += __shfl_xor(e, o);
    if (lane == 0) sRed[0] = e;
  } else if (wv == 1) {
    float e = (lane < RN) ? sEi[lane] : 0.f;
    #pragma unroll
    for (int o = 32; o > 0; o >>= 1) e += __shfl_xor(e, o);
    if (lane == 0) sRed[1] = e;
  }
  __syncthreads();
  if (tid == 0)
    scores[(size_t)it*CN + c] = __logf(sRed[0]*sRed[1])/LLSE;
}

// ---------------- Kernel 4: margin ranking loss ----------------
__global__ __launch_bounds__(128) void loss_kernel(
    const float* __restrict__ S, float* __restrict__ out)
{
  __shared__ float red[128];
  const int t = threadIdx.x;
  const float d = S[t*CN + t];
  float m1 = -1e30f, m2 = -1e30f;
  for (int cc = 0; cc < CN; ++cc)
    if (cc != t) m1 = fmaxf(m1, 0.2f + S[t*CN+cc] - d);
  for (int i2 = 0; i2 < INN; ++i2)
    if (i2 != t) m2 = fmaxf(m2, 0.2f + S[i2*CN+t] - d);
  red[t] = fmaxf(m1, 0.f) + fmaxf(m2, 0.f);
  __syncthreads();
  for (int s = 64; s > 0; s >>= 1) {
    if (t < s) red[t] += red[t+s];
    __syncthreads();
  }
  if (t == 0) out[0] = red[0];
}

extern "C" void kernel_launch(void* const* d_in, const int* in_sizes, int n_in,
                              void* d_out, int out_size, void* d_ws, size_t ws_size,
                              hipStream_t stream) {
  (void)in_sizes; (void)n_in; (void)out_size;
  const float* imgs = (const float*)d_in[0];
  const float* caps = (const float*)d_in[1];
  const int*   lens = (const int*)d_in[2];

  const size_t bfUS = 2*((size_t)MT + NT)*DN;
  const size_t gbUS = (size_t)(INN + CN)*3072;
  const size_t smallF = (size_t)INN*RN*RN + INN*RN + (size_t)CN*LN*LN + CN*LN + (size_t)INN*CN;
  int g = CN;
  while (g > 8) {
    const size_t need = (bfUS + gbUS)*2 + (smallF + (size_t)g*LN*NT)*4;
    if (need <= ws_size) break;
    g >>= 1;
  }

  ushort* aHi = (ushort*)d_ws;
  ushort* aLo = aHi + (size_t)MT*DN;   // unused slot (layout stability)
  ushort* bHi = aLo + (size_t)MT*DN;
  ushort* bLo = bHi + (size_t)NT*DN;
  ushort* gIb = bLo + (size_t)NT*DN;
  ushort* gCb = gIb + (size_t)INN*3072;
  float* fbase = (float*)(gCb + (size_t)CN*3072);
  float* gI     = fbase;
  float* nI     = gI + (size_t)INN*RN*RN;
  float* gC     = nI + (size_t)INN*RN;
  float* nC     = gC + (size_t)CN*LN*LN;
  float* scores = nC + (size_t)CN*LN;
  float* dots   = scores + (size_t)INN*CN;

  gram_conv_kernel<<<dim3(INN+CN), dim3(256), 0, stream>>>(
      imgs, caps, gI, nI, gC, nC, aHi, bHi, bLo, gIb, gCb);
  for (int c0 = 0; c0 < CN; c0 += g) {
    dots_gemm_mfma<<<dim3(NT/128, g*LN/128), dim3(256), 0, stream>>>(
        aHi, bHi, bLo, dots, c0*LN);
    attn_kernel<<<dim3(INN, g), dim3(256), 0, stream>>>(
        dots, lens, gIb, gCb, nI, nC, scores, c0);
  }
  loss_kernel<<<dim3(1), dim3(128), 0, stream>>>(scores, (float*)d_out);
}

// Round 20
// 304.006 us; speedup vs baseline: 1.2913x; 1.1322x over previous
//
#include <hip/hip_runtime.h>
#include <math.h>

#define CN 128   // captions
#define INN 128  // images
#define LN 48    // words
#define RN 36    // regions
#define DN 1024  // feature dim
#define RTA 36   // regions per attn block (TIA=1)
#define MT 6144  // CN*LN
#define NT 4608  // INN*RN
#define EPSF 1e-8f
#define LSM 9.0f
#define LLSE 6.0f

__device__ __forceinline__ float leaky(float x){ return x > 0.f ? x : 0.1f*x; }
__device__ __forceinline__ float dot4(float4 a, float4 b){
  return a.x*b.x + a.y*b.y + a.z*b.z + a.w*b.w;
}

typedef const __attribute__((address_space(1))) unsigned int* gp_t;
typedef __attribute__((address_space(3))) unsigned int* lp_t;
__device__ __forceinline__ void gload16u(const ushort* g, ushort* l) {
  __builtin_amdgcn_global_load_lds((gp_t)g, (lp_t)l, 16, 0, 0);
}

typedef short s16x8 __attribute__((ext_vector_type(8)));
typedef float f32x4 __attribute__((ext_vector_type(4)));

__device__ __forceinline__ ushort bf16rne(float f) {
  const unsigned u = __float_as_uint(f);
  return (ushort)((u + 0x7fffu + ((u>>16)&1u)) >> 16);
}
__device__ __forceinline__ float bf2f(ushort u) {
  return __uint_as_float((unsigned)u << 16);
}
// XOR swizzle within a 64-elem bf16 row (8-elem granules): 2-way max bank alias
__device__ __forceinline__ int swzi(int row, int col) {
  return (col & 7) | ((((col >> 3) ^ (row & 7)) & 7) << 3);
}

// ---------------- Kernel 1: Gram + norms + bf16 emission (hi planes only) ----------
// R20: bLo emission dropped (bf16x1 GEMM). Emission fused in staging registers.
__global__ __launch_bounds__(256) void gram_conv_kernel(
    const float* __restrict__ imgs, const float* __restrict__ caps,
    float* __restrict__ gI, float* __restrict__ nI,
    float* __restrict__ gC, float* __restrict__ nC,
    ushort* __restrict__ aHi, ushort* __restrict__ bHi,
    ushort* __restrict__ gIb, ushort* __restrict__ gCb)
{
  __shared__ __align__(16) float L[LN*132];
  const int b = blockIdx.x, tid = threadIdx.x;
  if (b < INN) {
    const float* base = imgs + (size_t)b*RN*DN;
    const int rg = tid/12, cg = tid - (tid/12)*12;
    const bool active = tid < 216;
    float a[2][3];
    #pragma unroll
    for (int u = 0; u < 2; ++u)
      #pragma unroll
      for (int v = 0; v < 3; ++v) a[u][v] = 0.f;
    for (int d0 = 0; d0 < DN; d0 += 128) {
      __syncthreads();
      for (int idx = tid; idx < RN*32; idx += 256) {
        const int row = idx >> 5, ch = idx & 31;
        const float4 v = *(const float4*)(base + row*DN + d0 + ch*4);
        *(float4*)&L[row*132 + ch*4] = v;
        const size_t off = (size_t)(b*RN + row)*DN + d0 + ch*4;
        *(ushort4*)(bHi + off) = make_ushort4(
            bf16rne(v.x), bf16rne(v.y), bf16rne(v.z), bf16rne(v.w));
      }
      __syncthreads();
      if (active) {
        const float* r0 = &L[(2*rg)*132],   * r1 = &L[(2*rg+1)*132];
        const float* c0 = &L[(3*cg)*132],   * c1 = &L[(3*cg+1)*132], * c2 = &L[(3*cg+2)*132];
        #pragma unroll
        for (int k = 0; k < 32; ++k) {
          const float4 x0 = *(const float4*)(r0 + k*4);
          const float4 x1 = *(const float4*)(r1 + k*4);
          const float4 y0 = *(const float4*)(c0 + k*4);
          const float4 y1 = *(const float4*)(c1 + k*4);
          const float4 y2 = *(const float4*)(c2 + k*4);
          a[0][0] += dot4(x0,y0); a[0][1] += dot4(x0,y1); a[0][2] += dot4(x0,y2);
          a[1][0] += dot4(x1,y0); a[1][1] += dot4(x1,y1); a[1][2] += dot4(x1,y2);
        }
      }
    }
    if (active) {
      float* gb = gI + (size_t)b*RN*RN;
      #pragma unroll
      for (int u = 0; u < 2; ++u)
        #pragma unroll
        for (int v = 0; v < 3; ++v) {
          const int r = 2*rg + u, s = 3*cg + v;
          gb[r*RN + s] = a[u][v];
          if (r == s) nI[b*RN + r] = sqrtf(fmaxf(a[u][v], 1e-16f));
        }
    }
    __threadfence_block();
    __syncthreads();
    const float* gsrc = gI + (size_t)b*RN*RN;
    ushort* gdst = gIb + (size_t)b*3072;
    for (int idx = tid; idx < 3072; idx += 256) {
      const int row = idx >> 6, col = idx & 63;
      gdst[idx] = (row < RN && col < RN) ? bf16rne(gsrc[row*RN + col]) : (ushort)0;
    }
  } else {
    const int c = b - INN;
    const float* base = caps + (size_t)c*LN*DN;
    const int rg = tid >> 4, cg = tid & 15;
    float a[3][3];
    #pragma unroll
    for (int u = 0; u < 3; ++u)
      #pragma unroll
      for (int v = 0; v < 3; ++v) a[u][v] = 0.f;
    for (int d0 = 0; d0 < DN; d0 += 128) {
      __syncthreads();
      for (int idx = tid; idx < LN*32; idx += 256) {
        const int row = idx >> 5, ch = idx & 31;
        const float4 v = *(const float4*)(base + row*DN + d0 + ch*4);
        *(float4*)&L[row*132 + ch*4] = v;
        const size_t off = (size_t)(c*LN + row)*DN + d0 + ch*4;
        *(ushort4*)(aHi + off) = make_ushort4(
            bf16rne(v.x), bf16rne(v.y), bf16rne(v.z), bf16rne(v.w));
      }
      __syncthreads();
      const float* r0 = &L[(3*rg)*132],   * r1 = &L[(3*rg+1)*132], * r2 = &L[(3*rg+2)*132];
      const float* c0 = &L[(3*cg)*132],   * c1 = &L[(3*cg+1)*132], * c2 = &L[(3*cg+2)*132];
      #pragma unroll
      for (int k = 0; k < 32; ++k) {
        const float4 x0 = *(const float4*)(r0 + k*4);
        const float4 x1 = *(const float4*)(r1 + k*4);
        const float4 x2 = *(const float4*)(r2 + k*4);
        const float4 y0 = *(const float4*)(c0 + k*4);
        const float4 y1 = *(const float4*)(c1 + k*4);
        const float4 y2 = *(const float4*)(c2 + k*4);
        a[0][0] += dot4(x0,y0); a[0][1] += dot4(x0,y1); a[0][2] += dot4(x0,y2);
        a[1][0] += dot4(x1,y0); a[1][1] += dot4(x1,y1); a[1][2] += dot4(x1,y2);
        a[2][0] += dot4(x2,y0); a[2][1] += dot4(x2,y1); a[2][2] += dot4(x2,y2);
      }
    }
    float* gb = gC + (size_t)c*LN*LN;
    #pragma unroll
    for (int u = 0; u < 3; ++u)
      #pragma unroll
      for (int v = 0; v < 3; ++v) {
        const int r = 3*rg + u, s = 3*cg + v;
        gb[r*LN + s] = a[u][v];
        if (r == s) nC[c*LN + r] = sqrtf(fmaxf(a[u][v], 1e-16f));
      }
    __threadfence_block();
    __syncthreads();
    const float* gsrc = gC + (size_t)c*LN*LN;
    ushort* gdst = gCb + (size_t)c*3072;
    for (int idx = tid; idx < 3072; idx += 256) {
      const int row = idx >> 6, col = idx & 63;
      gdst[idx] = (col < LN) ? bf16rne(gsrc[row*LN + col]) : (ushort)0;
    }
  }
}

// ---------------- Kernel 2: dots GEMM via bf16 MFMA (single plane) ----------------
// R20: dots ~= ah*bh (both lo terms dropped; each contributes ~0.04 std on dots
// of std 32 — R14's first dropped term measured absmax 0.0 at the loss).
__global__ __launch_bounds__(256) void dots_gemm_mfma(
    const ushort* __restrict__ aHi, const ushort* __restrict__ bHi,
    float* __restrict__ dots, int arow0)
{
  __shared__ __align__(16) ushort sT[8192];   // Ah [0,4096) Bh [4096,8192)
  const int tid = threadIdx.x;
  const int wv = tid >> 6, lane = tid & 63;
  const int l15 = lane & 15, kg = lane >> 4;
  const int wr = wv >> 1, wc = wv & 1;
  const int M0 = blockIdx.y * 128;
  const int N0 = blockIdx.x * 128;

  int offA[4], offB[4];
  #pragma unroll
  for (int f = 0; f < 4; ++f) {
    const int rA = wr*64 + f*16 + l15;
    offA[f] = rA*32 + ((kg ^ ((rA>>1)&3)) << 3);
    const int rB = wc*64 + f*16 + l15;
    offB[f] = rB*32 + ((kg ^ ((rB>>1)&3)) << 3);
  }
  int srow[2], sgk[2]; unsigned dOff[2];
  #pragma unroll
  for (int h = 0; h < 2; ++h) {
    const int ch = h*256 + wv*64 + lane;
    const int row = ch >> 2, gp = ch & 3;
    srow[h] = row;
    sgk[h] = (gp ^ ((row>>1)&3)) * 8;
    dOff[h] = (unsigned)(h*256 + wv*64) * 8;
  }

  f32x4 acc[4][4];
  #pragma unroll
  for (int mf = 0; mf < 4; ++mf)
    #pragma unroll
    for (int nf = 0; nf < 4; ++nf) acc[mf][nf] = (f32x4){0.f,0.f,0.f,0.f};

  const size_t aR = (size_t)(arow0 + M0);
  for (int k0 = 0; k0 < DN; k0 += 32) {
    __syncthreads();
    #pragma unroll
    for (int h = 0; h < 2; ++h) {
      const size_t ao = (aR + srow[h])*DN + k0 + sgk[h];
      const size_t bo = ((size_t)(N0 + srow[h]))*DN + k0 + sgk[h];
      gload16u(aHi + ao, sT + dOff[h]);
      gload16u(bHi + bo, sT + 4096 + dOff[h]);
    }
    asm volatile("s_waitcnt vmcnt(0)" ::: "memory");
    __syncthreads();
    s16x8 ah[4], bh[4];
    #pragma unroll
    for (int f = 0; f < 4; ++f) {
      ah[f] = *(const s16x8*)&sT[offA[f]];
      bh[f] = *(const s16x8*)&sT[4096 + offB[f]];
    }
    #pragma unroll
    for (int mf = 0; mf < 4; ++mf)
      #pragma unroll
      for (int nf = 0; nf < 4; ++nf)
        acc[mf][nf] = __builtin_amdgcn_mfma_f32_16x16x32_bf16(ah[mf], bh[nf], acc[mf][nf], 0,0,0);
  }
  #pragma unroll
  for (int mf = 0; mf < 4; ++mf)
    #pragma unroll
    for (int nf = 0; nf < 4; ++nf) {
      const int n = N0 + wc*64 + nf*16 + l15;
      #pragma unroll
      for (int r = 0; r < 4; ++r) {
        const int m = M0 + wr*64 + mf*16 + kg*4 + r;
        dots[(size_t)m*NT + n] = acc[mf][nf][r];
      }
    }
}

// ---------------- Kernel 3: attention (R19 version, unchanged) ----------------
__global__ __launch_bounds__(256) void attn_kernel(
    const float* __restrict__ dots, const int* __restrict__ cap_lens,
    const ushort* __restrict__ gIb, const ushort* __restrict__ gCb,
    const float* __restrict__ nI, const float* __restrict__ nC,
    float* __restrict__ scores, int cbase)
{
  __shared__ float sDots[LN][RTA+1];                  // 48 x 37
  __shared__ __align__(16) ushort sMeT[LN*64];        // A: [l][r] swizzled
  __shared__ __align__(16) ushort sMeIT[48*64];       // B: [r][l] swizzled
  __shared__ float sQqT[LN], sQqI[48];
  __shared__ float sW12t[LN], sInvT[LN];
  __shared__ float sW12i[RN], sInvI[RN];
  __shared__ float sColInv[RN], sRowInv[LN];
  __shared__ float sCapN[LN], sImgN[RN];
  __shared__ float sEt[LN], sEi[RN];
  __shared__ float sRed[2];

  const int cl = blockIdx.y;
  const int c  = cbase + cl;
  const int it = blockIdx.x;
  const int tid = threadIdx.x;
  const int lane = tid & 63, wv = tid >> 6;
  const int l15 = lane & 15, kg = lane >> 4;
  const int team = tid >> 2, q4 = tid & 3;
  const int nw = cap_lens[c];
  const float nwf = (float)nw;

  // ---- Phase A: stage dots + zero Me ----
  for (int idx = tid; idx < LN*RTA/4; idx += 256) {
    const int l = idx / (RTA/4), jseg = idx - l*(RTA/4);
    const float4 v = *(const float4*)(dots + ((size_t)cl*LN + l)*NT + (size_t)it*RTA + jseg*4);
    float* dst = &sDots[l][jseg*4];
    dst[0]=v.x; dst[1]=v.y; dst[2]=v.z; dst[3]=v.w;
  }
  for (int idx = tid; idx < 768; idx += 256) {
    if (idx < 384) ((uint4*)sMeT)[idx] = make_uint4(0,0,0,0);
    else ((uint4*)sMeIT)[idx-384] = make_uint4(0,0,0,0);
  }
  if (tid < LN) { sCapN[tid] = nC[c*LN + tid]; sQqT[tid] = 0.f; }
  if (tid >= 64 && tid < 64+48) sQqI[tid-64] = 0.f;
  if (tid >= 128 && tid < 128+RN) sImgN[tid-128] = nI[it*RN + (tid-128)];
  __syncthreads();

  // ---- norms: team-parallel, two 64-team passes ----
  #pragma unroll 1
  for (int pass = 0; pass < 2; ++pass) {
    const int vrow = pass*64 + team;
    if (vrow < RN) {
      float s = 0.f;
      #pragma unroll
      for (int j = 0; j < 12; ++j) { const float v = leaky(sDots[q4*12+j][vrow]); s += v*v; }
      s += __shfl_xor(s, 1, 4); s += __shfl_xor(s, 2, 4);
      if (q4 == 0) sColInv[vrow] = LSM * __builtin_amdgcn_rcpf(sqrtf(s) + EPSF);
    } else if (vrow < RN + LN) {
      const int l = vrow - RN;
      float s = 0.f;
      #pragma unroll
      for (int j = 0; j < 9; ++j) { const float v = leaky(sDots[l][q4*9+j]); s += v*v; }
      s += __shfl_xor(s, 1, 4); s += __shfl_xor(s, 2, 4);
      if (q4 == 0) sRowInv[l] = LSM * __builtin_amdgcn_rcpf(sqrtf(s) + EPSF);
    }
  }
  __syncthreads();

  // ---- Phase B: me rows (one row per 4-lane team; R8: do NOT re-batch) ----
  #pragma unroll 1
  for (int pass = 0; pass < 2; ++pass) {
    const int vrow = pass*64 + team;
    if (vrow < LN) {
      const int l = vrow;
      const int cb = q4*9;
      float d9[9], x9[9];
      #pragma unroll
      for (int j = 0; j < 9; ++j) d9[j] = sDots[l][cb + j];
      float se = 0.f;
      #pragma unroll
      for (int j = 0; j < 9; ++j) {
        const float e = __expf(leaky(d9[j]) * sColInv[cb + j]);
        x9[j] = e; se += e;
      }
      se += __shfl_xor(se, 1, 4); se += __shfl_xor(se, 2, 4);
      float ts = 0.f;
      #pragma unroll
      for (int j = 0; j < 9; ++j) {
        const float me = (x9[j]*36.f > se) ? x9[j] : 0.f;
        x9[j] = me; ts += me;
      }
      ts += __shfl_xor(ts, 1, 4); ts += __shfl_xor(ts, 2, 4);
      float w12 = 0.f;
      #pragma unroll
      for (int j = 0; j < 9; ++j) w12 += x9[j]*d9[j];
      w12 += __shfl_xor(w12, 1, 4); w12 += __shfl_xor(w12, 2, 4);
      #pragma unroll
      for (int j = 0; j < 9; ++j)
        sMeT[l*64 + swzi(l, cb + j)] = bf16rne(x9[j]);
      if (q4 == 0) {
        sW12t[l] = w12;
        sInvT[l] = __builtin_amdgcn_rcpf((ts > 0.f) ? ts : 1.f);
      }
    } else {
      const int r = vrow - LN;
      if (r < RN) {
        float d12[12], x12[12];
        #pragma unroll
        for (int j = 0; j < 12; ++j) d12[j] = sDots[q4*12+j][r];
        float se = 0.f;
        #pragma unroll
        for (int j = 0; j < 12; ++j) {
          const int l = q4*12 + j;
          const float e = (l < nw) ? __expf(leaky(d12[j]) * sRowInv[l]) : 0.f;
          x12[j] = e; se += e;
        }
        se += __shfl_xor(se, 1, 4); se += __shfl_xor(se, 2, 4);
        float ts = 0.f;
        #pragma unroll
        for (int j = 0; j < 12; ++j) {
          const float me = (x12[j]*nwf > se) ? x12[j] : 0.f;
          x12[j] = me; ts += me;
        }
        ts += __shfl_xor(ts, 1, 4); ts += __shfl_xor(ts, 2, 4);
        float w12 = 0.f;
        #pragma unroll
        for (int j = 0; j < 12; ++j) w12 += x12[j]*d12[j];
        w12 += __shfl_xor(w12, 1, 4); w12 += __shfl_xor(w12, 2, 4);
        #pragma unroll
        for (int j = 0; j < 12; ++j)
          sMeIT[r*64 + swzi(r, q4*12 + j)] = bf16rne(x12[j]);
        if (q4 == 0) {
          sW12i[r] = w12;
          sInvI[r] = __builtin_amdgcn_rcpf((ts > 0.f) ? ts : 1.f);
        }
      }
    }
  }
  __syncthreads();

  // ---- Phase C: qq via MFMA; G operands direct from global (L2-hit) ----
  const ushort* gIbase = gIb + (size_t)it*3072;
  const ushort* gCbase = gCb + (size_t)c*3072;
  #pragma unroll 1
  for (int t = wv; t < 18; t += 4) {
    const bool isT = (t < 9);
    const int tt = isT ? t : t - 9;
    const int mt = tt / 3, nt = tt - 3*(tt/3);
    const int arow = mt*16 + l15;
    const int brow = nt*16 + l15;
    f32x4 acc = (f32x4){0.f,0.f,0.f,0.f};
    if (isT) {
      #pragma unroll
      for (int ks = 0; ks < 2; ++ks) {
        const s16x8 af = *(const s16x8*)&sMeT[arow*64 + (((ks*4+kg) ^ (arow&7)))*8];
        const s16x8 bf = *(const s16x8*)(gIbase + brow*64 + (ks*4+kg)*8);
        acc = __builtin_amdgcn_mfma_f32_16x16x32_bf16(af, bf, acc, 0,0,0);
      }
      float part[4];
      #pragma unroll
      for (int rg = 0; rg < 4; ++rg) {
        const int l = mt*16 + kg*4 + rg, s = nt*16 + l15;
        part[rg] = acc[rg] * bf2f(sMeT[l*64 + swzi(l, s)]);
      }
      #pragma unroll
      for (int o = 1; o < 16; o <<= 1)
        #pragma unroll
        for (int rg = 0; rg < 4; ++rg) part[rg] += __shfl_xor(part[rg], o, 16);
      if (l15 == 0)
        #pragma unroll
        for (int rg = 0; rg < 4; ++rg)
          atomicAdd(&sQqT[mt*16 + kg*4 + rg], part[rg]);
    } else {
      #pragma unroll
      for (int ks = 0; ks < 2; ++ks) {
        const s16x8 af = *(const s16x8*)(gCbase + arow*64 + (ks*4+kg)*8);
        const s16x8 bf = *(const s16x8*)&sMeIT[brow*64 + (((ks*4+kg) ^ (brow&7)))*8];
        acc = __builtin_amdgcn_mfma_f32_16x16x32_bf16(af, bf, acc, 0,0,0);
      }
      float part = 0.f;
      #pragma unroll
      for (int rg = 0; rg < 4; ++rg) {
        const int l = mt*16 + kg*4 + rg, r = nt*16 + l15;
        part += acc[rg] * bf2f(sMeIT[r*64 + swzi(r, l)]);
      }
      part += __shfl_xor(part, 16);
      part += __shfl_xor(part, 32);
      if (lane < 16) atomicAdd(&sQqI[nt*16 + l15], part);
    }
  }
  __syncthreads();

  // ---- Epilogue ----
  if (tid < LN) {
    const float invd = sInvT[tid];
    const float w2 = sqrtf(fmaxf(sQqT[tid]*invd*invd, 1e-16f));
    const float sim = (sW12t[tid]*invd) * __builtin_amdgcn_rcpf(fmaxf(sCapN[tid]*w2, EPSF));
    sEt[tid] = (tid < nw) ? __expf(LLSE*sim) : 0.f;
  }
  if (tid >= 64 && tid < 64+RN) {
    const int r = tid - 64;
    const float invd = sInvI[r];
    const float w2 = sqrtf(fmaxf(sQqI[r]*invd*invd, 1e-16f));
    const float sim = (sW12i[r]*invd) * __builtin_amdgcn_rcpf(fmaxf(sImgN[r]*w2, EPSF));
    sEi[r] = __expf(LLSE*sim);
  }
  __syncthreads();
  if (wv == 0) {
    float e = (lane < LN) ? sEt[lane] : 0.f;
    #pragma unroll
    for (int o = 32; o > 0; o >>= 1) e += __shfl_xor(e, o);
    if (lane == 0) sRed[0] = e;
  } else if (wv == 1) {
    float e = (lane < RN) ? sEi[lane] : 0.f;
    #pragma unroll
    for (int o = 32; o > 0; o >>= 1) e += __shfl_xor(e, o);
    if (lane == 0) sRed[1] = e;
  }
  __syncthreads();
  if (tid == 0)
    scores[(size_t)it*CN + c] = __logf(sRed[0]*sRed[1])/LLSE;
}

// ---------------- Kernel 4: margin ranking loss ----------------
__global__ __launch_bounds__(128) void loss_kernel(
    const float* __restrict__ S, float* __restrict__ out)
{
  __shared__ float red[128];
  const int t = threadIdx.x;
  const float d = S[t*CN + t];
  float m1 = -1e30f, m2 = -1e30f;
  for (int cc = 0; cc < CN; ++cc)
    if (cc != t) m1 = fmaxf(m1, 0.2f + S[t*CN+cc] - d);
  for (int i2 = 0; i2 < INN; ++i2)
    if (i2 != t) m2 = fmaxf(m2, 0.2f + S[i2*CN+t] - d);
  red[t] = fmaxf(m1, 0.f) + fmaxf(m2, 0.f);
  __syncthreads();
  for (int s = 64; s > 0; s >>= 1) {
    if (t < s) red[t] += red[t+s];
    __syncthreads();
  }
  if (t == 0) out[0] = red[0];
}

extern "C" void kernel_launch(void* const* d_in, const int* in_sizes, int n_in,
                              void* d_out, int out_size, void* d_ws, size_t ws_size,
                              hipStream_t stream) {
  (void)in_sizes; (void)n_in; (void)out_size;
  const float* imgs = (const float*)d_in[0];
  const float* caps = (const float*)d_in[1];
  const int*   lens = (const int*)d_in[2];

  const size_t bfUS = 2*((size_t)MT + NT)*DN;   // layout unchanged (lo slots unused)
  const size_t gbUS = (size_t)(INN + CN)*3072;
  const size_t smallF = (size_t)INN*RN*RN + INN*RN + (size_t)CN*LN*LN + CN*LN + (size_t)INN*CN;
  int g = CN;
  while (g > 8) {
    const size_t need = (bfUS + gbUS)*2 + (smallF + (size_t)g*LN*NT)*4;
    if (need <= ws_size) break;
    g >>= 1;
  }

  ushort* aHi = (ushort*)d_ws;
  ushort* aLo = aHi + (size_t)MT*DN;   // unused
  ushort* bHi = aLo + (size_t)MT*DN;
  ushort* bLo = bHi + (size_t)NT*DN;   // unused (R20)
  ushort* gIb = bLo + (size_t)NT*DN;
  ushort* gCb = gIb + (size_t)INN*3072;
  float* fbase = (float*)(gCb + (size_t)CN*3072);
  float* gI     = fbase;
  float* nI     = gI + (size_t)INN*RN*RN;
  float* gC     = nI + (size_t)INN*RN;
  float* nC     = gC + (size_t)CN*LN*LN;
  float* scores = nC + (size_t)CN*LN;
  float* dots   = scores + (size_t)INN*CN;

  gram_conv_kernel<<<dim3(INN+CN), dim3(256), 0, stream>>>(
      imgs, caps, gI, nI, gC, nC, aHi, bHi, gIb, gCb);
  for (int c0 = 0; c0 < CN; c0 += g) {
    dots_gemm_mfma<<<dim3(NT/128, g*LN/128), dim3(256), 0, stream>>>(
        aHi, bHi, dots, c0*LN);
    attn_kernel<<<dim3(INN, g), dim3(256), 0, stream>>>(
        dots, lens, gIb, gCb, nI, nC, scores, c0);
  }
  loss_kernel<<<dim3(1), dim3(128), 0, stream>>>(scores, (float*)d_out);
}

// Round 21
// 293.207 us; speedup vs baseline: 1.3389x; 1.0368x over previous
//
#include <hip/hip_runtime.h>
#include <math.h>

#define CN 128   // captions
#define INN 128  // images
#define LN 48    // words
#define RN 36    // regions
#define DN 1024  // feature dim
#define RTA 36   // regions per attn block (TIA=1)
#define MT 6144  // CN*LN
#define NT 4608  // INN*RN
#define EPSF 1e-8f
#define LSM 9.0f
#define LLSE 6.0f
#define LOG2E 1.4426950408889634f

__device__ __forceinline__ float leaky(float x){ return x > 0.f ? x : 0.1f*x; }
__device__ __forceinline__ float dot4(float4 a, float4 b){
  return a.x*b.x + a.y*b.y + a.z*b.z + a.w*b.w;
}

typedef const __attribute__((address_space(1))) unsigned int* gp_t;
typedef __attribute__((address_space(3))) unsigned int* lp_t;
__device__ __forceinline__ void gload16u(const ushort* g, ushort* l) {
  __builtin_amdgcn_global_load_lds((gp_t)g, (lp_t)l, 16, 0, 0);
}

typedef short s16x8 __attribute__((ext_vector_type(8)));
typedef float f32x4 __attribute__((ext_vector_type(4)));

__device__ __forceinline__ ushort bf16rne(float f) {
  const unsigned u = __float_as_uint(f);
  return (ushort)((u + 0x7fffu + ((u>>16)&1u)) >> 16);
}
__device__ __forceinline__ float bf2f(ushort u) {
  return __uint_as_float((unsigned)u << 16);
}
// XOR swizzle within a 64-elem bf16 row (8-elem granules): 2-way max bank alias
__device__ __forceinline__ int swzi(int row, int col) {
  return (col & 7) | ((((col >> 3) ^ (row & 7)) & 7) << 3);
}

// ---------------- Kernel 1: Gram + norms + bf16 emission (hi planes only) ----------
__global__ __launch_bounds__(256) void gram_conv_kernel(
    const float* __restrict__ imgs, const float* __restrict__ caps,
    float* __restrict__ gI, float* __restrict__ nI,
    float* __restrict__ gC, float* __restrict__ nC,
    ushort* __restrict__ aHi, ushort* __restrict__ bHi,
    ushort* __restrict__ gIb, ushort* __restrict__ gCb)
{
  __shared__ __align__(16) float L[LN*132];
  const int b = blockIdx.x, tid = threadIdx.x;
  if (b < INN) {
    const float* base = imgs + (size_t)b*RN*DN;
    const int rg = tid/12, cg = tid - (tid/12)*12;
    const bool active = tid < 216;
    float a[2][3];
    #pragma unroll
    for (int u = 0; u < 2; ++u)
      #pragma unroll
      for (int v = 0; v < 3; ++v) a[u][v] = 0.f;
    for (int d0 = 0; d0 < DN; d0 += 128) {
      __syncthreads();
      for (int idx = tid; idx < RN*32; idx += 256) {
        const int row = idx >> 5, ch = idx & 31;
        const float4 v = *(const float4*)(base + row*DN + d0 + ch*4);
        *(float4*)&L[row*132 + ch*4] = v;
        const size_t off = (size_t)(b*RN + row)*DN + d0 + ch*4;
        *(ushort4*)(bHi + off) = make_ushort4(
            bf16rne(v.x), bf16rne(v.y), bf16rne(v.z), bf16rne(v.w));
      }
      __syncthreads();
      if (active) {
        const float* r0 = &L[(2*rg)*132],   * r1 = &L[(2*rg+1)*132];
        const float* c0 = &L[(3*cg)*132],   * c1 = &L[(3*cg+1)*132], * c2 = &L[(3*cg+2)*132];
        #pragma unroll
        for (int k = 0; k < 32; ++k) {
          const float4 x0 = *(const float4*)(r0 + k*4);
          const float4 x1 = *(const float4*)(r1 + k*4);
          const float4 y0 = *(const float4*)(c0 + k*4);
          const float4 y1 = *(const float4*)(c1 + k*4);
          const float4 y2 = *(const float4*)(c2 + k*4);
          a[0][0] += dot4(x0,y0); a[0][1] += dot4(x0,y1); a[0][2] += dot4(x0,y2);
          a[1][0] += dot4(x1,y0); a[1][1] += dot4(x1,y1); a[1][2] += dot4(x1,y2);
        }
      }
    }
    if (active) {
      float* gb = gI + (size_t)b*RN*RN;
      #pragma unroll
      for (int u = 0; u < 2; ++u)
        #pragma unroll
        for (int v = 0; v < 3; ++v) {
          const int r = 2*rg + u, s = 3*cg + v;
          gb[r*RN + s] = a[u][v];
          if (r == s) nI[b*RN + r] = sqrtf(fmaxf(a[u][v], 1e-16f));
        }
    }
    __threadfence_block();
    __syncthreads();
    const float* gsrc = gI + (size_t)b*RN*RN;
    ushort* gdst = gIb + (size_t)b*3072;
    for (int idx = tid; idx < 3072; idx += 256) {
      const int row = idx >> 6, col = idx & 63;
      gdst[idx] = (row < RN && col < RN) ? bf16rne(gsrc[row*RN + col]) : (ushort)0;
    }
  } else {
    const int c = b - INN;
    const float* base = caps + (size_t)c*LN*DN;
    const int rg = tid >> 4, cg = tid & 15;
    float a[3][3];
    #pragma unroll
    for (int u = 0; u < 3; ++u)
      #pragma unroll
      for (int v = 0; v < 3; ++v) a[u][v] = 0.f;
    for (int d0 = 0; d0 < DN; d0 += 128) {
      __syncthreads();
      for (int idx = tid; idx < LN*32; idx += 256) {
        const int row = idx >> 5, ch = idx & 31;
        const float4 v = *(const float4*)(base + row*DN + d0 + ch*4);
        *(float4*)&L[row*132 + ch*4] = v;
        const size_t off = (size_t)(c*LN + row)*DN + d0 + ch*4;
        *(ushort4*)(aHi + off) = make_ushort4(
            bf16rne(v.x), bf16rne(v.y), bf16rne(v.z), bf16rne(v.w));
      }
      __syncthreads();
      const float* r0 = &L[(3*rg)*132],   * r1 = &L[(3*rg+1)*132], * r2 = &L[(3*rg+2)*132];
      const float* c0 = &L[(3*cg)*132],   * c1 = &L[(3*cg+1)*132], * c2 = &L[(3*cg+2)*132];
      #pragma unroll
      for (int k = 0; k < 32; ++k) {
        const float4 x0 = *(const float4*)(r0 + k*4);
        const float4 x1 = *(const float4*)(r1 + k*4);
        const float4 x2 = *(const float4*)(r2 + k*4);
        const float4 y0 = *(const float4*)(c0 + k*4);
        const float4 y1 = *(const float4*)(c1 + k*4);
        const float4 y2 = *(const float4*)(c2 + k*4);
        a[0][0] += dot4(x0,y0); a[0][1] += dot4(x0,y1); a[0][2] += dot4(x0,y2);
        a[1][0] += dot4(x1,y0); a[1][1] += dot4(x1,y1); a[1][2] += dot4(x1,y2);
        a[2][0] += dot4(x2,y0); a[2][1] += dot4(x2,y1); a[2][2] += dot4(x2,y2);
      }
    }
    float* gb = gC + (size_t)c*LN*LN;
    #pragma unroll
    for (int u = 0; u < 3; ++u)
      #pragma unroll
      for (int v = 0; v < 3; ++v) {
        const int r = 3*rg + u, s = 3*cg + v;
        gb[r*LN + s] = a[u][v];
        if (r == s) nC[c*LN + r] = sqrtf(fmaxf(a[u][v], 1e-16f));
      }
    __threadfence_block();
    __syncthreads();
    const float* gsrc = gC + (size_t)c*LN*LN;
    ushort* gdst = gCb + (size_t)c*3072;
    for (int idx = tid; idx < 3072; idx += 256) {
      const int row = idx >> 6, col = idx & 63;
      gdst[idx] = (col < LN) ? bf16rne(gsrc[row*LN + col]) : (ushort)0;
    }
  }
}

// ---------------- Kernel 2: dots GEMM via bf16 MFMA (single plane, unchanged) -------
__global__ __launch_bounds__(256) void dots_gemm_mfma(
    const ushort* __restrict__ aHi, const ushort* __restrict__ bHi,
    float* __restrict__ dots, int arow0)
{
  __shared__ __align__(16) ushort sT[8192];   // Ah [0,4096) Bh [4096,8192)
  const int tid = threadIdx.x;
  const int wv = tid >> 6, lane = tid & 63;
  const int l15 = lane & 15, kg = lane >> 4;
  const int wr = wv >> 1, wc = wv & 1;
  const int M0 = blockIdx.y * 128;
  const int N0 = blockIdx.x * 128;

  int offA[4], offB[4];
  #pragma unroll
  for (int f = 0; f < 4; ++f) {
    const int rA = wr*64 + f*16 + l15;
    offA[f] = rA*32 + ((kg ^ ((rA>>1)&3)) << 3);
    const int rB = wc*64 + f*16 + l15;
    offB[f] = rB*32 + ((kg ^ ((rB>>1)&3)) << 3);
  }
  int srow[2], sgk[2]; unsigned dOff[2];
  #pragma unroll
  for (int h = 0; h < 2; ++h) {
    const int ch = h*256 + wv*64 + lane;
    const int row = ch >> 2, gp = ch & 3;
    srow[h] = row;
    sgk[h] = (gp ^ ((row>>1)&3)) * 8;
    dOff[h] = (unsigned)(h*256 + wv*64) * 8;
  }

  f32x4 acc[4][4];
  #pragma unroll
  for (int mf = 0; mf < 4; ++mf)
    #pragma unroll
    for (int nf = 0; nf < 4; ++nf) acc[mf][nf] = (f32x4){0.f,0.f,0.f,0.f};

  const size_t aR = (size_t)(arow0 + M0);
  for (int k0 = 0; k0 < DN; k0 += 32) {
    __syncthreads();
    #pragma unroll
    for (int h = 0; h < 2; ++h) {
      const size_t ao = (aR + srow[h])*DN + k0 + sgk[h];
      const size_t bo = ((size_t)(N0 + srow[h]))*DN + k0 + sgk[h];
      gload16u(aHi + ao, sT + dOff[h]);
      gload16u(bHi + bo, sT + 4096 + dOff[h]);
    }
    asm volatile("s_waitcnt vmcnt(0)" ::: "memory");
    __syncthreads();
    s16x8 ah[4], bh[4];
    #pragma unroll
    for (int f = 0; f < 4; ++f) {
      ah[f] = *(const s16x8*)&sT[offA[f]];
      bh[f] = *(const s16x8*)&sT[4096 + offB[f]];
    }
    #pragma unroll
    for (int mf = 0; mf < 4; ++mf)
      #pragma unroll
      for (int nf = 0; nf < 4; ++nf)
        acc[mf][nf] = __builtin_amdgcn_mfma_f32_16x16x32_bf16(ah[mf], bh[nf], acc[mf][nf], 0,0,0);
  }
  #pragma unroll
  for (int mf = 0; mf < 4; ++mf)
    #pragma unroll
    for (int nf = 0; nf < 4; ++nf) {
      const int n = N0 + wc*64 + nf*16 + l15;
      #pragma unroll
      for (int r = 0; r < 4; ++r) {
        const int m = M0 + wr*64 + mf*16 + kg*4 + r;
        dots[(size_t)m*NT + n] = acc[mf][nf][r];
      }
    }
}

// ---------------- Kernel 3: attention ----------------
// R21: (1) exp2 with log2e folded into norm scales / LSE constants (removes
// one v_mul per exp); (2) Phase C unified: t2i computed as H^T = Gi*Me_t^T
// (Gi symmetric) so BOTH paths are A=G(global) x B=Me(LDS) with a 2-shuffle
// reduce over output rows + lane<16 atomic. Exact reassociation.
__global__ __launch_bounds__(256) void attn_kernel(
    const float* __restrict__ dots, const int* __restrict__ cap_lens,
    const ushort* __restrict__ gIb, const ushort* __restrict__ gCb,
    const float* __restrict__ nI, const float* __restrict__ nC,
    float* __restrict__ scores, int cbase)
{
  __shared__ float sDots[LN][RTA+1];                  // 48 x 37
  __shared__ __align__(16) ushort sMeT[LN*64];        // [l][r] swizzled (Me_t rows)
  __shared__ __align__(16) ushort sMeIT[48*64];       // [r][l] swizzled (Me_i^T rows)
  __shared__ float sQqT[LN], sQqI[48];
  __shared__ float sW12t[LN], sInvT[LN];
  __shared__ float sW12i[RN], sInvI[RN];
  __shared__ float sColInv[RN], sRowInv[LN];
  __shared__ float sCapN[LN], sImgN[RN];
  __shared__ float sEt[LN], sEi[RN];
  __shared__ float sRed[2];

  const int cl = blockIdx.y;
  const int c  = cbase + cl;
  const int it = blockIdx.x;
  const int tid = threadIdx.x;
  const int lane = tid & 63, wv = tid >> 6;
  const int l15 = lane & 15, kg = lane >> 4;
  const int team = tid >> 2, q4 = tid & 3;
  const int nw = cap_lens[c];
  const float nwf = (float)nw;

  // ---- Phase A: stage dots + zero Me ----
  for (int idx = tid; idx < LN*RTA/4; idx += 256) {
    const int l = idx / (RTA/4), jseg = idx - l*(RTA/4);
    const float4 v = *(const float4*)(dots + ((size_t)cl*LN + l)*NT + (size_t)it*RTA + jseg*4);
    float* dst = &sDots[l][jseg*4];
    dst[0]=v.x; dst[1]=v.y; dst[2]=v.z; dst[3]=v.w;
  }
  for (int idx = tid; idx < 768; idx += 256) {
    if (idx < 384) ((uint4*)sMeT)[idx] = make_uint4(0,0,0,0);
    else ((uint4*)sMeIT)[idx-384] = make_uint4(0,0,0,0);
  }
  if (tid < LN) { sCapN[tid] = nC[c*LN + tid]; sQqT[tid] = 0.f; }
  if (tid >= 64 && tid < 64+48) sQqI[tid-64] = 0.f;
  if (tid >= 128 && tid < 128+RN) sImgN[tid-128] = nI[it*RN + (tid-128)];
  __syncthreads();

  // ---- norms: team-parallel, two 64-team passes (log2e folded) ----
  #pragma unroll 1
  for (int pass = 0; pass < 2; ++pass) {
    const int vrow = pass*64 + team;
    if (vrow < RN) {
      float s = 0.f;
      #pragma unroll
      for (int j = 0; j < 12; ++j) { const float v = leaky(sDots[q4*12+j][vrow]); s += v*v; }
      s += __shfl_xor(s, 1, 4); s += __shfl_xor(s, 2, 4);
      if (q4 == 0) sColInv[vrow] = (LSM*LOG2E) * __builtin_amdgcn_rcpf(sqrtf(s) + EPSF);
    } else if (vrow < RN + LN) {
      const int l = vrow - RN;
      float s = 0.f;
      #pragma unroll
      for (int j = 0; j < 9; ++j) { const float v = leaky(sDots[l][q4*9+j]); s += v*v; }
      s += __shfl_xor(s, 1, 4); s += __shfl_xor(s, 2, 4);
      if (q4 == 0) sRowInv[l] = (LSM*LOG2E) * __builtin_amdgcn_rcpf(sqrtf(s) + EPSF);
    }
  }
  __syncthreads();

  // ---- Phase B: me rows (one row per 4-lane team; R8: do NOT re-batch) ----
  #pragma unroll 1
  for (int pass = 0; pass < 2; ++pass) {
    const int vrow = pass*64 + team;
    if (vrow < LN) {
      const int l = vrow;
      const int cb = q4*9;
      float d9[9], x9[9];
      #pragma unroll
      for (int j = 0; j < 9; ++j) d9[j] = sDots[l][cb + j];
      float se = 0.f;
      #pragma unroll
      for (int j = 0; j < 9; ++j) {
        const float e = exp2f(leaky(d9[j]) * sColInv[cb + j]);
        x9[j] = e; se += e;
      }
      se += __shfl_xor(se, 1, 4); se += __shfl_xor(se, 2, 4);
      float ts = 0.f;
      #pragma unroll
      for (int j = 0; j < 9; ++j) {
        const float me = (x9[j]*36.f > se) ? x9[j] : 0.f;
        x9[j] = me; ts += me;
      }
      ts += __shfl_xor(ts, 1, 4); ts += __shfl_xor(ts, 2, 4);
      float w12 = 0.f;
      #pragma unroll
      for (int j = 0; j < 9; ++j) w12 += x9[j]*d9[j];
      w12 += __shfl_xor(w12, 1, 4); w12 += __shfl_xor(w12, 2, 4);
      #pragma unroll
      for (int j = 0; j < 9; ++j)
        sMeT[l*64 + swzi(l, cb + j)] = bf16rne(x9[j]);
      if (q4 == 0) {
        sW12t[l] = w12;
        sInvT[l] = __builtin_amdgcn_rcpf((ts > 0.f) ? ts : 1.f);
      }
    } else {
      const int r = vrow - LN;
      if (r < RN) {
        float d12[12], x12[12];
        #pragma unroll
        for (int j = 0; j < 12; ++j) d12[j] = sDots[q4*12+j][r];
        float se = 0.f;
        #pragma unroll
        for (int j = 0; j < 12; ++j) {
          const int l = q4*12 + j;
          const float e = (l < nw) ? exp2f(leaky(d12[j]) * sRowInv[l]) : 0.f;
          x12[j] = e; se += e;
        }
        se += __shfl_xor(se, 1, 4); se += __shfl_xor(se, 2, 4);
        float ts = 0.f;
        #pragma unroll
        for (int j = 0; j < 12; ++j) {
          const float me = (x12[j]*nwf > se) ? x12[j] : 0.f;
          x12[j] = me; ts += me;
        }
        ts += __shfl_xor(ts, 1, 4); ts += __shfl_xor(ts, 2, 4);
        float w12 = 0.f;
        #pragma unroll
        for (int j = 0; j < 12; ++j) w12 += x12[j]*d12[j];
        w12 += __shfl_xor(w12, 1, 4); w12 += __shfl_xor(w12, 2, 4);
        #pragma unroll
        for (int j = 0; j < 12; ++j)
          sMeIT[r*64 + swzi(r, q4*12 + j)] = bf16rne(x12[j]);
        if (q4 == 0) {
          sW12i[r] = w12;
          sInvI[r] = __builtin_amdgcn_rcpf((ts > 0.f) ? ts : 1.f);
        }
      }
    }
  }
  __syncthreads();

  // ---- Phase C: qq via MFMA, unified paths ----
  // t2i: H^T[r][l] = sum_s Gi[r][s]*Me_t[l][s]  (A=Gi global, B=sMeT row l)
  //      qq_t[l]  += sum_r H^T[r][l]*Me_t[l][r]
  // i2t: H[l][r]  = sum_m Gc[l][m]*Me_i[m][r]   (A=Gc global, B=sMeIT row r)
  //      qq_i[r]  += sum_l H[l][r]*Me_i[l][r]
  const ushort* gIbase = gIb + (size_t)it*3072;
  const ushort* gCbase = gCb + (size_t)c*3072;
  #pragma unroll 1
  for (int t = wv; t < 18; t += 4) {
    const bool isT = (t < 9);
    const int tt = isT ? t : t - 9;
    const int mt = tt / 3, nt = tt - 3*(tt/3);
    const ushort* Ab = isT ? gIbase : gCbase;
    const ushort* Mb = isT ? sMeT   : sMeIT;
    const int arow = mt*16 + l15;        // A row (r for t2i, l for i2t)
    const int brow = nt*16 + l15;        // Me row (l for t2i, r for i2t)
    f32x4 acc = (f32x4){0.f,0.f,0.f,0.f};
    #pragma unroll
    for (int ks = 0; ks < 2; ++ks) {
      const s16x8 af = *(const s16x8*)(Ab + arow*64 + (ks*4+kg)*8);
      const s16x8 bf = *(const s16x8*)&Mb[brow*64 + (((ks*4+kg) ^ (brow&7)))*8];
      acc = __builtin_amdgcn_mfma_f32_16x16x32_bf16(af, bf, acc, 0,0,0);
    }
    // C[row = mt*16+kg*4+reg][col = brow]; weight by Me[brow][row]
    float part = 0.f;
    #pragma unroll
    for (int rg = 0; rg < 4; ++rg) {
      const int orow = mt*16 + kg*4 + rg;
      part += acc[rg] * bf2f(Mb[brow*64 + swzi(brow, orow)]);
    }
    part += __shfl_xor(part, 16);
    part += __shfl_xor(part, 32);
    if (lane < 16)
      atomicAdd(isT ? &sQqT[nt*16 + l15] : &sQqI[nt*16 + l15], part);
  }
  __syncthreads();

  // ---- Epilogue (exp2/log2 with folded constants) ----
  if (tid < LN) {
    const float invd = sInvT[tid];
    const float w2 = sqrtf(fmaxf(sQqT[tid]*invd*invd, 1e-16f));
    const float sim = (sW12t[tid]*invd) * __builtin_amdgcn_rcpf(fmaxf(sCapN[tid]*w2, EPSF));
    sEt[tid] = (tid < nw) ? exp2f((LLSE*LOG2E)*sim) : 0.f;
  }
  if (tid >= 64 && tid < 64+RN) {
    const int r = tid - 64;
    const float invd = sInvI[r];
    const float w2 = sqrtf(fmaxf(sQqI[r]*invd*invd, 1e-16f));
    const float sim = (sW12i[r]*invd) * __builtin_amdgcn_rcpf(fmaxf(sImgN[r]*w2, EPSF));
    sEi[r] = exp2f((LLSE*LOG2E)*sim);
  }
  __syncthreads();
  if (wv == 0) {
    float e = (lane < LN) ? sEt[lane] : 0.f;
    #pragma unroll
    for (int o = 32; o > 0; o >>= 1) e += __shfl_xor(e, o);
    if (lane == 0) sRed[0] = e;
  } else if (wv == 1) {
    float e = (lane < RN) ? sEi[lane] : 0.f;
    #pragma unroll
    for (int o = 32; o > 0; o >>= 1) e += __shfl_xor(e, o);
    if (lane == 0) sRed[1] = e;
  }
  __syncthreads();
  if (tid == 0)
    scores[(size_t)it*CN + c] = log2f(sRed[0]*sRed[1]) * (1.f/(LLSE*LOG2E));
}

// ---------------- Kernel 4: margin ranking loss ----------------
__global__ __launch_bounds__(128) void loss_kernel(
    const float* __restrict__ S, float* __restrict__ out)
{
  __shared__ float red[128];
  const int t = threadIdx.x;
  const float d = S[t*CN + t];
  float m1 = -1e30f, m2 = -1e30f;
  for (int cc = 0; cc < CN; ++cc)
    if (cc != t) m1 = fmaxf(m1, 0.2f + S[t*CN+cc] - d);
  for (int i2 = 0; i2 < INN; ++i2)
    if (i2 != t) m2 = fmaxf(m2, 0.2f + S[i2*CN+t] - d);
  red[t] = fmaxf(m1, 0.f) + fmaxf(m2, 0.f);
  __syncthreads();
  for (int s = 64; s > 0; s >>= 1) {
    if (t < s) red[t] += red[t+s];
    __syncthreads();
  }
  if (t == 0) out[0] = red[0];
}

extern "C" void kernel_launch(void* const* d_in, const int* in_sizes, int n_in,
                              void* d_out, int out_size, void* d_ws, size_t ws_size,
                              hipStream_t stream) {
  (void)in_sizes; (void)n_in; (void)out_size;
  const float* imgs = (const float*)d_in[0];
  const float* caps = (const float*)d_in[1];
  const int*   lens = (const int*)d_in[2];

  const size_t bfUS = 2*((size_t)MT + NT)*DN;   // layout unchanged (lo slots unused)
  const size_t gbUS = (size_t)(INN + CN)*3072;
  const size_t smallF = (size_t)INN*RN*RN + INN*RN + (size_t)CN*LN*LN + CN*LN + (size_t)INN*CN;
  int g = CN;
  while (g > 8) {
    const size_t need = (bfUS + gbUS)*2 + (smallF + (size_t)g*LN*NT)*4;
    if (need <= ws_size) break;
    g >>= 1;
  }

  ushort* aHi = (ushort*)d_ws;
  ushort* aLo = aHi + (size_t)MT*DN;   // unused
  ushort* bHi = aLo + (size_t)MT*DN;
  ushort* bLo = bHi + (size_t)NT*DN;   // unused
  ushort* gIb = bLo + (size_t)NT*DN;
  ushort* gCb = gIb + (size_t)INN*3072;
  float* fbase = (float*)(gCb + (size_t)CN*3072);
  float* gI     = fbase;
  float* nI     = gI + (size_t)INN*RN*RN;
  float* gC     = nI + (size_t)INN*RN;
  float* nC     = gC + (size_t)CN*LN*LN;
  float* scores = nC + (size_t)CN*LN;
  float* dots   = scores + (size_t)INN*CN;

  gram_conv_kernel<<<dim3(INN+CN), dim3(256), 0, stream>>>(
      imgs, caps, gI, nI, gC, nC, aHi, bHi, gIb, gCb);
  for (int c0 = 0; c0 < CN; c0 += g) {
    dots_gemm_mfma<<<dim3(NT/128, g*LN/128), dim3(256), 0, stream>>>(
        aHi, bHi, dots, c0*LN);
    attn_kernel<<<dim3(INN, g), dim3(256), 0, stream>>>(
        dots, lens, gIb, gCb, nI, nC, scores, c0);
  }
  loss_kernel<<<dim3(1), dim3(128), 0, stream>>>(scores, (float*)d_out);
}

// Round 22
// 277.899 us; speedup vs baseline: 1.4127x; 1.0551x over previous
//
#include <hip/hip_runtime.h>
#include <math.h>

#define CN 128   // captions
#define INN 128  // images
#define LN 48    // words
#define RN 36    // regions
#define DN 1024  // feature dim
#define RTA 36   // regions per attn block (TIA=1)
#define MT 6144  // CN*LN
#define NT 4608  // INN*RN
#define EPSF 1e-8f
#define LSM 9.0f
#define LLSE 6.0f
#define LOG2E 1.4426950408889634f

__device__ __forceinline__ float leaky(float x){ return x > 0.f ? x : 0.1f*x; }
__device__ __forceinline__ float dot4(float4 a, float4 b){
  return a.x*b.x + a.y*b.y + a.z*b.z + a.w*b.w;
}

typedef const __attribute__((address_space(1))) unsigned int* gp_t;
typedef __attribute__((address_space(3))) unsigned int* lp_t;
__device__ __forceinline__ void gload16u(const ushort* g, ushort* l) {
  __builtin_amdgcn_global_load_lds((gp_t)g, (lp_t)l, 16, 0, 0);
}

typedef short s16x8 __attribute__((ext_vector_type(8)));
typedef float f32x4 __attribute__((ext_vector_type(4)));

__device__ __forceinline__ ushort bf16rne(float f) {
  const unsigned u = __float_as_uint(f);
  return (ushort)((u + 0x7fffu + ((u>>16)&1u)) >> 16);
}
__device__ __forceinline__ float bf2f(ushort u) {
  return __uint_as_float((unsigned)u << 16);
}
// XOR swizzle within a 64-elem bf16 row (8-elem granules): 2-way max bank alias
__device__ __forceinline__ int swzi(int row, int col) {
  return (col & 7) | ((((col >> 3) ^ (row & 7)) & 7) << 3);
}

// ---------------- Kernel 1: Gram + norms + bf16 emission (hi planes only) ----------
__global__ __launch_bounds__(256) void gram_conv_kernel(
    const float* __restrict__ imgs, const float* __restrict__ caps,
    float* __restrict__ gI, float* __restrict__ nI,
    float* __restrict__ gC, float* __restrict__ nC,
    ushort* __restrict__ aHi, ushort* __restrict__ bHi,
    ushort* __restrict__ gIb, ushort* __restrict__ gCb)
{
  __shared__ __align__(16) float L[LN*132];
  const int b = blockIdx.x, tid = threadIdx.x;
  if (b < INN) {
    const float* base = imgs + (size_t)b*RN*DN;
    const int rg = tid/12, cg = tid - (tid/12)*12;
    const bool active = tid < 216;
    float a[2][3];
    #pragma unroll
    for (int u = 0; u < 2; ++u)
      #pragma unroll
      for (int v = 0; v < 3; ++v) a[u][v] = 0.f;
    for (int d0 = 0; d0 < DN; d0 += 128) {
      __syncthreads();
      for (int idx = tid; idx < RN*32; idx += 256) {
        const int row = idx >> 5, ch = idx & 31;
        const float4 v = *(const float4*)(base + row*DN + d0 + ch*4);
        *(float4*)&L[row*132 + ch*4] = v;
        const size_t off = (size_t)(b*RN + row)*DN + d0 + ch*4;
        *(ushort4*)(bHi + off) = make_ushort4(
            bf16rne(v.x), bf16rne(v.y), bf16rne(v.z), bf16rne(v.w));
      }
      __syncthreads();
      if (active) {
        const float* r0 = &L[(2*rg)*132],   * r1 = &L[(2*rg+1)*132];
        const float* c0 = &L[(3*cg)*132],   * c1 = &L[(3*cg+1)*132], * c2 = &L[(3*cg+2)*132];
        #pragma unroll
        for (int k = 0; k < 32; ++k) {
          const float4 x0 = *(const float4*)(r0 + k*4);
          const float4 x1 = *(const float4*)(r1 + k*4);
          const float4 y0 = *(const float4*)(c0 + k*4);
          const float4 y1 = *(const float4*)(c1 + k*4);
          const float4 y2 = *(const float4*)(c2 + k*4);
          a[0][0] += dot4(x0,y0); a[0][1] += dot4(x0,y1); a[0][2] += dot4(x0,y2);
          a[1][0] += dot4(x1,y0); a[1][1] += dot4(x1,y1); a[1][2] += dot4(x1,y2);
        }
      }
    }
    if (active) {
      float* gb = gI + (size_t)b*RN*RN;
      #pragma unroll
      for (int u = 0; u < 2; ++u)
        #pragma unroll
        for (int v = 0; v < 3; ++v) {
          const int r = 2*rg + u, s = 3*cg + v;
          gb[r*RN + s] = a[u][v];
          if (r == s) nI[b*RN + r] = sqrtf(fmaxf(a[u][v], 1e-16f));
        }
    }
    __threadfence_block();
    __syncthreads();
    const float* gsrc = gI + (size_t)b*RN*RN;
    ushort* gdst = gIb + (size_t)b*3072;
    for (int idx = tid; idx < 3072; idx += 256) {
      const int row = idx >> 6, col = idx & 63;
      gdst[idx] = (row < RN && col < RN) ? bf16rne(gsrc[row*RN + col]) : (ushort)0;
    }
  } else {
    const int c = b - INN;
    const float* base = caps + (size_t)c*LN*DN;
    const int rg = tid >> 4, cg = tid & 15;
    float a[3][3];
    #pragma unroll
    for (int u = 0; u < 3; ++u)
      #pragma unroll
      for (int v = 0; v < 3; ++v) a[u][v] = 0.f;
    for (int d0 = 0; d0 < DN; d0 += 128) {
      __syncthreads();
      for (int idx = tid; idx < LN*32; idx += 256) {
        const int row = idx >> 5, ch = idx & 31;
        const float4 v = *(const float4*)(base + row*DN + d0 + ch*4);
        *(float4*)&L[row*132 + ch*4] = v;
        const size_t off = (size_t)(c*LN + row)*DN + d0 + ch*4;
        *(ushort4*)(aHi + off) = make_ushort4(
            bf16rne(v.x), bf16rne(v.y), bf16rne(v.z), bf16rne(v.w));
      }
      __syncthreads();
      const float* r0 = &L[(3*rg)*132],   * r1 = &L[(3*rg+1)*132], * r2 = &L[(3*rg+2)*132];
      const float* c0 = &L[(3*cg)*132],   * c1 = &L[(3*cg+1)*132], * c2 = &L[(3*cg+2)*132];
      #pragma unroll
      for (int k = 0; k < 32; ++k) {
        const float4 x0 = *(const float4*)(r0 + k*4);
        const float4 x1 = *(const float4*)(r1 + k*4);
        const float4 x2 = *(const float4*)(r2 + k*4);
        const float4 y0 = *(const float4*)(c0 + k*4);
        const float4 y1 = *(const float4*)(c1 + k*4);
        const float4 y2 = *(const float4*)(c2 + k*4);
        a[0][0] += dot4(x0,y0); a[0][1] += dot4(x0,y1); a[0][2] += dot4(x0,y2);
        a[1][0] += dot4(x1,y0); a[1][1] += dot4(x1,y1); a[1][2] += dot4(x1,y2);
        a[2][0] += dot4(x2,y0); a[2][1] += dot4(x2,y1); a[2][2] += dot4(x2,y2);
      }
    }
    float* gb = gC + (size_t)c*LN*LN;
    #pragma unroll
    for (int u = 0; u < 3; ++u)
      #pragma unroll
      for (int v = 0; v < 3; ++v) {
        const int r = 3*rg + u, s = 3*cg + v;
        gb[r*LN + s] = a[u][v];
        if (r == s) nC[c*LN + r] = sqrtf(fmaxf(a[u][v], 1e-16f));
      }
    __threadfence_block();
    __syncthreads();
    const float* gsrc = gC + (size_t)c*LN*LN;
    ushort* gdst = gCb + (size_t)c*3072;
    for (int idx = tid; idx < 3072; idx += 256) {
      const int row = idx >> 6, col = idx & 63;
      gdst[idx] = (col < LN) ? bf16rne(gsrc[row*LN + col]) : (ushort)0;
    }
  }
}

// ---------------- Kernel 2: dots GEMM via bf16 MFMA, BK=64 ----------------
// R22: BK 32->64 — 16 K-iterations (was 32), halving the vmcnt(0)+barrier
// drains. LDS 32KB (A,B tiles [128][64]); accumulation order unchanged
// (k ascending) => bit-identical output. Row stride 128B, granule ^= row&7
// swizzle keeps ds_read_b128 at 2-way (free).
__global__ __launch_bounds__(256) void dots_gemm_mfma(
    const ushort* __restrict__ aHi, const ushort* __restrict__ bHi,
    float* __restrict__ dots, int arow0)
{
  __shared__ __align__(16) ushort sT[16384];   // Ah [0,8192) Bh [8192,16384)
  const int tid = threadIdx.x;
  const int wv = tid >> 6, lane = tid & 63;
  const int l15 = lane & 15, kg = lane >> 4;
  const int wr = wv >> 1, wc = wv & 1;
  const int M0 = blockIdx.y * 128;
  const int N0 = blockIdx.x * 128;

  // fragment LDS offsets: row*64 + ((ks*4+kg)^(row&7))*8, ks in {0,1}
  int offA[4], offB[4];
  #pragma unroll
  for (int f = 0; f < 4; ++f) {
    offA[f] = (wr*64 + f*16 + l15)*64;
    offB[f] = (wc*64 + f*16 + l15)*64;
  }
  // staging: 4 chunks per plane per thread; chunk ch = h*256+tid, row=ch>>3, gp=ch&7
  int srow[4], sgk[4]; unsigned dOff[4];
  #pragma unroll
  for (int h = 0; h < 4; ++h) {
    const int ch = h*256 + tid;
    const int row = ch >> 3, gp = ch & 7;
    srow[h] = row;
    sgk[h] = (gp ^ (row & 7)) * 8;
    dOff[h] = (unsigned)(h*256 + wv*64) * 8;   // wave-uniform base, lane*16B auto
  }

  f32x4 acc[4][4];
  #pragma unroll
  for (int mf = 0; mf < 4; ++mf)
    #pragma unroll
    for (int nf = 0; nf < 4; ++nf) acc[mf][nf] = (f32x4){0.f,0.f,0.f,0.f};

  const size_t aR = (size_t)(arow0 + M0);
  for (int k0 = 0; k0 < DN; k0 += 64) {
    __syncthreads();
    #pragma unroll
    for (int h = 0; h < 4; ++h) {
      const size_t ao = (aR + srow[h])*DN + k0 + sgk[h];
      const size_t bo = ((size_t)(N0 + srow[h]))*DN + k0 + sgk[h];
      gload16u(aHi + ao, sT + dOff[h]);
      gload16u(bHi + bo, sT + 8192 + dOff[h]);
    }
    asm volatile("s_waitcnt vmcnt(0)" ::: "memory");
    __syncthreads();
    #pragma unroll
    for (int ks = 0; ks < 2; ++ks) {
      s16x8 ah[4], bh[4];
      #pragma unroll
      for (int f = 0; f < 4; ++f) {
        const int rA = wr*64 + f*16 + l15;
        const int rB = wc*64 + f*16 + l15;
        ah[f] = *(const s16x8*)&sT[offA[f] + (((ks*4+kg) ^ (rA&7)))*8];
        bh[f] = *(const s16x8*)&sT[8192 + offB[f] + (((ks*4+kg) ^ (rB&7)))*8];
      }
      #pragma unroll
      for (int mf = 0; mf < 4; ++mf)
        #pragma unroll
        for (int nf = 0; nf < 4; ++nf)
          acc[mf][nf] = __builtin_amdgcn_mfma_f32_16x16x32_bf16(ah[mf], bh[nf], acc[mf][nf], 0,0,0);
    }
  }
  #pragma unroll
  for (int mf = 0; mf < 4; ++mf)
    #pragma unroll
    for (int nf = 0; nf < 4; ++nf) {
      const int n = N0 + wc*64 + nf*16 + l15;
      #pragma unroll
      for (int r = 0; r < 4; ++r) {
        const int m = M0 + wr*64 + mf*16 + kg*4 + r;
        dots[(size_t)m*NT + n] = acc[mf][nf][r];
      }
    }
}

// ---------------- Kernel 3: attention (R21 version, unchanged) ----------------
__global__ __launch_bounds__(256) void attn_kernel(
    const float* __restrict__ dots, const int* __restrict__ cap_lens,
    const ushort* __restrict__ gIb, const ushort* __restrict__ gCb,
    const float* __restrict__ nI, const float* __restrict__ nC,
    float* __restrict__ scores, int cbase)
{
  __shared__ float sDots[LN][RTA+1];                  // 48 x 37
  __shared__ __align__(16) ushort sMeT[LN*64];        // [l][r] swizzled (Me_t rows)
  __shared__ __align__(16) ushort sMeIT[48*64];       // [r][l] swizzled (Me_i^T rows)
  __shared__ float sQqT[LN], sQqI[48];
  __shared__ float sW12t[LN], sInvT[LN];
  __shared__ float sW12i[RN], sInvI[RN];
  __shared__ float sColInv[RN], sRowInv[LN];
  __shared__ float sCapN[LN], sImgN[RN];
  __shared__ float sEt[LN], sEi[RN];
  __shared__ float sRed[2];

  const int cl = blockIdx.y;
  const int c  = cbase + cl;
  const int it = blockIdx.x;
  const int tid = threadIdx.x;
  const int lane = tid & 63, wv = tid >> 6;
  const int l15 = lane & 15, kg = lane >> 4;
  const int team = tid >> 2, q4 = tid & 3;
  const int nw = cap_lens[c];
  const float nwf = (float)nw;

  // ---- Phase A: stage dots + zero Me ----
  for (int idx = tid; idx < LN*RTA/4; idx += 256) {
    const int l = idx / (RTA/4), jseg = idx - l*(RTA/4);
    const float4 v = *(const float4*)(dots + ((size_t)cl*LN + l)*NT + (size_t)it*RTA + jseg*4);
    float* dst = &sDots[l][jseg*4];
    dst[0]=v.x; dst[1]=v.y; dst[2]=v.z; dst[3]=v.w;
  }
  for (int idx = tid; idx < 768; idx += 256) {
    if (idx < 384) ((uint4*)sMeT)[idx] = make_uint4(0,0,0,0);
    else ((uint4*)sMeIT)[idx-384] = make_uint4(0,0,0,0);
  }
  if (tid < LN) { sCapN[tid] = nC[c*LN + tid]; sQqT[tid] = 0.f; }
  if (tid >= 64 && tid < 64+48) sQqI[tid-64] = 0.f;
  if (tid >= 128 && tid < 128+RN) sImgN[tid-128] = nI[it*RN + (tid-128)];
  __syncthreads();

  // ---- norms: team-parallel, two 64-team passes (log2e folded) ----
  #pragma unroll 1
  for (int pass = 0; pass < 2; ++pass) {
    const int vrow = pass*64 + team;
    if (vrow < RN) {
      float s = 0.f;
      #pragma unroll
      for (int j = 0; j < 12; ++j) { const float v = leaky(sDots[q4*12+j][vrow]); s += v*v; }
      s += __shfl_xor(s, 1, 4); s += __shfl_xor(s, 2, 4);
      if (q4 == 0) sColInv[vrow] = (LSM*LOG2E) * __builtin_amdgcn_rcpf(sqrtf(s) + EPSF);
    } else if (vrow < RN + LN) {
      const int l = vrow - RN;
      float s = 0.f;
      #pragma unroll
      for (int j = 0; j < 9; ++j) { const float v = leaky(sDots[l][q4*9+j]); s += v*v; }
      s += __shfl_xor(s, 1, 4); s += __shfl_xor(s, 2, 4);
      if (q4 == 0) sRowInv[l] = (LSM*LOG2E) * __builtin_amdgcn_rcpf(sqrtf(s) + EPSF);
    }
  }
  __syncthreads();

  // ---- Phase B: me rows (one row per 4-lane team; R8: do NOT re-batch) ----
  #pragma unroll 1
  for (int pass = 0; pass < 2; ++pass) {
    const int vrow = pass*64 + team;
    if (vrow < LN) {
      const int l = vrow;
      const int cb = q4*9;
      float d9[9], x9[9];
      #pragma unroll
      for (int j = 0; j < 9; ++j) d9[j] = sDots[l][cb + j];
      float se = 0.f;
      #pragma unroll
      for (int j = 0; j < 9; ++j) {
        const float e = exp2f(leaky(d9[j]) * sColInv[cb + j]);
        x9[j] = e; se += e;
      }
      se += __shfl_xor(se, 1, 4); se += __shfl_xor(se, 2, 4);
      float ts = 0.f;
      #pragma unroll
      for (int j = 0; j < 9; ++j) {
        const float me = (x9[j]*36.f > se) ? x9[j] : 0.f;
        x9[j] = me; ts += me;
      }
      ts += __shfl_xor(ts, 1, 4); ts += __shfl_xor(ts, 2, 4);
      float w12 = 0.f;
      #pragma unroll
      for (int j = 0; j < 9; ++j) w12 += x9[j]*d9[j];
      w12 += __shfl_xor(w12, 1, 4); w12 += __shfl_xor(w12, 2, 4);
      #pragma unroll
      for (int j = 0; j < 9; ++j)
        sMeT[l*64 + swzi(l, cb + j)] = bf16rne(x9[j]);
      if (q4 == 0) {
        sW12t[l] = w12;
        sInvT[l] = __builtin_amdgcn_rcpf((ts > 0.f) ? ts : 1.f);
      }
    } else {
      const int r = vrow - LN;
      if (r < RN) {
        float d12[12], x12[12];
        #pragma unroll
        for (int j = 0; j < 12; ++j) d12[j] = sDots[q4*12+j][r];
        float se = 0.f;
        #pragma unroll
        for (int j = 0; j < 12; ++j) {
          const int l = q4*12 + j;
          const float e = (l < nw) ? exp2f(leaky(d12[j]) * sRowInv[l]) : 0.f;
          x12[j] = e; se += e;
        }
        se += __shfl_xor(se, 1, 4); se += __shfl_xor(se, 2, 4);
        float ts = 0.f;
        #pragma unroll
        for (int j = 0; j < 12; ++j) {
          const float me = (x12[j]*nwf > se) ? x12[j] : 0.f;
          x12[j] = me; ts += me;
        }
        ts += __shfl_xor(ts, 1, 4); ts += __shfl_xor(ts, 2, 4);
        float w12 = 0.f;
        #pragma unroll
        for (int j = 0; j < 12; ++j) w12 += x12[j]*d12[j];
        w12 += __shfl_xor(w12, 1, 4); w12 += __shfl_xor(w12, 2, 4);
        #pragma unroll
        for (int j = 0; j < 12; ++j)
          sMeIT[r*64 + swzi(r, q4*12 + j)] = bf16rne(x12[j]);
        if (q4 == 0) {
          sW12i[r] = w12;
          sInvI[r] = __builtin_amdgcn_rcpf((ts > 0.f) ? ts : 1.f);
        }
      }
    }
  }
  __syncthreads();

  // ---- Phase C: qq via MFMA, unified paths ----
  const ushort* gIbase = gIb + (size_t)it*3072;
  const ushort* gCbase = gCb + (size_t)c*3072;
  #pragma unroll 1
  for (int t = wv; t < 18; t += 4) {
    const bool isT = (t < 9);
    const int tt = isT ? t : t - 9;
    const int mt = tt / 3, nt = tt - 3*(tt/3);
    const ushort* Ab = isT ? gIbase : gCbase;
    const ushort* Mb = isT ? sMeT   : sMeIT;
    const int arow = mt*16 + l15;
    const int brow = nt*16 + l15;
    f32x4 acc = (f32x4){0.f,0.f,0.f,0.f};
    #pragma unroll
    for (int ks = 0; ks < 2; ++ks) {
      const s16x8 af = *(const s16x8*)(Ab + arow*64 + (ks*4+kg)*8);
      const s16x8 bf = *(const s16x8*)&Mb[brow*64 + (((ks*4+kg) ^ (brow&7)))*8];
      acc = __builtin_amdgcn_mfma_f32_16x16x32_bf16(af, bf, acc, 0,0,0);
    }
    float part = 0.f;
    #pragma unroll
    for (int rg = 0; rg < 4; ++rg) {
      const int orow = mt*16 + kg*4 + rg;
      part += acc[rg] * bf2f(Mb[brow*64 + swzi(brow, orow)]);
    }
    part += __shfl_xor(part, 16);
    part += __shfl_xor(part, 32);
    if (lane < 16)
      atomicAdd(isT ? &sQqT[nt*16 + l15] : &sQqI[nt*16 + l15], part);
  }
  __syncthreads();

  // ---- Epilogue (exp2/log2 with folded constants) ----
  if (tid < LN) {
    const float invd = sInvT[tid];
    const float w2 = sqrtf(fmaxf(sQqT[tid]*invd*invd, 1e-16f));
    const float sim = (sW12t[tid]*invd) * __builtin_amdgcn_rcpf(fmaxf(sCapN[tid]*w2, EPSF));
    sEt[tid] = (tid < nw) ? exp2f((LLSE*LOG2E)*sim) : 0.f;
  }
  if (tid >= 64 && tid < 64+RN) {
    const int r = tid - 64;
    const float invd = sInvI[r];
    const float w2 = sqrtf(fmaxf(sQqI[r]*invd*invd, 1e-16f));
    const float sim = (sW12i[r]*invd) * __builtin_amdgcn_rcpf(fmaxf(sImgN[r]*w2, EPSF));
    sEi[r] = exp2f((LLSE*LOG2E)*sim);
  }
  __syncthreads();
  if (wv == 0) {
    float e = (lane < LN) ? sEt[lane] : 0.f;
    #pragma unroll
    for (int o = 32; o > 0; o >>= 1) e += __shfl_xor(e, o);
    if (lane == 0) sRed[0] = e;
  } else if (wv == 1) {
    float e = (lane < RN) ? sEi[lane] : 0.f;
    #pragma unroll
    for (int o = 32; o > 0; o >>= 1) e += __shfl_xor(e, o);
    if (lane == 0) sRed[1] = e;
  }
  __syncthreads();
  if (tid == 0)
    scores[(size_t)it*CN + c] = log2f(sRed[0]*sRed[1]) * (1.f/(LLSE*LOG2E));
}

// ---------------- Kernel 4: margin ranking loss ----------------
__global__ __launch_bounds__(128) void loss_kernel(
    const float* __restrict__ S, float* __restrict__ out)
{
  __shared__ float red[128];
  const int t = threadIdx.x;
  const float d = S[t*CN + t];
  float m1 = -1e30f, m2 = -1e30f;
  for (int cc = 0; cc < CN; ++cc)
    if (cc != t) m1 = fmaxf(m1, 0.2f + S[t*CN+cc] - d);
  for (int i2 = 0; i2 < INN; ++i2)
    if (i2 != t) m2 = fmaxf(m2, 0.2f + S[i2*CN+t] - d);
  red[t] = fmaxf(m1, 0.f) + fmaxf(m2, 0.f);
  __syncthreads();
  for (int s = 64; s > 0; s >>= 1) {
    if (t < s) red[t] += red[t+s];
    __syncthreads();
  }
  if (t == 0) out[0] = red[0];
}

extern "C" void kernel_launch(void* const* d_in, const int* in_sizes, int n_in,
                              void* d_out, int out_size, void* d_ws, size_t ws_size,
                              hipStream_t stream) {
  (void)in_sizes; (void)n_in; (void)out_size;
  const float* imgs = (const float*)d_in[0];
  const float* caps = (const float*)d_in[1];
  const int*   lens = (const int*)d_in[2];

  const size_t bfUS = 2*((size_t)MT + NT)*DN;   // layout unchanged (lo slots unused)
  const size_t gbUS = (size_t)(INN + CN)*3072;
  const size_t smallF = (size_t)INN*RN*RN + INN*RN + (size_t)CN*LN*LN + CN*LN + (size_t)INN*CN;
  int g = CN;
  while (g > 8) {
    const size_t need = (bfUS + gbUS)*2 + (smallF + (size_t)g*LN*NT)*4;
    if (need <= ws_size) break;
    g >>= 1;
  }

  ushort* aHi = (ushort*)d_ws;
  ushort* aLo = aHi + (size_t)MT*DN;   // unused
  ushort* bHi = aLo + (size_t)MT*DN;
  ushort* bLo = bHi + (size_t)NT*DN;   // unused
  ushort* gIb = bLo + (size_t)NT*DN;
  ushort* gCb = gIb + (size_t)INN*3072;
  float* fbase = (float*)(gCb + (size_t)CN*3072);
  float* gI     = fbase;
  float* nI     = gI + (size_t)INN*RN*RN;
  float* gC     = nI + (size_t)INN*RN;
  float* nC     = gC + (size_t)CN*LN*LN;
  float* scores = nC + (size_t)CN*LN;
  float* dots   = scores + (size_t)INN*CN;

  gram_conv_kernel<<<dim3(INN+CN), dim3(256), 0, stream>>>(
      imgs, caps, gI, nI, gC, nC, aHi, bHi, gIb, gCb);
  for (int c0 = 0; c0 < CN; c0 += g) {
    dots_gemm_mfma<<<dim3(NT/128, g*LN/128), dim3(256), 0, stream>>>(
        aHi, bHi, dots, c0*LN);
    attn_kernel<<<dim3(INN, g), dim3(256), 0, stream>>>(
        dots, lens, gIb, gCb, nI, nC, scores, c0);
  }
  loss_kernel<<<dim3(1), dim3(128), 0, stream>>>(scores, (float*)d_out);
}

// Round 23
// 250.169 us; speedup vs baseline: 1.5692x; 1.1108x over previous
//
#include <hip/hip_runtime.h>
#include <math.h>

#define CN 128   // captions
#define INN 128  // images
#define LN 48    // words
#define RN 36    // regions
#define DN 1024  // feature dim
#define RTA 36   // regions per attn block (TIA=1)
#define MT 6144  // CN*LN
#define NT 4608  // INN*RN
#define EPSF 1e-8f
#define LSM 9.0f
#define LLSE 6.0f
#define LOG2E 1.4426950408889634f

__device__ __forceinline__ float leaky(float x){ return x > 0.f ? x : 0.1f*x; }

typedef const __attribute__((address_space(1))) unsigned int* gp_t;
typedef __attribute__((address_space(3))) unsigned int* lp_t;
__device__ __forceinline__ void gload16u(const ushort* g, ushort* l) {
  __builtin_amdgcn_global_load_lds((gp_t)g, (lp_t)l, 16, 0, 0);
}

typedef short s16x8 __attribute__((ext_vector_type(8)));
typedef float f32x4 __attribute__((ext_vector_type(4)));

__device__ __forceinline__ ushort bf16rne(float f) {
  const unsigned u = __float_as_uint(f);
  return (ushort)((u + 0x7fffu + ((u>>16)&1u)) >> 16);
}
__device__ __forceinline__ float bf2f(ushort u) {
  return __uint_as_float((unsigned)u << 16);
}
// XOR swizzle within a 64-elem bf16 row (8-elem granules): 2-way max bank alias
__device__ __forceinline__ int swzi(int row, int col) {
  return (col & 7) | ((((col >> 3) ^ (row & 7)) & 7) << 3);
}

// ---------------- Kernel 0: fp32 -> bf16 planes (pure streaming) ----------------
__global__ __launch_bounds__(256) void conv_kernel(
    const float* __restrict__ caps, const float* __restrict__ imgs,
    ushort* __restrict__ aHi, ushort* __restrict__ bHi)
{
  const int NA = MT*DN/4, NB = NT*DN/4;
  for (int i = blockIdx.x*256 + threadIdx.x; i < NA + NB; i += gridDim.x*256) {
    const float4 v = (i < NA) ? ((const float4*)caps)[i] : ((const float4*)imgs)[i - NA];
    const ushort4 h = make_ushort4(bf16rne(v.x), bf16rne(v.y), bf16rne(v.z), bf16rne(v.w));
    if (i < NA) ((ushort4*)aHi)[i] = h;
    else        ((ushort4*)bHi)[i-NA] = h;
  }
}

// ---------------- Kernel 1: Gram via MFMA from bf16 planes ----------------
// G = X * X^T (symmetric: A and B fragments read the SAME LDS rows; layout
// identical to attn Phase C, verified). Rows >= R are stale LDS — they only
// affect output rows/cols >= R, which are masked to 0. Diag -> norms.
__global__ __launch_bounds__(256) void gram_mfma_kernel(
    const ushort* __restrict__ aHi, const ushort* __restrict__ bHi,
    float* __restrict__ nI, float* __restrict__ nC,
    ushort* __restrict__ gIb, ushort* __restrict__ gCb)
{
  __shared__ __align__(16) ushort sX[48*64];   // 6KB, granule-swizzled
  const int b = blockIdx.x, tid = threadIdx.x;
  const bool isImg = b < INN;
  const int R = isImg ? RN : LN;
  const ushort* X = isImg ? (bHi + (size_t)b*RN*DN) : (aHi + (size_t)(b-INN)*LN*DN);
  ushort* gOut = isImg ? (gIb + (size_t)b*3072) : (gCb + (size_t)(b-INN)*3072);
  float* nOut = isImg ? (nI + b*RN) : (nC + (b-INN)*LN);
  const int lane = tid & 63, wv = tid >> 6;
  const int l15 = lane & 15, kg = lane >> 4;

  f32x4 acc[3];
  #pragma unroll
  for (int i = 0; i < 3; ++i) acc[i] = (f32x4){0.f,0.f,0.f,0.f};

  for (int k0 = 0; k0 < DN; k0 += 64) {
    __syncthreads();
    for (int idx = tid; idx < R*8; idx += 256) {      // stage rows 0..R-1, swizzled
      const int row = idx >> 3, gp = idx & 7;
      *(uint4*)&sX[row*64 + (gp ^ (row&7))*8] =
        *(const uint4*)(X + (size_t)row*DN + k0 + gp*8);
    }
    __syncthreads();
    #pragma unroll
    for (int i = 0; i < 3; ++i) {
      const int tt = wv + 4*i;
      if (tt < 9) {
        const int mt = tt/3, nt = tt - 3*(tt/3);
        #pragma unroll
        for (int ks = 0; ks < 2; ++ks) {
          const int rA = mt*16 + l15, rB = nt*16 + l15;
          const s16x8 af = *(const s16x8*)&sX[rA*64 + (((ks*4+kg) ^ (rA&7)))*8];
          const s16x8 bf = *(const s16x8*)&sX[rB*64 + (((ks*4+kg) ^ (rB&7)))*8];
          acc[i] = __builtin_amdgcn_mfma_f32_16x16x32_bf16(af, bf, acc[i], 0,0,0);
        }
      }
    }
  }
  // epilogue: C[m][n] with m = mt*16+kg*4+rg, n = nt*16+l15 (verified map)
  #pragma unroll
  for (int i = 0; i < 3; ++i) {
    const int tt = wv + 4*i;
    if (tt < 9) {
      const int mt = tt/3, nt = tt - 3*(tt/3);
      #pragma unroll
      for (int rg = 0; rg < 4; ++rg) {
        const int m = mt*16 + kg*4 + rg, n = nt*16 + l15;
        const float cv = acc[i][rg];
        gOut[m*64 + n] = (m < R && n < R) ? bf16rne(cv) : (ushort)0;
        if (m == n && m < R) nOut[m] = sqrtf(fmaxf(cv, 1e-16f));
      }
    }
  }
  for (int idx = tid; idx < 48*16; idx += 256) {      // zero pad cols 48..63
    const int row = idx >> 4, col = 48 + (idx & 15);
    gOut[row*64 + col] = 0;
  }
}

// ---------------- Kernel 2: dots GEMM via bf16 MFMA, BK=64 (unchanged) ----------
__global__ __launch_bounds__(256) void dots_gemm_mfma(
    const ushort* __restrict__ aHi, const ushort* __restrict__ bHi,
    float* __restrict__ dots, int arow0)
{
  __shared__ __align__(16) ushort sT[16384];   // Ah [0,8192) Bh [8192,16384)
  const int tid = threadIdx.x;
  const int wv = tid >> 6, lane = tid & 63;
  const int l15 = lane & 15, kg = lane >> 4;
  const int wr = wv >> 1, wc = wv & 1;
  const int M0 = blockIdx.y * 128;
  const int N0 = blockIdx.x * 128;

  int offA[4], offB[4];
  #pragma unroll
  for (int f = 0; f < 4; ++f) {
    offA[f] = (wr*64 + f*16 + l15)*64;
    offB[f] = (wc*64 + f*16 + l15)*64;
  }
  int srow[4], sgk[4]; unsigned dOff[4];
  #pragma unroll
  for (int h = 0; h < 4; ++h) {
    const int ch = h*256 + tid;
    const int row = ch >> 3, gp = ch & 7;
    srow[h] = row;
    sgk[h] = (gp ^ (row & 7)) * 8;
    dOff[h] = (unsigned)(h*256 + wv*64) * 8;
  }

  f32x4 acc[4][4];
  #pragma unroll
  for (int mf = 0; mf < 4; ++mf)
    #pragma unroll
    for (int nf = 0; nf < 4; ++nf) acc[mf][nf] = (f32x4){0.f,0.f,0.f,0.f};

  const size_t aR = (size_t)(arow0 + M0);
  for (int k0 = 0; k0 < DN; k0 += 64) {
    __syncthreads();
    #pragma unroll
    for (int h = 0; h < 4; ++h) {
      const size_t ao = (aR + srow[h])*DN + k0 + sgk[h];
      const size_t bo = ((size_t)(N0 + srow[h]))*DN + k0 + sgk[h];
      gload16u(aHi + ao, sT + dOff[h]);
      gload16u(bHi + bo, sT + 8192 + dOff[h]);
    }
    asm volatile("s_waitcnt vmcnt(0)" ::: "memory");
    __syncthreads();
    #pragma unroll
    for (int ks = 0; ks < 2; ++ks) {
      s16x8 ah[4], bh[4];
      #pragma unroll
      for (int f = 0; f < 4; ++f) {
        const int rA = wr*64 + f*16 + l15;
        const int rB = wc*64 + f*16 + l15;
        ah[f] = *(const s16x8*)&sT[offA[f] + (((ks*4+kg) ^ (rA&7)))*8];
        bh[f] = *(const s16x8*)&sT[8192 + offB[f] + (((ks*4+kg) ^ (rB&7)))*8];
      }
      #pragma unroll
      for (int mf = 0; mf < 4; ++mf)
        #pragma unroll
        for (int nf = 0; nf < 4; ++nf)
          acc[mf][nf] = __builtin_amdgcn_mfma_f32_16x16x32_bf16(ah[mf], bh[nf], acc[mf][nf], 0,0,0);
    }
  }
  #pragma unroll
  for (int mf = 0; mf < 4; ++mf)
    #pragma unroll
    for (int nf = 0; nf < 4; ++nf) {
      const int n = N0 + wc*64 + nf*16 + l15;
      #pragma unroll
      for (int r = 0; r < 4; ++r) {
        const int m = M0 + wr*64 + mf*16 + kg*4 + r;
        dots[(size_t)m*NT + n] = acc[mf][nf][r];
      }
    }
}

// ---------------- Kernel 3: attention (R21 version, unchanged) ----------------
__global__ __launch_bounds__(256) void attn_kernel(
    const float* __restrict__ dots, const int* __restrict__ cap_lens,
    const ushort* __restrict__ gIb, const ushort* __restrict__ gCb,
    const float* __restrict__ nI, const float* __restrict__ nC,
    float* __restrict__ scores, int cbase)
{
  __shared__ float sDots[LN][RTA+1];                  // 48 x 37
  __shared__ __align__(16) ushort sMeT[LN*64];        // [l][r] swizzled (Me_t rows)
  __shared__ __align__(16) ushort sMeIT[48*64];       // [r][l] swizzled (Me_i^T rows)
  __shared__ float sQqT[LN], sQqI[48];
  __shared__ float sW12t[LN], sInvT[LN];
  __shared__ float sW12i[RN], sInvI[RN];
  __shared__ float sColInv[RN], sRowInv[LN];
  __shared__ float sCapN[LN], sImgN[RN];
  __shared__ float sEt[LN], sEi[RN];
  __shared__ float sRed[2];

  const int cl = blockIdx.y;
  const int c  = cbase + cl;
  const int it = blockIdx.x;
  const int tid = threadIdx.x;
  const int lane = tid & 63, wv = tid >> 6;
  const int l15 = lane & 15, kg = lane >> 4;
  const int team = tid >> 2, q4 = tid & 3;
  const int nw = cap_lens[c];
  const float nwf = (float)nw;

  // ---- Phase A: stage dots + zero Me ----
  for (int idx = tid; idx < LN*RTA/4; idx += 256) {
    const int l = idx / (RTA/4), jseg = idx - l*(RTA/4);
    const float4 v = *(const float4*)(dots + ((size_t)cl*LN + l)*NT + (size_t)it*RTA + jseg*4);
    float* dst = &sDots[l][jseg*4];
    dst[0]=v.x; dst[1]=v.y; dst[2]=v.z; dst[3]=v.w;
  }
  for (int idx = tid; idx < 768; idx += 256) {
    if (idx < 384) ((uint4*)sMeT)[idx] = make_uint4(0,0,0,0);
    else ((uint4*)sMeIT)[idx-384] = make_uint4(0,0,0,0);
  }
  if (tid < LN) { sCapN[tid] = nC[c*LN + tid]; sQqT[tid] = 0.f; }
  if (tid >= 64 && tid < 64+48) sQqI[tid-64] = 0.f;
  if (tid >= 128 && tid < 128+RN) sImgN[tid-128] = nI[it*RN + (tid-128)];
  __syncthreads();

  // ---- norms: team-parallel, two 64-team passes (log2e folded) ----
  #pragma unroll 1
  for (int pass = 0; pass < 2; ++pass) {
    const int vrow = pass*64 + team;
    if (vrow < RN) {
      float s = 0.f;
      #pragma unroll
      for (int j = 0; j < 12; ++j) { const float v = leaky(sDots[q4*12+j][vrow]); s += v*v; }
      s += __shfl_xor(s, 1, 4); s += __shfl_xor(s, 2, 4);
      if (q4 == 0) sColInv[vrow] = (LSM*LOG2E) * __builtin_amdgcn_rcpf(sqrtf(s) + EPSF);
    } else if (vrow < RN + LN) {
      const int l = vrow - RN;
      float s = 0.f;
      #pragma unroll
      for (int j = 0; j < 9; ++j) { const float v = leaky(sDots[l][q4*9+j]); s += v*v; }
      s += __shfl_xor(s, 1, 4); s += __shfl_xor(s, 2, 4);
      if (q4 == 0) sRowInv[l] = (LSM*LOG2E) * __builtin_amdgcn_rcpf(sqrtf(s) + EPSF);
    }
  }
  __syncthreads();

  // ---- Phase B: me rows (one row per 4-lane team; R8: do NOT re-batch) ----
  #pragma unroll 1
  for (int pass = 0; pass < 2; ++pass) {
    const int vrow = pass*64 + team;
    if (vrow < LN) {
      const int l = vrow;
      const int cb = q4*9;
      float d9[9], x9[9];
      #pragma unroll
      for (int j = 0; j < 9; ++j) d9[j] = sDots[l][cb + j];
      float se = 0.f;
      #pragma unroll
      for (int j = 0; j < 9; ++j) {
        const float e = exp2f(leaky(d9[j]) * sColInv[cb + j]);
        x9[j] = e; se += e;
      }
      se += __shfl_xor(se, 1, 4); se += __shfl_xor(se, 2, 4);
      float ts = 0.f;
      #pragma unroll
      for (int j = 0; j < 9; ++j) {
        const float me = (x9[j]*36.f > se) ? x9[j] : 0.f;
        x9[j] = me; ts += me;
      }
      ts += __shfl_xor(ts, 1, 4); ts += __shfl_xor(ts, 2, 4);
      float w12 = 0.f;
      #pragma unroll
      for (int j = 0; j < 9; ++j) w12 += x9[j]*d9[j];
      w12 += __shfl_xor(w12, 1, 4); w12 += __shfl_xor(w12, 2, 4);
      #pragma unroll
      for (int j = 0; j < 9; ++j)
        sMeT[l*64 + swzi(l, cb + j)] = bf16rne(x9[j]);
      if (q4 == 0) {
        sW12t[l] = w12;
        sInvT[l] = __builtin_amdgcn_rcpf((ts > 0.f) ? ts : 1.f);
      }
    } else {
      const int r = vrow - LN;
      if (r < RN) {
        float d12[12], x12[12];
        #pragma unroll
        for (int j = 0; j < 12; ++j) d12[j] = sDots[q4*12+j][r];
        float se = 0.f;
        #pragma unroll
        for (int j = 0; j < 12; ++j) {
          const int l = q4*12 + j;
          const float e = (l < nw) ? exp2f(leaky(d12[j]) * sRowInv[l]) : 0.f;
          x12[j] = e; se += e;
        }
        se += __shfl_xor(se, 1, 4); se += __shfl_xor(se, 2, 4);
        float ts = 0.f;
        #pragma unroll
        for (int j = 0; j < 12; ++j) {
          const float me = (x12[j]*nwf > se) ? x12[j] : 0.f;
          x12[j] = me; ts += me;
        }
        ts += __shfl_xor(ts, 1, 4); ts += __shfl_xor(ts, 2, 4);
        float w12 = 0.f;
        #pragma unroll
        for (int j = 0; j < 12; ++j) w12 += x12[j]*d12[j];
        w12 += __shfl_xor(w12, 1, 4); w12 += __shfl_xor(w12, 2, 4);
        #pragma unroll
        for (int j = 0; j < 12; ++j)
          sMeIT[r*64 + swzi(r, q4*12 + j)] = bf16rne(x12[j]);
        if (q4 == 0) {
          sW12i[r] = w12;
          sInvI[r] = __builtin_amdgcn_rcpf((ts > 0.f) ? ts : 1.f);
        }
      }
    }
  }
  __syncthreads();

  // ---- Phase C: qq via MFMA, unified paths ----
  const ushort* gIbase = gIb + (size_t)it*3072;
  const ushort* gCbase = gCb + (size_t)c*3072;
  #pragma unroll 1
  for (int t = wv; t < 18; t += 4) {
    const bool isT = (t < 9);
    const int tt = isT ? t : t - 9;
    const int mt = tt / 3, nt = tt - 3*(tt/3);
    const ushort* Ab = isT ? gIbase : gCbase;
    const ushort* Mb = isT ? sMeT   : sMeIT;
    const int arow = mt*16 + l15;
    const int brow = nt*16 + l15;
    f32x4 acc = (f32x4){0.f,0.f,0.f,0.f};
    #pragma unroll
    for (int ks = 0; ks < 2; ++ks) {
      const s16x8 af = *(const s16x8*)(Ab + arow*64 + (ks*4+kg)*8);
      const s16x8 bf = *(const s16x8*)&Mb[brow*64 + (((ks*4+kg) ^ (brow&7)))*8];
      acc = __builtin_amdgcn_mfma_f32_16x16x32_bf16(af, bf, acc, 0,0,0);
    }
    float part = 0.f;
    #pragma unroll
    for (int rg = 0; rg < 4; ++rg) {
      const int orow = mt*16 + kg*4 + rg;
      part += acc[rg] * bf2f(Mb[brow*64 + swzi(brow, orow)]);
    }
    part += __shfl_xor(part, 16);
    part += __shfl_xor(part, 32);
    if (lane < 16)
      atomicAdd(isT ? &sQqT[nt*16 + l15] : &sQqI[nt*16 + l15], part);
  }
  __syncthreads();

  // ---- Epilogue (exp2/log2 with folded constants) ----
  if (tid < LN) {
    const float invd = sInvT[tid];
    const float w2 = sqrtf(fmaxf(sQqT[tid]*invd*invd, 1e-16f));
    const float sim = (sW12t[tid]*invd) * __builtin_amdgcn_rcpf(fmaxf(sCapN[tid]*w2, EPSF));
    sEt[tid] = (tid < nw) ? exp2f((LLSE*LOG2E)*sim) : 0.f;
  }
  if (tid >= 64 && tid < 64+RN) {
    const int r = tid - 64;
    const float invd = sInvI[r];
    const float w2 = sqrtf(fmaxf(sQqI[r]*invd*invd, 1e-16f));
    const float sim = (sW12i[r]*invd) * __builtin_amdgcn_rcpf(fmaxf(sImgN[r]*w2, EPSF));
    sEi[r] = exp2f((LLSE*LOG2E)*sim);
  }
  __syncthreads();
  if (wv == 0) {
    float e = (lane < LN) ? sEt[lane] : 0.f;
    #pragma unroll
    for (int o = 32; o > 0; o >>= 1) e += __shfl_xor(e, o);
    if (lane == 0) sRed[0] = e;
  } else if (wv == 1) {
    float e = (lane < RN) ? sEi[lane] : 0.f;
    #pragma unroll
    for (int o = 32; o > 0; o >>= 1) e += __shfl_xor(e, o);
    if (lane == 0) sRed[1] = e;
  }
  __syncthreads();
  if (tid == 0)
    scores[(size_t)it*CN + c] = log2f(sRed[0]*sRed[1]) * (1.f/(LLSE*LOG2E));
}

// ---------------- Kernel 4: margin ranking loss ----------------
__global__ __launch_bounds__(128) void loss_kernel(
    const float* __restrict__ S, float* __restrict__ out)
{
  __shared__ float red[128];
  const int t = threadIdx.x;
  const float d = S[t*CN + t];
  float m1 = -1e30f, m2 = -1e30f;
  for (int cc = 0; cc < CN; ++cc)
    if (cc != t) m1 = fmaxf(m1, 0.2f + S[t*CN+cc] - d);
  for (int i2 = 0; i2 < INN; ++i2)
    if (i2 != t) m2 = fmaxf(m2, 0.2f + S[i2*CN+t] - d);
  red[t] = fmaxf(m1, 0.f) + fmaxf(m2, 0.f);
  __syncthreads();
  for (int s = 64; s > 0; s >>= 1) {
    if (t < s) red[t] += red[t+s];
    __syncthreads();
  }
  if (t == 0) out[0] = red[0];
}

extern "C" void kernel_launch(void* const* d_in, const int* in_sizes, int n_in,
                              void* d_out, int out_size, void* d_ws, size_t ws_size,
                              hipStream_t stream) {
  (void)in_sizes; (void)n_in; (void)out_size;
  const float* imgs = (const float*)d_in[0];
  const float* caps = (const float*)d_in[1];
  const int*   lens = (const int*)d_in[2];

  const size_t bfUS = 2*((size_t)MT + NT)*DN;   // layout unchanged (lo slots unused)
  const size_t gbUS = (size_t)(INN + CN)*3072;
  const size_t smallF = (size_t)INN*RN*RN + INN*RN + (size_t)CN*LN*LN + CN*LN + (size_t)INN*CN;
  int g = CN;
  while (g > 8) {
    const size_t need = (bfUS + gbUS)*2 + (smallF + (size_t)g*LN*NT)*4;
    if (need <= ws_size) break;
    g >>= 1;
  }

  ushort* aHi = (ushort*)d_ws;
  ushort* aLo = aHi + (size_t)MT*DN;   // unused
  ushort* bHi = aLo + (size_t)MT*DN;
  ushort* bLo = bHi + (size_t)NT*DN;   // unused
  ushort* gIb = bLo + (size_t)NT*DN;
  ushort* gCb = gIb + (size_t)INN*3072;
  float* fbase = (float*)(gCb + (size_t)CN*3072);
  float* gI     = fbase;               // unused (R23: fp32 G eliminated)
  float* nI     = gI + (size_t)INN*RN*RN;
  float* gC     = nI + (size_t)INN*RN; // unused
  float* nC     = gC + (size_t)CN*LN*LN;
  float* scores = nC + (size_t)CN*LN;
  float* dots   = scores + (size_t)INN*CN;

  conv_kernel<<<dim3(1024), dim3(256), 0, stream>>>(caps, imgs, aHi, bHi);
  gram_mfma_kernel<<<dim3(INN+CN), dim3(256), 0, stream>>>(
      aHi, bHi, nI, nC, gIb, gCb);
  for (int c0 = 0; c0 < CN; c0 += g) {
    dots_gemm_mfma<<<dim3(NT/128, g*LN/128), dim3(256), 0, stream>>>(
        aHi, bHi, dots, c0*LN);
    attn_kernel<<<dim3(INN, g), dim3(256), 0, stream>>>(
        dots, lens, gIb, gCb, nI, nC, scores, c0);
  }
  loss_kernel<<<dim3(1), dim3(128), 0, stream>>>(scores, (float*)d_out);
}

// Round 24
// 248.332 us; speedup vs baseline: 1.5809x; 1.0074x over previous
//
#include <hip/hip_runtime.h>
#include <math.h>

#define CN 128   // captions
#define INN 128  // images
#define LN 48    // words
#define RN 36    // regions
#define DN 1024  // feature dim
#define RTA 36   // regions per attn block (TIA=1)
#define MT 6144  // CN*LN
#define NT 4608  // INN*RN
#define EPSF 1e-8f
#define LSM 9.0f
#define LLSE 6.0f
#define LOG2E 1.4426950408889634f

__device__ __forceinline__ float leaky(float x){ return x > 0.f ? x : 0.1f*x; }

typedef const __attribute__((address_space(1))) unsigned int* gp_t;
typedef __attribute__((address_space(3))) unsigned int* lp_t;
__device__ __forceinline__ void gload16u(const ushort* g, ushort* l) {
  __builtin_amdgcn_global_load_lds((gp_t)g, (lp_t)l, 16, 0, 0);
}

typedef short s16x8 __attribute__((ext_vector_type(8)));
typedef float f32x4 __attribute__((ext_vector_type(4)));

__device__ __forceinline__ ushort bf16rne(float f) {
  const unsigned u = __float_as_uint(f);
  return (ushort)((u + 0x7fffu + ((u>>16)&1u)) >> 16);
}
__device__ __forceinline__ float bf2f(ushort u) {
  return __uint_as_float((unsigned)u << 16);
}
// XOR swizzle within a 64-elem bf16 row (8-elem granules): 2-way max bank alias
__device__ __forceinline__ int swzi(int row, int col) {
  return (col & 7) | ((((col >> 3) ^ (row & 7)) & 7) << 3);
}

// ---------------- Kernel 0: fp32 -> bf16 planes (pure streaming) ----------------
__global__ __launch_bounds__(256) void conv_kernel(
    const float* __restrict__ caps, const float* __restrict__ imgs,
    ushort* __restrict__ aHi, ushort* __restrict__ bHi)
{
  const int NA = MT*DN/4, NB = NT*DN/4;
  for (int i = blockIdx.x*256 + threadIdx.x; i < NA + NB; i += gridDim.x*256) {
    const float4 v = (i < NA) ? ((const float4*)caps)[i] : ((const float4*)imgs)[i - NA];
    const ushort4 h = make_ushort4(bf16rne(v.x), bf16rne(v.y), bf16rne(v.z), bf16rne(v.w));
    if (i < NA) ((ushort4*)aHi)[i] = h;
    else        ((ushort4*)bHi)[i-NA] = h;
  }
}

// ---------------- Kernel 1: Gram via MFMA from bf16 planes (R23, verified) -------
__global__ __launch_bounds__(256) void gram_mfma_kernel(
    const ushort* __restrict__ aHi, const ushort* __restrict__ bHi,
    float* __restrict__ nI, float* __restrict__ nC,
    ushort* __restrict__ gIb, ushort* __restrict__ gCb)
{
  __shared__ __align__(16) ushort sX[48*64];   // 6KB, granule-swizzled
  const int b = blockIdx.x, tid = threadIdx.x;
  const bool isImg = b < INN;
  const int R = isImg ? RN : LN;
  const ushort* X = isImg ? (bHi + (size_t)b*RN*DN) : (aHi + (size_t)(b-INN)*LN*DN);
  ushort* gOut = isImg ? (gIb + (size_t)b*3072) : (gCb + (size_t)(b-INN)*3072);
  float* nOut = isImg ? (nI + b*RN) : (nC + (b-INN)*LN);
  const int lane = tid & 63, wv = tid >> 6;
  const int l15 = lane & 15, kg = lane >> 4;

  f32x4 acc[3];
  #pragma unroll
  for (int i = 0; i < 3; ++i) acc[i] = (f32x4){0.f,0.f,0.f,0.f};

  for (int k0 = 0; k0 < DN; k0 += 64) {
    __syncthreads();
    for (int idx = tid; idx < R*8; idx += 256) {
      const int row = idx >> 3, gp = idx & 7;
      *(uint4*)&sX[row*64 + (gp ^ (row&7))*8] =
        *(const uint4*)(X + (size_t)row*DN + k0 + gp*8);
    }
    __syncthreads();
    #pragma unroll
    for (int i = 0; i < 3; ++i) {
      const int tt = wv + 4*i;
      if (tt < 9) {
        const int mt = tt/3, nt = tt - 3*(tt/3);
        #pragma unroll
        for (int ks = 0; ks < 2; ++ks) {
          const int rA = mt*16 + l15, rB = nt*16 + l15;
          const s16x8 af = *(const s16x8*)&sX[rA*64 + (((ks*4+kg) ^ (rA&7)))*8];
          const s16x8 bf = *(const s16x8*)&sX[rB*64 + (((ks*4+kg) ^ (rB&7)))*8];
          acc[i] = __builtin_amdgcn_mfma_f32_16x16x32_bf16(af, bf, acc[i], 0,0,0);
        }
      }
    }
  }
  #pragma unroll
  for (int i = 0; i < 3; ++i) {
    const int tt = wv + 4*i;
    if (tt < 9) {
      const int mt = tt/3, nt = tt - 3*(tt/3);
      #pragma unroll
      for (int rg = 0; rg < 4; ++rg) {
        const int m = mt*16 + kg*4 + rg, n = nt*16 + l15;
        const float cv = acc[i][rg];
        gOut[m*64 + n] = (m < R && n < R) ? bf16rne(cv) : (ushort)0;
        if (m == n && m < R) nOut[m] = sqrtf(fmaxf(cv, 1e-16f));
      }
    }
  }
  for (int idx = tid; idx < 48*16; idx += 256) {
    const int row = idx >> 4, col = 48 + (idx & 15);
    gOut[row*64 + col] = 0;
  }
}

// ---------------- Kernel 2: dots GEMM — BK=32, double-buffered (T3-minimum) ------
// R24: STAGE(buf^1, t+1) issued BEFORE compute(buf[t]); single vmcnt(0)+barrier
// per K-step so next-tile loads fly under this tile's MFMA. Indexing = R20's
// verified BK=32 layout; accumulation order unchanged (bit-identical output).
// LDS 2x16KB = 32KB => 5 blocks/CU (same as R22's single-buf BK=64).
__global__ __launch_bounds__(256) void dots_gemm_mfma(
    const ushort* __restrict__ aHi, const ushort* __restrict__ bHi,
    float* __restrict__ dots, int arow0)
{
  __shared__ __align__(16) ushort sT[2][8192];   // per buf: A [0,4096) B [4096,8192)
  const int tid = threadIdx.x;
  const int wv = tid >> 6, lane = tid & 63;
  const int l15 = lane & 15, kg = lane >> 4;
  const int wr = wv >> 1, wc = wv & 1;
  const int M0 = blockIdx.y * 128;
  const int N0 = blockIdx.x * 128;

  int offA[4], offB[4];
  #pragma unroll
  for (int f = 0; f < 4; ++f) {
    const int rA = wr*64 + f*16 + l15;
    offA[f] = rA*32 + ((kg ^ ((rA>>1)&3)) << 3);
    const int rB = wc*64 + f*16 + l15;
    offB[f] = rB*32 + ((kg ^ ((rB>>1)&3)) << 3);
  }
  int srow[2], sgk[2]; unsigned dOff[2];
  #pragma unroll
  for (int h = 0; h < 2; ++h) {
    const int ch = h*256 + wv*64 + lane;
    const int row = ch >> 2, gp = ch & 3;
    srow[h] = row;
    sgk[h] = (gp ^ ((row>>1)&3)) * 8;
    dOff[h] = (unsigned)(h*256 + wv*64) * 8;   // wave-uniform base, lane*16B auto
  }

  f32x4 acc[4][4];
  #pragma unroll
  for (int mf = 0; mf < 4; ++mf)
    #pragma unroll
    for (int nf = 0; nf < 4; ++nf) acc[mf][nf] = (f32x4){0.f,0.f,0.f,0.f};

  const size_t aR = (size_t)(arow0 + M0);

  // prologue: stage tile 0 into buf 0, drain, sync
  #pragma unroll
  for (int h = 0; h < 2; ++h) {
    gload16u(aHi + (aR + srow[h])*DN + sgk[h],                  &sT[0][0]    + dOff[h]);
    gload16u(bHi + ((size_t)(N0 + srow[h]))*DN + sgk[h],        &sT[0][4096] + dOff[h]);
  }
  asm volatile("s_waitcnt vmcnt(0)" ::: "memory");
  __syncthreads();

  int cur = 0;
  for (int t = 0; t < 32; ++t) {
    if (t < 31) {                       // issue next tile's loads (async, in flight)
      const int k1 = (t + 1) * 32;
      #pragma unroll
      for (int h = 0; h < 2; ++h) {
        gload16u(aHi + (aR + srow[h])*DN + k1 + sgk[h],           &sT[cur^1][0]    + dOff[h]);
        gload16u(bHi + ((size_t)(N0 + srow[h]))*DN + k1 + sgk[h], &sT[cur^1][4096] + dOff[h]);
      }
    }
    s16x8 ah[4], bh[4];
    #pragma unroll
    for (int f = 0; f < 4; ++f) {
      ah[f] = *(const s16x8*)&sT[cur][offA[f]];
      bh[f] = *(const s16x8*)&sT[cur][4096 + offB[f]];
    }
    #pragma unroll
    for (int mf = 0; mf < 4; ++mf)
      #pragma unroll
      for (int nf = 0; nf < 4; ++nf)
        acc[mf][nf] = __builtin_amdgcn_mfma_f32_16x16x32_bf16(ah[mf], bh[nf], acc[mf][nf], 0,0,0);
    asm volatile("s_waitcnt vmcnt(0)" ::: "memory");   // next tile landed
    __syncthreads();                                   // all waves done reading sT[cur]
    cur ^= 1;
  }
  #pragma unroll
  for (int mf = 0; mf < 4; ++mf)
    #pragma unroll
    for (int nf = 0; nf < 4; ++nf) {
      const int n = N0 + wc*64 + nf*16 + l15;
      #pragma unroll
      for (int r = 0; r < 4; ++r) {
        const int m = M0 + wr*64 + mf*16 + kg*4 + r;
        dots[(size_t)m*NT + n] = acc[mf][nf][r];
      }
    }
}

// ---------------- Kernel 3: attention (R21 version, unchanged) ----------------
__global__ __launch_bounds__(256) void attn_kernel(
    const float* __restrict__ dots, const int* __restrict__ cap_lens,
    const ushort* __restrict__ gIb, const ushort* __restrict__ gCb,
    const float* __restrict__ nI, const float* __restrict__ nC,
    float* __restrict__ scores, int cbase)
{
  __shared__ float sDots[LN][RTA+1];                  // 48 x 37
  __shared__ __align__(16) ushort sMeT[LN*64];        // [l][r] swizzled (Me_t rows)
  __shared__ __align__(16) ushort sMeIT[48*64];       // [r][l] swizzled (Me_i^T rows)
  __shared__ float sQqT[LN], sQqI[48];
  __shared__ float sW12t[LN], sInvT[LN];
  __shared__ float sW12i[RN], sInvI[RN];
  __shared__ float sColInv[RN], sRowInv[LN];
  __shared__ float sCapN[LN], sImgN[RN];
  __shared__ float sEt[LN], sEi[RN];
  __shared__ float sRed[2];

  const int cl = blockIdx.y;
  const int c  = cbase + cl;
  const int it = blockIdx.x;
  const int tid = threadIdx.x;
  const int lane = tid & 63, wv = tid >> 6;
  const int l15 = lane & 15, kg = lane >> 4;
  const int team = tid >> 2, q4 = tid & 3;
  const int nw = cap_lens[c];
  const float nwf = (float)nw;

  // ---- Phase A: stage dots + zero Me ----
  for (int idx = tid; idx < LN*RTA/4; idx += 256) {
    const int l = idx / (RTA/4), jseg = idx - l*(RTA/4);
    const float4 v = *(const float4*)(dots + ((size_t)cl*LN + l)*NT + (size_t)it*RTA + jseg*4);
    float* dst = &sDots[l][jseg*4];
    dst[0]=v.x; dst[1]=v.y; dst[2]=v.z; dst[3]=v.w;
  }
  for (int idx = tid; idx < 768; idx += 256) {
    if (idx < 384) ((uint4*)sMeT)[idx] = make_uint4(0,0,0,0);
    else ((uint4*)sMeIT)[idx-384] = make_uint4(0,0,0,0);
  }
  if (tid < LN) { sCapN[tid] = nC[c*LN + tid]; sQqT[tid] = 0.f; }
  if (tid >= 64 && tid < 64+48) sQqI[tid-64] = 0.f;
  if (tid >= 128 && tid < 128+RN) sImgN[tid-128] = nI[it*RN + (tid-128)];
  __syncthreads();

  // ---- norms: team-parallel, two 64-team passes (log2e folded) ----
  #pragma unroll 1
  for (int pass = 0; pass < 2; ++pass) {
    const int vrow = pass*64 + team;
    if (vrow < RN) {
      float s = 0.f;
      #pragma unroll
      for (int j = 0; j < 12; ++j) { const float v = leaky(sDots[q4*12+j][vrow]); s += v*v; }
      s += __shfl_xor(s, 1, 4); s += __shfl_xor(s, 2, 4);
      if (q4 == 0) sColInv[vrow] = (LSM*LOG2E) * __builtin_amdgcn_rcpf(sqrtf(s) + EPSF);
    } else if (vrow < RN + LN) {
      const int l = vrow - RN;
      float s = 0.f;
      #pragma unroll
      for (int j = 0; j < 9; ++j) { const float v = leaky(sDots[l][q4*9+j]); s += v*v; }
      s += __shfl_xor(s, 1, 4); s += __shfl_xor(s, 2, 4);
      if (q4 == 0) sRowInv[l] = (LSM*LOG2E) * __builtin_amdgcn_rcpf(sqrtf(s) + EPSF);
    }
  }
  __syncthreads();

  // ---- Phase B: me rows (one row per 4-lane team; R8: do NOT re-batch) ----
  #pragma unroll 1
  for (int pass = 0; pass < 2; ++pass) {
    const int vrow = pass*64 + team;
    if (vrow < LN) {
      const int l = vrow;
      const int cb = q4*9;
      float d9[9], x9[9];
      #pragma unroll
      for (int j = 0; j < 9; ++j) d9[j] = sDots[l][cb + j];
      float se = 0.f;
      #pragma unroll
      for (int j = 0; j < 9; ++j) {
        const float e = exp2f(leaky(d9[j]) * sColInv[cb + j]);
        x9[j] = e; se += e;
      }
      se += __shfl_xor(se, 1, 4); se += __shfl_xor(se, 2, 4);
      float ts = 0.f;
      #pragma unroll
      for (int j = 0; j < 9; ++j) {
        const float me = (x9[j]*36.f > se) ? x9[j] : 0.f;
        x9[j] = me; ts += me;
      }
      ts += __shfl_xor(ts, 1, 4); ts += __shfl_xor(ts, 2, 4);
      float w12 = 0.f;
      #pragma unroll
      for (int j = 0; j < 9; ++j) w12 += x9[j]*d9[j];
      w12 += __shfl_xor(w12, 1, 4); w12 += __shfl_xor(w12, 2, 4);
      #pragma unroll
      for (int j = 0; j < 9; ++j)
        sMeT[l*64 + swzi(l, cb + j)] = bf16rne(x9[j]);
      if (q4 == 0) {
        sW12t[l] = w12;
        sInvT[l] = __builtin_amdgcn_rcpf((ts > 0.f) ? ts : 1.f);
      }
    } else {
      const int r = vrow - LN;
      if (r < RN) {
        float d12[12], x12[12];
        #pragma unroll
        for (int j = 0; j < 12; ++j) d12[j] = sDots[q4*12+j][r];
        float se = 0.f;
        #pragma unroll
        for (int j = 0; j < 12; ++j) {
          const int l = q4*12 + j;
          const float e = (l < nw) ? exp2f(leaky(d12[j]) * sRowInv[l]) : 0.f;
          x12[j] = e; se += e;
        }
        se += __shfl_xor(se, 1, 4); se += __shfl_xor(se, 2, 4);
        float ts = 0.f;
        #pragma unroll
        for (int j = 0; j < 12; ++j) {
          const float me = (x12[j]*nwf > se) ? x12[j] : 0.f;
          x12[j] = me; ts += me;
        }
        ts += __shfl_xor(ts, 1, 4); ts += __shfl_xor(ts, 2, 4);
        float w12 = 0.f;
        #pragma unroll
        for (int j = 0; j < 12; ++j) w12 += x12[j]*d12[j];
        w12 += __shfl_xor(w12, 1, 4); w12 += __shfl_xor(w12, 2, 4);
        #pragma unroll
        for (int j = 0; j < 12; ++j)
          sMeIT[r*64 + swzi(r, q4*12 + j)] = bf16rne(x12[j]);
        if (q4 == 0) {
          sW12i[r] = w12;
          sInvI[r] = __builtin_amdgcn_rcpf((ts > 0.f) ? ts : 1.f);
        }
      }
    }
  }
  __syncthreads();

  // ---- Phase C: qq via MFMA, unified paths ----
  const ushort* gIbase = gIb + (size_t)it*3072;
  const ushort* gCbase = gCb + (size_t)c*3072;
  #pragma unroll 1
  for (int t = wv; t < 18; t += 4) {
    const bool isT = (t < 9);
    const int tt = isT ? t : t - 9;
    const int mt = tt / 3, nt = tt - 3*(tt/3);
    const ushort* Ab = isT ? gIbase : gCbase;
    const ushort* Mb = isT ? sMeT   : sMeIT;
    const int arow = mt*16 + l15;
    const int brow = nt*16 + l15;
    f32x4 acc = (f32x4){0.f,0.f,0.f,0.f};
    #pragma unroll
    for (int ks = 0; ks < 2; ++ks) {
      const s16x8 af = *(const s16x8*)(Ab + arow*64 + (ks*4+kg)*8);
      const s16x8 bf = *(const s16x8*)&Mb[brow*64 + (((ks*4+kg) ^ (brow&7)))*8];
      acc = __builtin_amdgcn_mfma_f32_16x16x32_bf16(af, bf, acc, 0,0,0);
    }
    float part = 0.f;
    #pragma unroll
    for (int rg = 0; rg < 4; ++rg) {
      const int orow = mt*16 + kg*4 + rg;
      part += acc[rg] * bf2f(Mb[brow*64 + swzi(brow, orow)]);
    }
    part += __shfl_xor(part, 16);
    part += __shfl_xor(part, 32);
    if (lane < 16)
      atomicAdd(isT ? &sQqT[nt*16 + l15] : &sQqI[nt*16 + l15], part);
  }
  __syncthreads();

  // ---- Epilogue (exp2/log2 with folded constants) ----
  if (tid < LN) {
    const float invd = sInvT[tid];
    const float w2 = sqrtf(fmaxf(sQqT[tid]*invd*invd, 1e-16f));
    const float sim = (sW12t[tid]*invd) * __builtin_amdgcn_rcpf(fmaxf(sCapN[tid]*w2, EPSF));
    sEt[tid] = (tid < nw) ? exp2f((LLSE*LOG2E)*sim) : 0.f;
  }
  if (tid >= 64 && tid < 64+RN) {
    const int r = tid - 64;
    const float invd = sInvI[r];
    const float w2 = sqrtf(fmaxf(sQqI[r]*invd*invd, 1e-16f));
    const float sim = (sW12i[r]*invd) * __builtin_amdgcn_rcpf(fmaxf(sImgN[r]*w2, EPSF));
    sEi[r] = exp2f((LLSE*LOG2E)*sim);
  }
  __syncthreads();
  if (wv == 0) {
    float e = (lane < LN) ? sEt[lane] : 0.f;
    #pragma unroll
    for (int o = 32; o > 0; o >>= 1) e += __shfl_xor(e, o);
    if (lane == 0) sRed[0] = e;
  } else if (wv == 1) {
    float e = (lane < RN) ? sEi[lane] : 0.f;
    #pragma unroll
    for (int o = 32; o > 0; o >>= 1) e += __shfl_xor(e, o);
    if (lane == 0) sRed[1] = e;
  }
  __syncthreads();
  if (tid == 0)
    scores[(size_t)it*CN + c] = log2f(sRed[0]*sRed[1]) * (1.f/(LLSE*LOG2E));
}

// ---------------- Kernel 4: margin ranking loss ----------------
__global__ __launch_bounds__(128) void loss_kernel(
    const float* __restrict__ S, float* __restrict__ out)
{
  __shared__ float red[128];
  const int t = threadIdx.x;
  const float d = S[t*CN + t];
  float m1 = -1e30f, m2 = -1e30f;
  for (int cc = 0; cc < CN; ++cc)
    if (cc != t) m1 = fmaxf(m1, 0.2f + S[t*CN+cc] - d);
  for (int i2 = 0; i2 < INN; ++i2)
    if (i2 != t) m2 = fmaxf(m2, 0.2f + S[i2*CN+t] - d);
  red[t] = fmaxf(m1, 0.f) + fmaxf(m2, 0.f);
  __syncthreads();
  for (int s = 64; s > 0; s >>= 1) {
    if (t < s) red[t] += red[t+s];
    __syncthreads();
  }
  if (t == 0) out[0] = red[0];
}

extern "C" void kernel_launch(void* const* d_in, const int* in_sizes, int n_in,
                              void* d_out, int out_size, void* d_ws, size_t ws_size,
                              hipStream_t stream) {
  (void)in_sizes; (void)n_in; (void)out_size;
  const float* imgs = (const float*)d_in[0];
  const float* caps = (const float*)d_in[1];
  const int*   lens = (const int*)d_in[2];

  const size_t bfUS = 2*((size_t)MT + NT)*DN;   // layout unchanged (lo slots unused)
  const size_t gbUS = (size_t)(INN + CN)*3072;
  const size_t smallF = (size_t)INN*RN*RN + INN*RN + (size_t)CN*LN*LN + CN*LN + (size_t)INN*CN;
  int g = CN;
  while (g > 8) {
    const size_t need = (bfUS + gbUS)*2 + (smallF + (size_t)g*LN*NT)*4;
    if (need <= ws_size) break;
    g >>= 1;
  }

  ushort* aHi = (ushort*)d_ws;
  ushort* aLo = aHi + (size_t)MT*DN;   // unused
  ushort* bHi = aLo + (size_t)MT*DN;
  ushort* bLo = bHi + (size_t)NT*DN;   // unused
  ushort* gIb = bLo + (size_t)NT*DN;
  ushort* gCb = gIb + (size_t)INN*3072;
  float* fbase = (float*)(gCb + (size_t)CN*3072);
  float* gI     = fbase;               // unused
  float* nI     = gI + (size_t)INN*RN*RN;
  float* gC     = nI + (size_t)INN*RN; // unused
  float* nC     = gC + (size_t)CN*LN*LN;
  float* scores = nC + (size_t)CN*LN;
  float* dots   = scores + (size_t)INN*CN;

  conv_kernel<<<dim3(1024), dim3(256), 0, stream>>>(caps, imgs, aHi, bHi);
  gram_mfma_kernel<<<dim3(INN+CN), dim3(256), 0, stream>>>(
      aHi, bHi, nI, nC, gIb, gCb);
  for (int c0 = 0; c0 < CN; c0 += g) {
    dots_gemm_mfma<<<dim3(NT/128, g*LN/128), dim3(256), 0, stream>>>(
        aHi, bHi, dots, c0*LN);
    attn_kernel<<<dim3(INN, g), dim3(256), 0, stream>>>(
        dots, lens, gIb, gCb, nI, nC, scores, c0);
  }
  loss_kernel<<<dim3(1), dim3(128), 0, stream>>>(scores, (float*)d_out);
}